// Round 2
// baseline (3685.315 us; speedup 1.0000x reference)
//
#include <hip/hip_runtime.h>
#include <math.h>

#define B_  8
#define CIN 3
#define HIN 256
#define WIN 256
#define CMID 16
#define HMID 128
#define WMID 128
#define DM 256
#define L_ 4096
#define DI 512
#define NH 8
#define HD 64
#define NS 128
#define KC 4
#define CONVDIM 768
#define PROJ 1288
#define MTOK (B_*L_)

typedef unsigned short bf16;

__device__ inline float bf2f(bf16 u) { return __uint_as_float(((unsigned int)u) << 16); }
__device__ inline bf16 f2bf(float f) {
  unsigned int x = __float_as_uint(f);
  return (bf16)((x + 0x7fffu + ((x >> 16) & 1u)) >> 16);
}

__device__ inline float4 ldA4(const float* p) { return *(const float4*)p; }
__device__ inline float4 ldA4(const bf16* p) {
  ushort4 u = *(const ushort4*)p;
  return make_float4(bf2f(u.x), bf2f(u.y), bf2f(u.z), bf2f(u.w));
}

// ---------------- conv 3x3 stride 2 pad 1 ----------------
__global__ void k_conv1(const float* __restrict__ x, const float* __restrict__ w,
                        const float* __restrict__ bias, float* __restrict__ out) {
  int idx = blockIdx.x*256 + threadIdx.x;
  if (idx >= B_*CMID*HMID*WMID) return;
  int xo = idx & 127, yo = (idx>>7)&127, co = (idx>>14)&15, b = idx>>18;
  float acc = bias[co];
  const float* xb = x + (size_t)b*CIN*HIN*WIN;
  const float* wc = w + co*CIN*9;
  #pragma unroll
  for (int ci=0; ci<CIN; ci++)
    #pragma unroll
    for (int ky=0; ky<3; ky++) {
      int yi = 2*yo - 1 + ky;
      if (yi < 0 || yi >= HIN) continue;
      #pragma unroll
      for (int kx=0; kx<3; kx++) {
        int xi = 2*xo - 1 + kx;
        if (xi < 0 || xi >= WIN) continue;
        acc += xb[(ci*HIN + yi)*WIN + xi] * wc[(ci*3+ky)*3+kx];
      }
    }
  out[idx] = acc;
}

// ---------------- batchnorm stats ----------------
__global__ void k_bnstats(const float* __restrict__ h, float* __restrict__ stats) {
  int c = blockIdx.x;
  int tid = threadIdx.x;
  const int NPC = B_*HMID*WMID;
  float s=0.f, s2=0.f;
  for (int i=tid; i<NPC; i+=256) {
    int b = i >> 14;
    int sp = i & 16383;
    float v = h[((size_t)(b*CMID + c))*16384 + sp];
    s += v; s2 += v*v;
  }
  #pragma unroll
  for (int off=1; off<64; off<<=1) { s += __shfl_xor(s, off); s2 += __shfl_xor(s2, off); }
  __shared__ float sb[2][4];
  int wv = tid>>6;
  if ((tid&63)==0) { sb[0][wv]=s; sb[1][wv]=s2; }
  __syncthreads();
  if (tid==0) {
    float S  = sb[0][0]+sb[0][1]+sb[0][2]+sb[0][3];
    float S2 = sb[1][0]+sb[1][1]+sb[1][2]+sb[1][3];
    float mean = S / (float)NPC;
    float var  = S2 / (float)NPC - mean*mean;
    stats[c]      = mean;
    stats[16 + c] = rsqrtf(var + 1e-5f);
  }
}

// ---------------- BN apply + exact GELU ----------------
__global__ void k_bngelu(float* __restrict__ h, const float* __restrict__ stats,
                         const float* __restrict__ gamma, const float* __restrict__ beta) {
  int idx = blockIdx.x*256 + threadIdx.x;
  if (idx >= B_*CMID*HMID*WMID) return;
  int c = (idx>>14)&15;
  float v = (h[idx] - stats[c]) * stats[16+c] * gamma[c] + beta[c];
  h[idx] = 0.5f * v * (1.f + erff(v * 0.70710678118654752f));
}

// ---------------- patch conv 2x2 s2 + bias + sincos -> tok (bf16) ----------------
__global__ __launch_bounds__(256) void k_patch(const float* __restrict__ h, const float* __restrict__ pw,
                       const float* __restrict__ pb, bf16* __restrict__ tok) {
  int bg = blockIdx.x;
  int b = bg >> 12, g = bg & 4095;
  int gy = g >> 6, gx = g & 63;
  __shared__ float sh[64];
  int tid = threadIdx.x;
  if (tid < 64) {
    int ci = tid >> 2, p = (tid>>1)&1, q = tid&1;
    sh[tid] = h[((size_t)(b*CMID+ci)*HMID + (2*gy+p))*WMID + (2*gx+q)];
  }
  __syncthreads();
  int d = tid;
  float acc = pb[d];
  const float* wr = pw + d*64;
  #pragma unroll 8
  for (int j=0;j<64;j++) acc += sh[j]*wr[j];
  int i = d & 63;
  float gv = (d < 128) ? (float)gx : (float)gy;
  float omega = expf(-(float)i * (9.210340371976184f/64.f));
  float ph = gv * omega;
  float pos = (d & 64) ? cosf(ph) : sinf(ph);
  tok[(size_t)bg*DM + d] = f2bf(acc + pos);
}

// ---------------- f32-accum GEMM: C[m,n] = sum_k A[m,k]*Bw[n,k] ----------------
// EPI 0: route cols -> z(bf16) / xpre(bf16) / dt-chain(f32 dtv,dAv)
// EPI 1: o_f[m,n] = acc + bf2f(res[m,n])
// EPI 2: acc + bias[n], pixel-shuffle scatter into output image
template<int EPI, typename TA>
__global__ __launch_bounds__(256) void k_gemm(
    const TA* __restrict__ A, const float* __restrict__ Bw,
    int M, int N, int K,
    bf16* __restrict__ o_z, bf16* __restrict__ o_x,
    float* __restrict__ o_f,
    const bf16* __restrict__ res_bf,
    const float* __restrict__ bias,
    const float* __restrict__ dt_bias, const float* __restrict__ A_log,
    float* __restrict__ dtv, float* __restrict__ dAv) {
  __shared__ __align__(16) float As[16][64];
  __shared__ __align__(16) float Bs[16][64];
  int tid = threadIdx.x;
  int tx = tid & 15, ty = tid >> 4;
  int m0 = blockIdx.y*64, n0 = blockIdx.x*64;
  float acc[4][4] = {{0.f}};
  for (int k0=0; k0<K; k0+=16) {
    int r = tid >> 2;
    int kq = (tid & 3) << 2;
    {
      float4 v = ldA4(A + (size_t)(m0+r)*K + k0 + kq);
      As[kq+0][r]=v.x; As[kq+1][r]=v.y; As[kq+2][r]=v.z; As[kq+3][r]=v.w;
    }
    {
      int n = n0 + r;
      float4 v = make_float4(0.f,0.f,0.f,0.f);
      if (n < N) v = *(const float4*)(Bw + (size_t)n*K + k0 + kq);
      Bs[kq+0][r]=v.x; Bs[kq+1][r]=v.y; Bs[kq+2][r]=v.z; Bs[kq+3][r]=v.w;
    }
    __syncthreads();
    #pragma unroll
    for (int k=0;k<16;k++) {
      float4 a  = *(const float4*)&As[k][ty*4];
      float4 bb = *(const float4*)&Bs[k][tx*4];
      float av[4] = {a.x,a.y,a.z,a.w};
      float bv[4] = {bb.x,bb.y,bb.z,bb.w};
      #pragma unroll
      for (int i=0;i<4;i++)
        #pragma unroll
        for (int j=0;j<4;j++)
          acc[i][j] = fmaf(av[i], bv[j], acc[i][j]);
    }
    __syncthreads();
  }
  #pragma unroll
  for (int i=0;i<4;i++) {
    int m = m0 + ty*4 + i;
    #pragma unroll
    for (int j=0;j<4;j++) {
      int n = n0 + tx*4 + j;
      float v = acc[i][j];
      if (EPI == 0) {
        if (n < DI) {
          o_z[(size_t)m*DI + n] = f2bf(v);
        } else if (n < DI + CONVDIM) {
          o_x[(size_t)m*CONVDIM + (n - DI)] = f2bf(v);
        } else if (n < PROJ) {
          int hh = n - (DI + CONVDIM);
          float xv = v + dt_bias[hh];
          float dt = (xv > 20.f) ? xv : log1pf(expf(xv));
          dtv[(size_t)m*NH + hh] = dt;
          dAv[(size_t)m*NH + hh] = expf(-expf(A_log[hh]) * dt);
        }
      } else if (EPI == 1) {
        o_f[(size_t)m*N + n] = v + bf2f(res_bf[(size_t)m*N + n]);
      } else {
        float vv = v + bias[n];
        int b = m >> 12, g = m & 4095;
        int gy = g >> 6, gx = g & 63;
        int p = n >> 5, q = (n>>4)&1, c = n & 15;
        o_f[(((size_t)(b*CMID+c))*HMID + 2*gy+p)*WMID + (2*gx+q)] = vv;
      }
    }
  }
}

// ---------------- causal depthwise conv1d (KC=4) + bias + silu (bf16 in/out) ----------------
__global__ void k_conv1d(const bf16* __restrict__ xpre, const float* __restrict__ cw,
                         const float* __restrict__ cb, bf16* __restrict__ xbc) {
  int ch = blockIdx.x*256 + threadIdx.x;
  if (ch >= CONVDIM) return;
  int bl = blockIdx.y;
  int b = bl >> 12, l = bl & 4095;
  float acc = cb[ch];
  #pragma unroll
  for (int k=0;k<KC;k++) {
    int lk = l - 3 + k;
    if (lk >= 0) acc = fmaf(cw[ch*KC+k], bf2f(xpre[((size_t)(b*L_)+lk)*CONVDIM + ch]), acc);
  }
  xbc[(size_t)bl*CONVDIM + ch] = f2bf(acc / (1.f + expf(-acc)));
}

// ---------------- selective scan: 128 blocks = (b, h, p-half) ----------------
__global__ __launch_bounds__(256) void k_scan(const bf16* __restrict__ xbc, const float* __restrict__ dtv,
                      const float* __restrict__ dAv, bf16* __restrict__ ys) {
  int blk = blockIdx.x;
  int ph = blk & 1, h = (blk>>1)&7, b = blk>>4;
  int tid = threadIdx.x;
  int lp = tid >> 3, ng = tid & 7;   // 32 p-rows x 8 n-groups
  int p = ph*32 + lp;
  int nb = ng*16;
  int hoff = h*HD + ph*32;
  float s[16];
  #pragma unroll
  for (int j=0;j<16;j++) s[j]=0.f;
  __shared__ float shBC[256];
  __shared__ float shX[32];
  const bf16* xbase = xbc + (size_t)b*L_*CONVDIM;
  const float* dtb = dtv + (size_t)b*L_*NH + h;
  const float* dab = dAv + (size_t)b*L_*NH + h;
  bf16* yb = ys + (size_t)b*L_*DI + h*HD + p;

  auto loadrow = [&](int t, float& vbc, float& vx, float& vdt, float& vda) {
    const bf16* row = xbase + (size_t)t*CONVDIM;
    vbc = bf2f(row[DI + tid]);
    vx  = (tid < 32) ? bf2f(row[hoff + tid]) : 0.f;
    vdt = dtb[(size_t)t*NH];
    vda = dab[(size_t)t*NH];
  };
  auto stage = [&](float vbc, float vx) {
    __syncthreads();
    shBC[tid] = vbc;
    if (tid < 32) shX[tid] = vx;
    __syncthreads();
  };
  auto math = [&](int t, float cdt, float cda) {
    float a = cdt * shX[lp];
    float acc = 0.f;
    #pragma unroll
    for (int j=0;j<16;j++) {
      s[j] = fmaf(s[j], cda, a*shBC[nb+j]);
      acc = fmaf(s[j], shBC[128+nb+j], acc);
    }
    acc += __shfl_xor(acc,1);
    acc += __shfl_xor(acc,2);
    acc += __shfl_xor(acc,4);
    if (ng==0) yb[(size_t)t*DI] = f2bf(acc);
  };

  float a_bc,a_x,a_dt,a_da, b_bc,b_x,b_dt,b_da;
  loadrow(0, a_bc,a_x,a_dt,a_da);
  loadrow(1, b_bc,b_x,b_dt,b_da);
  for (int t=0; t<L_; t+=2) {
    stage(a_bc, a_x);
    float cdt = a_dt, cda = a_da;
    if (t+2 < L_) loadrow(t+2, a_bc,a_x,a_dt,a_da);
    math(t, cdt, cda);
    stage(b_bc, b_x);
    cdt = b_dt; cda = b_da;
    if (t+3 < L_) loadrow(t+3, b_bc,b_x,b_dt,b_da);
    math(t+1, cdt, cda);
  }
}

// ---------------- y = (ys + D*xh)*silu(z), RMSNorm*w, in place (bf16) ----------------
__global__ __launch_bounds__(256) void k_combine(bf16* __restrict__ ys, const bf16* __restrict__ xbc,
                         const bf16* __restrict__ z, const float* __restrict__ Dp,
                         const float* __restrict__ nw) {
  int bl = blockIdx.x;
  int tid = threadIdx.x;
  bf16* yrow = ys + (size_t)bl*DI;
  const bf16* xrow = xbc + (size_t)bl*CONVDIM;
  const bf16* zrow = z + (size_t)bl*DI;
  float v[2]; float ss = 0.f;
  #pragma unroll
  for (int i=0;i<2;i++) {
    int d = tid + i*256;
    float xh = bf2f(xrow[d]);
    float y = bf2f(yrow[d]) + Dp[d>>6]*xh;
    float zv = bf2f(zrow[d]);
    y *= zv / (1.f + expf(-zv));
    v[i] = y; ss += y*y;
  }
  #pragma unroll
  for (int off=1; off<64; off<<=1) ss += __shfl_xor(ss, off);
  __shared__ float sb[4];
  if ((tid&63)==0) sb[tid>>6]=ss;
  __syncthreads();
  float total = sb[0]+sb[1]+sb[2]+sb[3];
  float scale = rsqrtf(total * (1.f/512.f) + 1e-5f);
  #pragma unroll
  for (int i=0;i<2;i++) {
    int d = tid + i*256;
    yrow[d] = f2bf(v[i]*scale*nw[d]);
  }
}

extern "C" void kernel_launch(void* const* d_in, const int* in_sizes, int n_in,
                              void* d_out, int out_size, void* d_ws, size_t ws_size,
                              hipStream_t stream) {
  const float* x         = (const float*)d_in[0];
  const float* conv_w    = (const float*)d_in[1];
  const float* conv_b    = (const float*)d_in[2];
  const float* bn_gamma  = (const float*)d_in[3];
  const float* bn_beta   = (const float*)d_in[4];
  const float* patch_w   = (const float*)d_in[5];
  const float* patch_b   = (const float*)d_in[6];
  const float* in_proj_w = (const float*)d_in[7];
  const float* conv1d_w  = (const float*)d_in[8];
  const float* conv1d_b  = (const float*)d_in[9];
  const float* dt_bias   = (const float*)d_in[10];
  const float* A_log     = (const float*)d_in[11];
  const float* Dp        = (const float*)d_in[12];
  const float* norm_w    = (const float*)d_in[13];
  const float* out_proj_w= (const float*)d_in[14];
  const float* final_w   = (const float*)d_in[15];
  const float* final_b   = (const float*)d_in[16];
  float* out = (float*)d_out;

  // workspace layout (byte offsets); aggressive aliasing of time-disjoint buffers
  char* Wb = (char*)d_ws;
  float* h_buf = (float*)(Wb + 0);              //  8 MB f32, dead after k_patch
  bf16*  xpost = (bf16*)(Wb + 0);               // 48 MB bf16, written at conv1d (after h_buf dead)
  bf16*  tok   = (bf16*)(Wb + 50331648);        // 16 MB bf16, live until gemm<1>
  bf16*  zbuf  = (bf16*)(Wb + 67108864);        // 32 MB bf16, dead after combine
  float* y2    = (float*)(Wb + 67108864);       // 32 MB f32, written at gemm<1> (aliases zbuf)
  bf16*  xpre  = (bf16*)(Wb + 100663296);       // 48 MB bf16, dead after conv1d
  bf16*  ysb   = (bf16*)(Wb + 100663296);       // 32 MB bf16, written at scan (aliases xpre)
  float* dtv   = (float*)(Wb + 150994944);      //  1 MB
  float* dAv   = (float*)(Wb + 152043520);      //  1 MB
  float* stats = (float*)(Wb + 153092096);      //  256 B
  const size_t NEED = 153092352;
  if (ws_size < NEED) {
    // graceful degrade: zero output instead of faulting on OOB workspace
    hipMemsetAsync(d_out, 0, (size_t)out_size*sizeof(float), stream);
    return;
  }

  k_conv1<<<dim3((B_*CMID*HMID*WMID)/256), dim3(256), 0, stream>>>(x, conv_w, conv_b, h_buf);
  k_bnstats<<<dim3(16), dim3(256), 0, stream>>>(h_buf, stats);
  k_bngelu<<<dim3((B_*CMID*HMID*WMID)/256), dim3(256), 0, stream>>>(h_buf, stats, bn_gamma, bn_beta);
  k_patch<<<dim3(MTOK), dim3(256), 0, stream>>>(h_buf, patch_w, patch_b, tok);
  k_gemm<0, bf16><<<dim3(21,512), dim3(256), 0, stream>>>(tok, in_proj_w, MTOK, PROJ, DM,
      zbuf, xpre, nullptr, nullptr, nullptr, dt_bias, A_log, dtv, dAv);
  k_conv1d<<<dim3(3, MTOK), dim3(256), 0, stream>>>(xpre, conv1d_w, conv1d_b, xpost);
  k_scan<<<dim3(128), dim3(256), 0, stream>>>(xpost, dtv, dAv, ysb);
  k_combine<<<dim3(MTOK), dim3(256), 0, stream>>>(ysb, xpost, zbuf, Dp, norm_w);
  k_gemm<1, bf16><<<dim3(4,512), dim3(256), 0, stream>>>(ysb, out_proj_w, MTOK, DM, DI,
      nullptr, nullptr, y2, tok, nullptr, nullptr, nullptr, nullptr, nullptr);
  k_gemm<2, float><<<dim3(1,512), dim3(256), 0, stream>>>(y2, final_w, MTOK, 64, DM,
      nullptr, nullptr, out, nullptr, final_b, nullptr, nullptr, nullptr, nullptr);
}

// Round 3
// 1432.334 us; speedup vs baseline: 2.5729x; 2.5729x over previous
//
#include <hip/hip_runtime.h>
#include <math.h>

#define B_  8
#define CIN 3
#define HIN 256
#define WIN 256
#define CMID 16
#define HMID 128
#define WMID 128
#define DM 256
#define L_ 4096
#define DI 512
#define NH 8
#define HD 64
#define NS 128
#define KC 4
#define CONVDIM 768
#define PROJ 1288
#define MTOK (B_*L_)
#define QCH 256          // chunk length
#define NCH 16           // number of chunks

typedef unsigned short bf16;

__device__ inline float bf2f(bf16 u) { return __uint_as_float(((unsigned int)u) << 16); }
__device__ inline bf16 f2bf(float f) {
  unsigned int x = __float_as_uint(f);
  return (bf16)((x + 0x7fffu + ((x >> 16) & 1u)) >> 16);
}
__device__ inline unsigned int pack2bf(float a, float b) {
  return (unsigned int)f2bf(a) | ((unsigned int)f2bf(b) << 16);
}

__device__ inline float4 ldA4(const float* p) { return *(const float4*)p; }
__device__ inline float4 ldA4(const bf16* p) {
  ushort4 u = *(const ushort4*)p;
  return make_float4(bf2f(u.x), bf2f(u.y), bf2f(u.z), bf2f(u.w));
}

// ---------------- conv 3x3 stride 2 pad 1 ----------------
__global__ void k_conv1(const float* __restrict__ x, const float* __restrict__ w,
                        const float* __restrict__ bias, float* __restrict__ out) {
  int idx = blockIdx.x*256 + threadIdx.x;
  if (idx >= B_*CMID*HMID*WMID) return;
  int xo = idx & 127, yo = (idx>>7)&127, co = (idx>>14)&15, b = idx>>18;
  float acc = bias[co];
  const float* xb = x + (size_t)b*CIN*HIN*WIN;
  const float* wc = w + co*CIN*9;
  #pragma unroll
  for (int ci=0; ci<CIN; ci++)
    #pragma unroll
    for (int ky=0; ky<3; ky++) {
      int yi = 2*yo - 1 + ky;
      if (yi < 0 || yi >= HIN) continue;
      #pragma unroll
      for (int kx=0; kx<3; kx++) {
        int xi = 2*xo - 1 + kx;
        if (xi < 0 || xi >= WIN) continue;
        acc += xb[(ci*HIN + yi)*WIN + xi] * wc[(ci*3+ky)*3+kx];
      }
    }
  out[idx] = acc;
}

// ---------------- batchnorm stats ----------------
__global__ void k_bnstats(const float* __restrict__ h, float* __restrict__ stats) {
  int c = blockIdx.x;
  int tid = threadIdx.x;
  const int NPC = B_*HMID*WMID;
  float s=0.f, s2=0.f;
  for (int i=tid; i<NPC; i+=256) {
    int b = i >> 14;
    int sp = i & 16383;
    float v = h[((size_t)(b*CMID + c))*16384 + sp];
    s += v; s2 += v*v;
  }
  #pragma unroll
  for (int off=1; off<64; off<<=1) { s += __shfl_xor(s, off); s2 += __shfl_xor(s2, off); }
  __shared__ float sb[2][4];
  int wv = tid>>6;
  if ((tid&63)==0) { sb[0][wv]=s; sb[1][wv]=s2; }
  __syncthreads();
  if (tid==0) {
    float S  = sb[0][0]+sb[0][1]+sb[0][2]+sb[0][3];
    float S2 = sb[1][0]+sb[1][1]+sb[1][2]+sb[1][3];
    float mean = S / (float)NPC;
    float var  = S2 / (float)NPC - mean*mean;
    stats[c]      = mean;
    stats[16 + c] = rsqrtf(var + 1e-5f);
  }
}

// ---------------- BN apply + exact GELU ----------------
__global__ void k_bngelu(float* __restrict__ h, const float* __restrict__ stats,
                         const float* __restrict__ gamma, const float* __restrict__ beta) {
  int idx = blockIdx.x*256 + threadIdx.x;
  if (idx >= B_*CMID*HMID*WMID) return;
  int c = (idx>>14)&15;
  float v = (h[idx] - stats[c]) * stats[16+c] * gamma[c] + beta[c];
  h[idx] = 0.5f * v * (1.f + erff(v * 0.70710678118654752f));
}

// ---------------- patch conv 2x2 s2 + bias + sincos -> tok (bf16) ----------------
__global__ __launch_bounds__(256) void k_patch(const float* __restrict__ h, const float* __restrict__ pw,
                       const float* __restrict__ pb, bf16* __restrict__ tok) {
  int bg = blockIdx.x;
  int b = bg >> 12, g = bg & 4095;
  int gy = g >> 6, gx = g & 63;
  __shared__ float sh[64];
  int tid = threadIdx.x;
  if (tid < 64) {
    int ci = tid >> 2, p = (tid>>1)&1, q = tid&1;
    sh[tid] = h[((size_t)(b*CMID+ci)*HMID + (2*gy+p))*WMID + (2*gx+q)];
  }
  __syncthreads();
  int d = tid;
  float acc = pb[d];
  const float* wr = pw + d*64;
  #pragma unroll 8
  for (int j=0;j<64;j++) acc += sh[j]*wr[j];
  int i = d & 63;
  float gv = (d < 128) ? (float)gx : (float)gy;
  float omega = expf(-(float)i * (9.210340371976184f/64.f));
  float ph = gv * omega;
  float pos = (d & 64) ? cosf(ph) : sinf(ph);
  tok[(size_t)bg*DM + d] = f2bf(acc + pos);
}

// ---------------- f32-accum GEMM: C[m,n] = sum_k A[m,k]*Bw[n,k] ----------------
template<int EPI, typename TA>
__global__ __launch_bounds__(256) void k_gemm(
    const TA* __restrict__ A, const float* __restrict__ Bw,
    int M, int N, int K,
    bf16* __restrict__ o_z, bf16* __restrict__ o_x,
    float* __restrict__ o_f,
    const bf16* __restrict__ res_bf,
    const float* __restrict__ bias,
    const float* __restrict__ dt_bias, const float* __restrict__ A_log,
    float* __restrict__ dtv, float* __restrict__ dAv) {
  __shared__ __align__(16) float As[16][64];
  __shared__ __align__(16) float Bs[16][64];
  int tid = threadIdx.x;
  int tx = tid & 15, ty = tid >> 4;
  int m0 = blockIdx.y*64, n0 = blockIdx.x*64;
  float acc[4][4] = {{0.f}};
  for (int k0=0; k0<K; k0+=16) {
    int r = tid >> 2;
    int kq = (tid & 3) << 2;
    {
      float4 v = ldA4(A + (size_t)(m0+r)*K + k0 + kq);
      As[kq+0][r]=v.x; As[kq+1][r]=v.y; As[kq+2][r]=v.z; As[kq+3][r]=v.w;
    }
    {
      int n = n0 + r;
      float4 v = make_float4(0.f,0.f,0.f,0.f);
      if (n < N) v = *(const float4*)(Bw + (size_t)n*K + k0 + kq);
      Bs[kq+0][r]=v.x; Bs[kq+1][r]=v.y; Bs[kq+2][r]=v.z; Bs[kq+3][r]=v.w;
    }
    __syncthreads();
    #pragma unroll
    for (int k=0;k<16;k++) {
      float4 a  = *(const float4*)&As[k][ty*4];
      float4 bb = *(const float4*)&Bs[k][tx*4];
      float av[4] = {a.x,a.y,a.z,a.w};
      float bv[4] = {bb.x,bb.y,bb.z,bb.w};
      #pragma unroll
      for (int i=0;i<4;i++)
        #pragma unroll
        for (int j=0;j<4;j++)
          acc[i][j] = fmaf(av[i], bv[j], acc[i][j]);
    }
    __syncthreads();
  }
  #pragma unroll
  for (int i=0;i<4;i++) {
    int m = m0 + ty*4 + i;
    #pragma unroll
    for (int j=0;j<4;j++) {
      int n = n0 + tx*4 + j;
      float v = acc[i][j];
      if (EPI == 0) {
        if (n < DI) {
          o_z[(size_t)m*DI + n] = f2bf(v);
        } else if (n < DI + CONVDIM) {
          o_x[(size_t)m*CONVDIM + (n - DI)] = f2bf(v);
        } else if (n < PROJ) {
          int hh = n - (DI + CONVDIM);
          float xv = v + dt_bias[hh];
          float dt = (xv > 20.f) ? xv : log1pf(expf(xv));
          dtv[(size_t)m*NH + hh] = dt;
          dAv[(size_t)m*NH + hh] = expf(-expf(A_log[hh]) * dt);
        }
      } else if (EPI == 1) {
        o_f[(size_t)m*N + n] = v + bf2f(res_bf[(size_t)m*N + n]);
      } else {
        float vv = v + bias[n];
        int b = m >> 12, g = m & 4095;
        int gy = g >> 6, gx = g & 63;
        int p = n >> 5, q = (n>>4)&1, c = n & 15;
        o_f[(((size_t)(b*CMID+c))*HMID + 2*gy+p)*WMID + (2*gx+q)] = vv;
      }
    }
  }
}

// ---------------- causal depthwise conv1d (KC=4) + bias + silu ----------------
__global__ void k_conv1d(const bf16* __restrict__ xpre, const float* __restrict__ cw,
                         const float* __restrict__ cb, bf16* __restrict__ xbc) {
  int ch = blockIdx.x*256 + threadIdx.x;
  if (ch >= CONVDIM) return;
  int bl = blockIdx.y;
  int b = bl >> 12, l = bl & 4095;
  float acc = cb[ch];
  #pragma unroll
  for (int k=0;k<KC;k++) {
    int lk = l - 3 + k;
    if (lk >= 0) acc = fmaf(cw[ch*KC+k], bf2f(xpre[((size_t)(b*L_)+lk)*CONVDIM + ch]), acc);
  }
  xbc[(size_t)bl*CONVDIM + ch] = f2bf(acc / (1.f + expf(-acc)));
}

// ================= chunked selective scan =================
// pass 1: per (b,h,chunk) scan from zero state; write intra-chunk y and final state T_c.
// thread layout: 128 threads = 4 n-quarters (half=tid&3, n0=half*32) x 32 p-pairs (p0=2*(tid>>2)).
// LDS B/C layout: word(t,bc,n) = t*288 + bc*144 + (n>>5)*36 + (n&31)  (conflict-free, 16B-aligned)
__global__ __launch_bounds__(128) void k_scan1(const bf16* __restrict__ xbc,
    const float* __restrict__ dtv, const float* __restrict__ dAv,
    bf16* __restrict__ ys, bf16* __restrict__ Sst) {
  int blk = blockIdx.x;
  int c = blk & (NCH-1), h = (blk>>4)&7, b = blk>>7;
  int tid = threadIdx.x;
  int half = tid & 3;
  int p0 = (tid>>2)*2;
  __shared__ __align__(16) float sBC[8*288];
  __shared__ __align__(16) float sX[8*64];
  __shared__ float sDT[16];
  float s0[32], s1[32];
  #pragma unroll
  for (int j=0;j<32;j++){ s0[j]=0.f; s1[j]=0.f; }
  size_t rowbase = (size_t)b*L_ + (size_t)c*QCH;

  for (int nb=0; nb<QCH/8; nb++){
    size_t bl0 = rowbase + nb*8;
    __syncthreads();
    {
      int t = tid>>4, seg = tid&15;
      const bf16* src = xbc + (bl0+t)*CONVDIM + DI + seg*16;
      uint4 u0 = *(const uint4*)src;
      uint4 u1 = *(const uint4*)(src+8);
      int n_abs = seg*16;
      float* w = &sBC[t*288 + (n_abs>>7)*144 + ((n_abs&127)>>5)*36 + (n_abs&31)];
      unsigned int uu[8] = {u0.x,u0.y,u0.z,u0.w,u1.x,u1.y,u1.z,u1.w};
      #pragma unroll
      for (int k=0;k<8;k++){
        w[2*k]   = __uint_as_float(uu[k]<<16);
        w[2*k+1] = __uint_as_float(uu[k]&0xffff0000u);
      }
      int col = (tid&15)*4;
      const bf16* xs = xbc + (bl0+t)*CONVDIM + h*HD + col;
      ushort4 xu = *(const ushort4*)xs;
      float* wx = &sX[t*64+col];
      wx[0]=bf2f(xu.x); wx[1]=bf2f(xu.y); wx[2]=bf2f(xu.z); wx[3]=bf2f(xu.w);
      if (tid < 8){
        sDT[tid*2]   = dtv[(bl0+tid)*NH + h];
        sDT[tid*2+1] = dAv[(bl0+tid)*NH + h];
      }
    }
    __syncthreads();
    #pragma unroll 2
    for (int t=0;t<8;t++){
      float dtt = sDT[t*2], da = sDT[t*2+1];
      float2 xv = *(const float2*)&sX[t*64+p0];
      float a0 = dtt*xv.x, a1 = dtt*xv.y;
      float y0=0.f, y1=0.f;
      const float* bb = &sBC[t*288 + half*36];
      const float* cb = bb + 144;
      #pragma unroll
      for (int g=0; g<8; g++){
        float4 Bv = *(const float4*)(bb + g*4);
        float4 Cv = *(const float4*)(cb + g*4);
        s0[g*4+0]=fmaf(s0[g*4+0],da,a0*Bv.x); y0=fmaf(s0[g*4+0],Cv.x,y0);
        s1[g*4+0]=fmaf(s1[g*4+0],da,a1*Bv.x); y1=fmaf(s1[g*4+0],Cv.x,y1);
        s0[g*4+1]=fmaf(s0[g*4+1],da,a0*Bv.y); y0=fmaf(s0[g*4+1],Cv.y,y0);
        s1[g*4+1]=fmaf(s1[g*4+1],da,a1*Bv.y); y1=fmaf(s1[g*4+1],Cv.y,y1);
        s0[g*4+2]=fmaf(s0[g*4+2],da,a0*Bv.z); y0=fmaf(s0[g*4+2],Cv.z,y0);
        s1[g*4+2]=fmaf(s1[g*4+2],da,a1*Bv.z); y1=fmaf(s1[g*4+2],Cv.z,y1);
        s0[g*4+3]=fmaf(s0[g*4+3],da,a0*Bv.w); y0=fmaf(s0[g*4+3],Cv.w,y0);
        s1[g*4+3]=fmaf(s1[g*4+3],da,a1*Bv.w); y1=fmaf(s1[g*4+3],Cv.w,y1);
      }
      y0 += __shfl_xor(y0,1); y0 += __shfl_xor(y0,2);
      y1 += __shfl_xor(y1,1); y1 += __shfl_xor(y1,2);
      if (half==0){
        *(unsigned int*)(ys + (bl0+t)*DI + h*HD + p0) = pack2bf(y0,y1);
      }
    }
  }
  size_t sb = (((size_t)(b*NH+h))*NCH + c)*8192;
  unsigned int* dp0 = (unsigned int*)(Sst + sb + (size_t)p0*128 + half*32);
  unsigned int* dp1 = (unsigned int*)(Sst + sb + (size_t)(p0+1)*128 + half*32);
  #pragma unroll
  for (int k=0;k<16;k++){
    dp0[k] = pack2bf(s0[2*k], s0[2*k+1]);
    dp1[k] = pack2bf(s1[2*k], s1[2*k+1]);
  }
}

// pass 2: prefix-combine chunk states in place: T_c -> I_c (incoming state of chunk c).
// I_0 = 0; I_{c+1} = T_c + P_c * I_c,  P_c = prod dA over chunk c.
__global__ __launch_bounds__(256) void k_scan2(bf16* __restrict__ Sst, const float* __restrict__ dAv) {
  int blk = blockIdx.x;
  int bh = blk>>2, q = blk&3;
  int b = bh>>3, h = bh&7;
  int tid = threadIdx.x;
  __shared__ float sP[NCH];
  {
    int c = tid>>4, seg = tid&15;
    float prod = 1.f;
    size_t base = ((size_t)b*L_ + c*QCH + seg*16)*NH + h;
    #pragma unroll
    for (int k=0;k<16;k++) prod *= dAv[base + (size_t)k*NH];
    prod *= __shfl_xor(prod, 1); prod *= __shfl_xor(prod, 2);
    prod *= __shfl_xor(prod, 4); prod *= __shfl_xor(prod, 8);
    if (seg==0) sP[c] = prod;
  }
  __syncthreads();
  int e0 = q*2048 + tid*8;
  float acc[8];
  #pragma unroll
  for (int j=0;j<8;j++) acc[j]=0.f;
  size_t sbase = (size_t)bh*NCH*8192 + e0;
  for (int c=0;c<NCH;c++){
    bf16* ptr = Sst + sbase + (size_t)c*8192;
    uint4 u = *(const uint4*)ptr;
    unsigned int uu[4] = {u.x,u.y,u.z,u.w};
    float tv[8];
    #pragma unroll
    for (int k=0;k<4;k++){
      tv[2*k]   = __uint_as_float(uu[k]<<16);
      tv[2*k+1] = __uint_as_float(uu[k]&0xffff0000u);
    }
    uint4 o;
    o.x = pack2bf(acc[0],acc[1]); o.y = pack2bf(acc[2],acc[3]);
    o.z = pack2bf(acc[4],acc[5]); o.w = pack2bf(acc[6],acc[7]);
    asm volatile("s_waitcnt vmcnt(0)" ::: "memory");  // ensure T_c load completed before in-place store
    *(uint4*)ptr = o;
    float P = sP[c];
    #pragma unroll
    for (int j=0;j<8;j++) acc[j] = tv[j] + P*acc[j];
  }
}

// pass 3: y[t,p] += scale_t * sum_n I_c[p,n] * C_t[n]; scale_t = inclusive cumprod of dA in chunk.
__global__ __launch_bounds__(128) void k_scan3(const bf16* __restrict__ xbc,
    const float* __restrict__ dAv, const bf16* __restrict__ Sst, bf16* __restrict__ ys) {
  int blk = blockIdx.x;
  int c = blk & (NCH-1), h=(blk>>4)&7, b=blk>>7;
  int tid = threadIdx.x;
  int half = tid&3, p0 = (tid>>2)*2;
  __shared__ __align__(16) float sC[8*144];
  __shared__ float sScale[QCH];
  __shared__ float sWT[2];
  int lane = tid & 63, w = tid>>6;
  size_t rowbase = (size_t)b*L_ + (size_t)c*QCH;
  {
    int t2 = tid*2;
    float a0v = dAv[(rowbase+t2)*NH + h];
    float a1v = dAv[(rowbase+t2+1)*NH + h];
    float pp = a0v*a1v;
    float inc = pp;
    #pragma unroll
    for (int off=1; off<64; off<<=1){
      float u = __shfl_up(inc, off);
      if (lane>=off) inc *= u;
    }
    if (lane==63) sWT[w] = inc;
    __syncthreads();
    if (w==1) inc *= sWT[0];
    float exc = __shfl_up(inc,1);
    if (lane==0) exc = (w==0) ? 1.f : sWT[0];
    sScale[t2]   = exc*a0v;
    sScale[t2+1] = exc*pp;
  }
  float I0[32], I1[32];
  size_t sb = (((size_t)(b*NH+h))*NCH + c)*8192;
  {
    const bf16* q0 = Sst + sb + (size_t)p0*128 + half*32;
    #pragma unroll
    for (int r=0;r<4;r++){
      uint4 u = *(const uint4*)(q0 + r*8);
      uint4 v = *(const uint4*)(q0 + 128 + r*8);
      unsigned int uu[4]={u.x,u.y,u.z,u.w}, vv[4]={v.x,v.y,v.z,v.w};
      #pragma unroll
      for (int k=0;k<4;k++){
        I0[r*8+2*k]   = __uint_as_float(uu[k]<<16);
        I0[r*8+2*k+1] = __uint_as_float(uu[k]&0xffff0000u);
        I1[r*8+2*k]   = __uint_as_float(vv[k]<<16);
        I1[r*8+2*k+1] = __uint_as_float(vv[k]&0xffff0000u);
      }
    }
  }
  for (int nb=0; nb<QCH/8; nb++){
    size_t bl0 = rowbase + nb*8;
    __syncthreads();
    {
      int t = tid>>4, seg = tid&15;
      const bf16* src = xbc + (bl0+t)*CONVDIM + (DI+NS) + seg*8;
      uint4 u = *(const uint4*)src;
      int n = seg*8;
      float* wp = &sC[t*144 + (n>>5)*36 + (n&31)];
      unsigned int uu[4]={u.x,u.y,u.z,u.w};
      #pragma unroll
      for (int k=0;k<4;k++){
        wp[2*k]   = __uint_as_float(uu[k]<<16);
        wp[2*k+1] = __uint_as_float(uu[k]&0xffff0000u);
      }
    }
    __syncthreads();
    #pragma unroll 2
    for (int t=0;t<8;t++){
      float sc = sScale[nb*8+t];
      const float* cb = &sC[t*144 + half*36];
      float y0=0.f, y1=0.f;
      #pragma unroll
      for (int g=0;g<8;g++){
        float4 Cv = *(const float4*)(cb+g*4);
        y0 = fmaf(I0[g*4+0],Cv.x,y0); y1 = fmaf(I1[g*4+0],Cv.x,y1);
        y0 = fmaf(I0[g*4+1],Cv.y,y0); y1 = fmaf(I1[g*4+1],Cv.y,y1);
        y0 = fmaf(I0[g*4+2],Cv.z,y0); y1 = fmaf(I1[g*4+2],Cv.z,y1);
        y0 = fmaf(I0[g*4+3],Cv.w,y0); y1 = fmaf(I1[g*4+3],Cv.w,y1);
      }
      y0 += __shfl_xor(y0,1); y0 += __shfl_xor(y0,2);
      y1 += __shfl_xor(y1,1); y1 += __shfl_xor(y1,2);
      if (half==0){
        unsigned int* yp = (unsigned int*)(ys + (bl0+t)*DI + h*HD + p0);
        unsigned int old = *yp;
        float o0 = bf2f((bf16)(old&0xffffu)) + sc*y0;
        float o1 = bf2f((bf16)(old>>16)) + sc*y1;
        *yp = pack2bf(o0,o1);
      }
    }
  }
}

// ---------------- y = (ys + D*xh)*silu(z), RMSNorm*w, in place (bf16) ----------------
__global__ __launch_bounds__(256) void k_combine(bf16* __restrict__ ys, const bf16* __restrict__ xbc,
                         const bf16* __restrict__ z, const float* __restrict__ Dp,
                         const float* __restrict__ nw) {
  int bl = blockIdx.x;
  int tid = threadIdx.x;
  bf16* yrow = ys + (size_t)bl*DI;
  const bf16* xrow = xbc + (size_t)bl*CONVDIM;
  const bf16* zrow = z + (size_t)bl*DI;
  float v[2]; float ss = 0.f;
  #pragma unroll
  for (int i=0;i<2;i++) {
    int d = tid + i*256;
    float xh = bf2f(xrow[d]);
    float y = bf2f(yrow[d]) + Dp[d>>6]*xh;
    float zv = bf2f(zrow[d]);
    y *= zv / (1.f + expf(-zv));
    v[i] = y; ss += y*y;
  }
  #pragma unroll
  for (int off=1; off<64; off<<=1) ss += __shfl_xor(ss, off);
  __shared__ float sb[4];
  if ((tid&63)==0) sb[tid>>6]=ss;
  __syncthreads();
  float total = sb[0]+sb[1]+sb[2]+sb[3];
  float scale = rsqrtf(total * (1.f/512.f) + 1e-5f);
  #pragma unroll
  for (int i=0;i<2;i++) {
    int d = tid + i*256;
    yrow[d] = f2bf(v[i]*scale*nw[d]);
  }
}

extern "C" void kernel_launch(void* const* d_in, const int* in_sizes, int n_in,
                              void* d_out, int out_size, void* d_ws, size_t ws_size,
                              hipStream_t stream) {
  const float* x         = (const float*)d_in[0];
  const float* conv_w    = (const float*)d_in[1];
  const float* conv_b    = (const float*)d_in[2];
  const float* bn_gamma  = (const float*)d_in[3];
  const float* bn_beta   = (const float*)d_in[4];
  const float* patch_w   = (const float*)d_in[5];
  const float* patch_b   = (const float*)d_in[6];
  const float* in_proj_w = (const float*)d_in[7];
  const float* conv1d_w  = (const float*)d_in[8];
  const float* conv1d_b  = (const float*)d_in[9];
  const float* dt_bias   = (const float*)d_in[10];
  const float* A_log     = (const float*)d_in[11];
  const float* Dp        = (const float*)d_in[12];
  const float* norm_w    = (const float*)d_in[13];
  const float* out_proj_w= (const float*)d_in[14];
  const float* final_w   = (const float*)d_in[15];
  const float* final_b   = (const float*)d_in[16];
  float* out = (float*)d_out;

  // workspace layout (byte offsets); aliasing of time-disjoint buffers
  char* Wb = (char*)d_ws;
  float* h_buf = (float*)(Wb + 0);              //  8 MB f32, dead after k_patch
  bf16*  xpost = (bf16*)(Wb + 0);               // 48 MB bf16, written at conv1d
  bf16*  tok   = (bf16*)(Wb + 50331648);        // 16 MB bf16, live until gemm<1>
  bf16*  zbuf  = (bf16*)(Wb + 67108864);        // 32 MB bf16, dead after combine
  float* y2    = (float*)(Wb + 67108864);       // 32 MB f32, written at gemm<1>
  bf16*  xpre  = (bf16*)(Wb + 100663296);       // 48 MB bf16, dead after conv1d
  bf16*  ysb   = (bf16*)(Wb + 100663296);       // 32 MB bf16, written by scan1 (over dead xpre)
  bf16*  Sst   = (bf16*)(Wb + 134217728);       // 16 MB bf16 chunk states (dead xpre tail)
  float* dtv   = (float*)(Wb + 150994944);      //  1 MB
  float* dAv   = (float*)(Wb + 152043520);      //  1 MB
  float* stats = (float*)(Wb + 153092096);      //  256 B
  const size_t NEED = 153092352;
  if (ws_size < NEED) {
    hipMemsetAsync(d_out, 0, (size_t)out_size*sizeof(float), stream);
    return;
  }

  k_conv1<<<dim3((B_*CMID*HMID*WMID)/256), dim3(256), 0, stream>>>(x, conv_w, conv_b, h_buf);
  k_bnstats<<<dim3(16), dim3(256), 0, stream>>>(h_buf, stats);
  k_bngelu<<<dim3((B_*CMID*HMID*WMID)/256), dim3(256), 0, stream>>>(h_buf, stats, bn_gamma, bn_beta);
  k_patch<<<dim3(MTOK), dim3(256), 0, stream>>>(h_buf, patch_w, patch_b, tok);
  k_gemm<0, bf16><<<dim3(21,512), dim3(256), 0, stream>>>(tok, in_proj_w, MTOK, PROJ, DM,
      zbuf, xpre, nullptr, nullptr, nullptr, dt_bias, A_log, dtv, dAv);
  k_conv1d<<<dim3(3, MTOK), dim3(256), 0, stream>>>(xpre, conv1d_w, conv1d_b, xpost);
  k_scan1<<<dim3(B_*NH*NCH), dim3(128), 0, stream>>>(xpost, dtv, dAv, ysb, Sst);
  k_scan2<<<dim3(B_*NH*4), dim3(256), 0, stream>>>(Sst, dAv);
  k_scan3<<<dim3(B_*NH*NCH), dim3(128), 0, stream>>>(xpost, dAv, Sst, ysb);
  k_combine<<<dim3(MTOK), dim3(256), 0, stream>>>(ysb, xpost, zbuf, Dp, norm_w);
  k_gemm<1, bf16><<<dim3(4,512), dim3(256), 0, stream>>>(ysb, out_proj_w, MTOK, DM, DI,
      nullptr, nullptr, y2, tok, nullptr, nullptr, nullptr, nullptr, nullptr);
  k_gemm<2, float><<<dim3(1,512), dim3(256), 0, stream>>>(y2, final_w, MTOK, 64, DM,
      nullptr, nullptr, out, nullptr, final_b, nullptr, nullptr, nullptr, nullptr);
}

// Round 4
// 1108.732 us; speedup vs baseline: 3.3239x; 1.2919x over previous
//
#include <hip/hip_runtime.h>
#include <math.h>

#define B_  8
#define CIN 3
#define HIN 256
#define WIN 256
#define CMID 16
#define HMID 128
#define WMID 128
#define DM 256
#define L_ 4096
#define DI 512
#define NH 8
#define HD 64
#define NS 128
#define KC 4
#define CONVDIM 768
#define PROJ 1288
#define NPADIN 1408
#define MTOK (B_*L_)
#define QCH 256          // chunk length
#define NCH 16           // number of chunks

typedef unsigned short bf16;
typedef __attribute__((ext_vector_type(8))) short bf16x8;
typedef __attribute__((ext_vector_type(4))) float f32x4;

__device__ inline float bf2f(bf16 u) { return __uint_as_float(((unsigned int)u) << 16); }
__device__ inline bf16 f2bf(float f) {
  unsigned int x = __float_as_uint(f);
  return (bf16)((x + 0x7fffu + ((x >> 16) & 1u)) >> 16);
}
__device__ inline unsigned int pack2bf(float a, float b) {
  return (unsigned int)f2bf(a) | ((unsigned int)f2bf(b) << 16);
}

__device__ inline float4 ldA4(const float* p) { return *(const float4*)p; }
__device__ inline float4 ldA4(const bf16* p) {
  ushort4 u = *(const ushort4*)p;
  return make_float4(bf2f(u.x), bf2f(u.y), bf2f(u.z), bf2f(u.w));
}

// ---------------- conv 3x3 stride 2 pad 1 ----------------
__global__ void k_conv1(const float* __restrict__ x, const float* __restrict__ w,
                        const float* __restrict__ bias, float* __restrict__ out) {
  int idx = blockIdx.x*256 + threadIdx.x;
  if (idx >= B_*CMID*HMID*WMID) return;
  int xo = idx & 127, yo = (idx>>7)&127, co = (idx>>14)&15, b = idx>>18;
  float acc = bias[co];
  const float* xb = x + (size_t)b*CIN*HIN*WIN;
  const float* wc = w + co*CIN*9;
  #pragma unroll
  for (int ci=0; ci<CIN; ci++)
    #pragma unroll
    for (int ky=0; ky<3; ky++) {
      int yi = 2*yo - 1 + ky;
      if (yi < 0 || yi >= HIN) continue;
      #pragma unroll
      for (int kx=0; kx<3; kx++) {
        int xi = 2*xo - 1 + kx;
        if (xi < 0 || xi >= WIN) continue;
        acc += xb[(ci*HIN + yi)*WIN + xi] * wc[(ci*3+ky)*3+kx];
      }
    }
  out[idx] = acc;
}

// ---------------- batchnorm stats ----------------
__global__ void k_bnstats(const float* __restrict__ h, float* __restrict__ stats) {
  int c = blockIdx.x;
  int tid = threadIdx.x;
  const int NPC = B_*HMID*WMID;
  float s=0.f, s2=0.f;
  for (int i=tid; i<NPC; i+=256) {
    int b = i >> 14;
    int sp = i & 16383;
    float v = h[((size_t)(b*CMID + c))*16384 + sp];
    s += v; s2 += v*v;
  }
  #pragma unroll
  for (int off=1; off<64; off<<=1) { s += __shfl_xor(s, off); s2 += __shfl_xor(s2, off); }
  __shared__ float sb[2][4];
  int wv = tid>>6;
  if ((tid&63)==0) { sb[0][wv]=s; sb[1][wv]=s2; }
  __syncthreads();
  if (tid==0) {
    float S  = sb[0][0]+sb[0][1]+sb[0][2]+sb[0][3];
    float S2 = sb[1][0]+sb[1][1]+sb[1][2]+sb[1][3];
    float mean = S / (float)NPC;
    float var  = S2 / (float)NPC - mean*mean;
    stats[c]      = mean;
    stats[16 + c] = rsqrtf(var + 1e-5f);
  }
}

// ---------------- BN apply + exact GELU ----------------
__global__ void k_bngelu(float* __restrict__ h, const float* __restrict__ stats,
                         const float* __restrict__ gamma, const float* __restrict__ beta) {
  int idx = blockIdx.x*256 + threadIdx.x;
  if (idx >= B_*CMID*HMID*WMID) return;
  int c = (idx>>14)&15;
  float v = (h[idx] - stats[c]) * stats[16+c] * gamma[c] + beta[c];
  h[idx] = 0.5f * v * (1.f + erff(v * 0.70710678118654752f));
}

// ---------------- patch conv 2x2 s2 + bias + sincos -> tok (bf16) ----------------
__global__ __launch_bounds__(256) void k_patch(const float* __restrict__ h, const float* __restrict__ pw,
                       const float* __restrict__ pb, bf16* __restrict__ tok) {
  int bg = blockIdx.x;
  int b = bg >> 12, g = bg & 4095;
  int gy = g >> 6, gx = g & 63;
  __shared__ float sh[64];
  int tid = threadIdx.x;
  if (tid < 64) {
    int ci = tid >> 2, p = (tid>>1)&1, q = tid&1;
    sh[tid] = h[((size_t)(b*CMID+ci)*HMID + (2*gy+p))*WMID + (2*gx+q)];
  }
  __syncthreads();
  int d = tid;
  float acc = pb[d];
  const float* wr = pw + d*64;
  #pragma unroll 8
  for (int j=0;j<64;j++) acc += sh[j]*wr[j];
  int i = d & 63;
  float gv = (d < 128) ? (float)gx : (float)gy;
  float omega = expf(-(float)i * (9.210340371976184f/64.f));
  float ph = gv * omega;
  float pos = (d & 64) ? cosf(ph) : sinf(ph);
  tok[(size_t)bg*DM + d] = f2bf(acc + pos);
}

// ---------------- weight f32 -> bf16 (with zero-padding to Npad rows) ----------------
__global__ void k_cvtw(const float* __restrict__ src, bf16* __restrict__ dst,
                       int N, int kshift, int total) {
  int idx = blockIdx.x*256 + threadIdx.x;
  if (idx >= total) return;
  int n = idx >> kshift;
  dst[idx] = (n < N) ? f2bf(src[idx]) : (bf16)0;
}

// ---------------- MFMA bf16 GEMM, 128x128 tile, C[m,n]=sum_k A[m,k]*Bw[n,k] ----------------
// LDS kg-swizzle: element (row, kg*8..) stored at byte row*64 + (kg ^ (row&3))*16.
// Staged via global_load_lds (linear dest) with pre-swizzled global source; read with same XOR.
// EPI 0: route cols -> z / xpre / dt-chain.  EPI 1: o_y[m,n] = acc + res[m,n] (bf16).
template<int EPI>
__global__ __launch_bounds__(256) void k_mgemm(
    const bf16* __restrict__ A, const bf16* __restrict__ Bw, int K,
    bf16* __restrict__ o_z, bf16* __restrict__ o_x,
    bf16* __restrict__ o_y, const bf16* __restrict__ res,
    const float* __restrict__ dt_bias, const float* __restrict__ A_log,
    float* __restrict__ dtv, float* __restrict__ dAv) {
  __shared__ __align__(16) bf16 sA[2][128*32];
  __shared__ __align__(16) bf16 sB[2][128*32];
  int tid = threadIdx.x;
  int lane = tid & 63, wid = tid >> 6;
  int wr = wid >> 1, wc = wid & 1;
  int m0 = blockIdx.x*128, n0 = blockIdx.y*128;
  int nk = K >> 5;
  f32x4 acc[4][4];
  #pragma unroll
  for (int i=0;i<4;i++)
    #pragma unroll
    for (int j=0;j<4;j++)
      acc[i][j] = (f32x4){0.f,0.f,0.f,0.f};

  auto stage = [&](int buf, int ks){
    int kk = ks << 5;
    #pragma unroll
    for (int i=0;i<2;i++){
      int j = i*256 + tid;
      int row = j >> 2, cc = j & 3;
      int kg = cc ^ (row & 3);
      unsigned ldsoff = (unsigned)((i*256 + wid*64) * 16);
      __builtin_amdgcn_global_load_lds(
        (const __attribute__((address_space(1))) void*)(A + (size_t)(m0+row)*K + kk + kg*8),
        (__attribute__((address_space(3))) void*)((char*)&sA[buf][0] + ldsoff), 16, 0, 0);
      __builtin_amdgcn_global_load_lds(
        (const __attribute__((address_space(1))) void*)(Bw + (size_t)(n0+row)*K + kk + kg*8),
        (__attribute__((address_space(3))) void*)((char*)&sB[buf][0] + ldsoff), 16, 0, 0);
    }
  };

  int r = lane & 15, q = lane >> 4;
  int kgo = (q ^ (r & 3)) << 3;   // swizzled element offset within row

  stage(0, 0);
  for (int ks=0; ks<nk; ++ks){
    int cur = ks & 1;
    __syncthreads();                    // drains vmcnt -> buf[cur] ready; guards buf reuse
    if (ks+1 < nk) stage(cur^1, ks+1);  // prefetch overlaps compute
    bf16x8 af[4], bfv[4];
    #pragma unroll
    for (int mf=0;mf<4;mf++){
      int rowm = wr*64 + mf*16 + r;
      af[mf] = *(const bf16x8*)&sA[cur][rowm*32 + kgo];
    }
    #pragma unroll
    for (int nf=0;nf<4;nf++){
      int rown = wc*64 + nf*16 + r;
      bfv[nf] = *(const bf16x8*)&sB[cur][rown*32 + kgo];
    }
    #pragma unroll
    for (int mf=0;mf<4;mf++)
      #pragma unroll
      for (int nf=0;nf<4;nf++)
        acc[mf][nf] = __builtin_amdgcn_mfma_f32_16x16x32_bf16(af[mf], bfv[nf], acc[mf][nf], 0, 0, 0);
  }

  // epilogue: C/D map col=lane&15, row=(lane>>4)*4+reg
  #pragma unroll
  for (int mf=0;mf<4;mf++){
    #pragma unroll
    for (int nf=0;nf<4;nf++){
      int n = n0 + wc*64 + nf*16 + r;
      int mbase = m0 + wr*64 + mf*16 + q*4;
      #pragma unroll
      for (int rr=0;rr<4;rr++){
        int m = mbase + rr;
        float val = acc[mf][nf][rr];
        if (EPI == 0){
          if (n < DI) {
            o_z[(size_t)m*DI + n] = f2bf(val);
          } else if (n < DI + CONVDIM) {
            o_x[(size_t)m*CONVDIM + (n - DI)] = f2bf(val);
          } else if (n < PROJ) {
            int hh = n - (DI + CONVDIM);
            float xv = val + dt_bias[hh];
            float dt = (xv > 20.f) ? xv : log1pf(expf(xv));
            dtv[(size_t)m*NH + hh] = dt;
            dAv[(size_t)m*NH + hh] = expf(-expf(A_log[hh]) * dt);
          }
        } else {
          o_y[(size_t)m*DM + n] = f2bf(val + bf2f(res[(size_t)m*DM + n]));
        }
      }
    }
  }
}

// ---------------- SIMT f32-accum GEMM (final layer only): EPI2 pixel-shuffle ----------------
template<int EPI, typename TA>
__global__ __launch_bounds__(256) void k_gemm(
    const TA* __restrict__ A, const float* __restrict__ Bw,
    int M, int N, int K,
    float* __restrict__ o_f, const float* __restrict__ bias) {
  __shared__ __align__(16) float As[16][64];
  __shared__ __align__(16) float Bs[16][64];
  int tid = threadIdx.x;
  int tx = tid & 15, ty = tid >> 4;
  int m0 = blockIdx.y*64, n0 = blockIdx.x*64;
  float acc[4][4] = {{0.f}};
  for (int k0=0; k0<K; k0+=16) {
    int rr = tid >> 2;
    int kq = (tid & 3) << 2;
    {
      float4 v = ldA4(A + (size_t)(m0+rr)*K + k0 + kq);
      As[kq+0][rr]=v.x; As[kq+1][rr]=v.y; As[kq+2][rr]=v.z; As[kq+3][rr]=v.w;
    }
    {
      int n = n0 + rr;
      float4 v = make_float4(0.f,0.f,0.f,0.f);
      if (n < N) v = *(const float4*)(Bw + (size_t)n*K + k0 + kq);
      Bs[kq+0][rr]=v.x; Bs[kq+1][rr]=v.y; Bs[kq+2][rr]=v.z; Bs[kq+3][rr]=v.w;
    }
    __syncthreads();
    #pragma unroll
    for (int k=0;k<16;k++) {
      float4 a  = *(const float4*)&As[k][ty*4];
      float4 bb = *(const float4*)&Bs[k][tx*4];
      float av[4] = {a.x,a.y,a.z,a.w};
      float bv[4] = {bb.x,bb.y,bb.z,bb.w};
      #pragma unroll
      for (int i=0;i<4;i++)
        #pragma unroll
        for (int j=0;j<4;j++)
          acc[i][j] = fmaf(av[i], bv[j], acc[i][j]);
    }
    __syncthreads();
  }
  #pragma unroll
  for (int i=0;i<4;i++) {
    int m = m0 + ty*4 + i;
    #pragma unroll
    for (int j=0;j<4;j++) {
      int n = n0 + tx*4 + j;
      if (n < N) {
        float vv = acc[i][j] + bias[n];
        int b = m >> 12, g = m & 4095;
        int gy = g >> 6, gx = g & 63;
        int p = n >> 5, qq = (n>>4)&1, c = n & 15;
        o_f[(((size_t)(b*CMID+c))*HMID + 2*gy+p)*WMID + (2*gx+qq)] = vv;
      }
    }
  }
}

// ---------------- causal depthwise conv1d (KC=4) + bias + silu ----------------
__global__ void k_conv1d(const bf16* __restrict__ xpre, const float* __restrict__ cw,
                         const float* __restrict__ cb, bf16* __restrict__ xbc) {
  int ch = blockIdx.x*256 + threadIdx.x;
  if (ch >= CONVDIM) return;
  int bl = blockIdx.y;
  int b = bl >> 12, l = bl & 4095;
  float acc = cb[ch];
  #pragma unroll
  for (int k=0;k<KC;k++) {
    int lk = l - 3 + k;
    if (lk >= 0) acc = fmaf(cw[ch*KC+k], bf2f(xpre[((size_t)(b*L_)+lk)*CONVDIM + ch]), acc);
  }
  xbc[(size_t)bl*CONVDIM + ch] = f2bf(acc / (1.f + expf(-acc)));
}

// ================= chunked selective scan =================
__global__ __launch_bounds__(128) void k_scan1(const bf16* __restrict__ xbc,
    const float* __restrict__ dtv, const float* __restrict__ dAv,
    bf16* __restrict__ ys, bf16* __restrict__ Sst) {
  int blk = blockIdx.x;
  int c = blk & (NCH-1), h = (blk>>4)&7, b = blk>>7;
  int tid = threadIdx.x;
  int half = tid & 3;
  int p0 = (tid>>2)*2;
  __shared__ __align__(16) float sBC[8*288];
  __shared__ __align__(16) float sX[8*64];
  __shared__ float sDT[16];
  float s0[32], s1[32];
  #pragma unroll
  for (int j=0;j<32;j++){ s0[j]=0.f; s1[j]=0.f; }
  size_t rowbase = (size_t)b*L_ + (size_t)c*QCH;

  for (int nb=0; nb<QCH/8; nb++){
    size_t bl0 = rowbase + nb*8;
    __syncthreads();
    {
      int t = tid>>4, seg = tid&15;
      const bf16* src = xbc + (bl0+t)*CONVDIM + DI + seg*16;
      uint4 u0 = *(const uint4*)src;
      uint4 u1 = *(const uint4*)(src+8);
      int n_abs = seg*16;
      float* w = &sBC[t*288 + (n_abs>>7)*144 + ((n_abs&127)>>5)*36 + (n_abs&31)];
      unsigned int uu[8] = {u0.x,u0.y,u0.z,u0.w,u1.x,u1.y,u1.z,u1.w};
      #pragma unroll
      for (int k=0;k<8;k++){
        w[2*k]   = __uint_as_float(uu[k]<<16);
        w[2*k+1] = __uint_as_float(uu[k]&0xffff0000u);
      }
      int col = (tid&15)*4;
      const bf16* xs = xbc + (bl0+t)*CONVDIM + h*HD + col;
      ushort4 xu = *(const ushort4*)xs;
      float* wx = &sX[t*64+col];
      wx[0]=bf2f(xu.x); wx[1]=bf2f(xu.y); wx[2]=bf2f(xu.z); wx[3]=bf2f(xu.w);
      if (tid < 8){
        sDT[tid*2]   = dtv[(bl0+tid)*NH + h];
        sDT[tid*2+1] = dAv[(bl0+tid)*NH + h];
      }
    }
    __syncthreads();
    #pragma unroll 2
    for (int t=0;t<8;t++){
      float dtt = sDT[t*2], da = sDT[t*2+1];
      float2 xv = *(const float2*)&sX[t*64+p0];
      float a0 = dtt*xv.x, a1 = dtt*xv.y;
      float y0=0.f, y1=0.f;
      const float* bb = &sBC[t*288 + half*36];
      const float* cb = bb + 144;
      #pragma unroll
      for (int g=0; g<8; g++){
        float4 Bv = *(const float4*)(bb + g*4);
        float4 Cv = *(const float4*)(cb + g*4);
        s0[g*4+0]=fmaf(s0[g*4+0],da,a0*Bv.x); y0=fmaf(s0[g*4+0],Cv.x,y0);
        s1[g*4+0]=fmaf(s1[g*4+0],da,a1*Bv.x); y1=fmaf(s1[g*4+0],Cv.x,y1);
        s0[g*4+1]=fmaf(s0[g*4+1],da,a0*Bv.y); y0=fmaf(s0[g*4+1],Cv.y,y0);
        s1[g*4+1]=fmaf(s1[g*4+1],da,a1*Bv.y); y1=fmaf(s1[g*4+1],Cv.y,y1);
        s0[g*4+2]=fmaf(s0[g*4+2],da,a0*Bv.z); y0=fmaf(s0[g*4+2],Cv.z,y0);
        s1[g*4+2]=fmaf(s1[g*4+2],da,a1*Bv.z); y1=fmaf(s1[g*4+2],Cv.z,y1);
        s0[g*4+3]=fmaf(s0[g*4+3],da,a0*Bv.w); y0=fmaf(s0[g*4+3],Cv.w,y0);
        s1[g*4+3]=fmaf(s1[g*4+3],da,a1*Bv.w); y1=fmaf(s1[g*4+3],Cv.w,y1);
      }
      y0 += __shfl_xor(y0,1); y0 += __shfl_xor(y0,2);
      y1 += __shfl_xor(y1,1); y1 += __shfl_xor(y1,2);
      if (half==0){
        *(unsigned int*)(ys + (bl0+t)*DI + h*HD + p0) = pack2bf(y0,y1);
      }
    }
  }
  size_t sb = (((size_t)(b*NH+h))*NCH + c)*8192;
  unsigned int* dp0 = (unsigned int*)(Sst + sb + (size_t)p0*128 + half*32);
  unsigned int* dp1 = (unsigned int*)(Sst + sb + (size_t)(p0+1)*128 + half*32);
  #pragma unroll
  for (int k=0;k<16;k++){
    dp0[k] = pack2bf(s0[2*k], s0[2*k+1]);
    dp1[k] = pack2bf(s1[2*k], s1[2*k+1]);
  }
}

__global__ __launch_bounds__(256) void k_scan2(bf16* __restrict__ Sst, const float* __restrict__ dAv) {
  int blk = blockIdx.x;
  int bh = blk>>2, q = blk&3;
  int b = bh>>3, h = bh&7;
  int tid = threadIdx.x;
  __shared__ float sP[NCH];
  {
    int c = tid>>4, seg = tid&15;
    float prod = 1.f;
    size_t base = ((size_t)b*L_ + c*QCH + seg*16)*NH + h;
    #pragma unroll
    for (int k=0;k<16;k++) prod *= dAv[base + (size_t)k*NH];
    prod *= __shfl_xor(prod, 1); prod *= __shfl_xor(prod, 2);
    prod *= __shfl_xor(prod, 4); prod *= __shfl_xor(prod, 8);
    if (seg==0) sP[c] = prod;
  }
  __syncthreads();
  int e0 = q*2048 + tid*8;
  float acc[8];
  #pragma unroll
  for (int j=0;j<8;j++) acc[j]=0.f;
  size_t sbase = (size_t)bh*NCH*8192 + e0;
  for (int c=0;c<NCH;c++){
    bf16* ptr = Sst + sbase + (size_t)c*8192;
    uint4 u = *(const uint4*)ptr;
    unsigned int uu[4] = {u.x,u.y,u.z,u.w};
    float tv[8];
    #pragma unroll
    for (int k=0;k<4;k++){
      tv[2*k]   = __uint_as_float(uu[k]<<16);
      tv[2*k+1] = __uint_as_float(uu[k]&0xffff0000u);
    }
    uint4 o;
    o.x = pack2bf(acc[0],acc[1]); o.y = pack2bf(acc[2],acc[3]);
    o.z = pack2bf(acc[4],acc[5]); o.w = pack2bf(acc[6],acc[7]);
    asm volatile("s_waitcnt vmcnt(0)" ::: "memory");
    *(uint4*)ptr = o;
    float P = sP[c];
    #pragma unroll
    for (int j=0;j<8;j++) acc[j] = tv[j] + P*acc[j];
  }
}

__global__ __launch_bounds__(128) void k_scan3(const bf16* __restrict__ xbc,
    const float* __restrict__ dAv, const bf16* __restrict__ Sst, bf16* __restrict__ ys) {
  int blk = blockIdx.x;
  int c = blk & (NCH-1), h=(blk>>4)&7, b=blk>>7;
  int tid = threadIdx.x;
  int half = tid&3, p0 = (tid>>2)*2;
  __shared__ __align__(16) float sC[8*144];
  __shared__ float sScale[QCH];
  __shared__ float sWT[2];
  int lane = tid & 63, w = tid>>6;
  size_t rowbase = (size_t)b*L_ + (size_t)c*QCH;
  {
    int t2 = tid*2;
    float a0v = dAv[(rowbase+t2)*NH + h];
    float a1v = dAv[(rowbase+t2+1)*NH + h];
    float pp = a0v*a1v;
    float inc = pp;
    #pragma unroll
    for (int off=1; off<64; off<<=1){
      float u = __shfl_up(inc, off);
      if (lane>=off) inc *= u;
    }
    if (lane==63) sWT[w] = inc;
    __syncthreads();
    if (w==1) inc *= sWT[0];
    float exc = __shfl_up(inc,1);
    if (lane==0) exc = (w==0) ? 1.f : sWT[0];
    sScale[t2]   = exc*a0v;
    sScale[t2+1] = exc*pp;
  }
  float I0[32], I1[32];
  size_t sb = (((size_t)(b*NH+h))*NCH + c)*8192;
  {
    const bf16* q0 = Sst + sb + (size_t)p0*128 + half*32;
    #pragma unroll
    for (int rr=0;rr<4;rr++){
      uint4 u = *(const uint4*)(q0 + rr*8);
      uint4 v = *(const uint4*)(q0 + 128 + rr*8);
      unsigned int uu[4]={u.x,u.y,u.z,u.w}, vv[4]={v.x,v.y,v.z,v.w};
      #pragma unroll
      for (int k=0;k<4;k++){
        I0[rr*8+2*k]   = __uint_as_float(uu[k]<<16);
        I0[rr*8+2*k+1] = __uint_as_float(uu[k]&0xffff0000u);
        I1[rr*8+2*k]   = __uint_as_float(vv[k]<<16);
        I1[rr*8+2*k+1] = __uint_as_float(vv[k]&0xffff0000u);
      }
    }
  }
  for (int nb=0; nb<QCH/8; nb++){
    size_t bl0 = rowbase + nb*8;
    __syncthreads();
    {
      int t = tid>>4, seg = tid&15;
      const bf16* src = xbc + (bl0+t)*CONVDIM + (DI+NS) + seg*8;
      uint4 u = *(const uint4*)src;
      int n = seg*8;
      float* wp = &sC[t*144 + (n>>5)*36 + (n&31)];
      unsigned int uu[4]={u.x,u.y,u.z,u.w};
      #pragma unroll
      for (int k=0;k<4;k++){
        wp[2*k]   = __uint_as_float(uu[k]<<16);
        wp[2*k+1] = __uint_as_float(uu[k]&0xffff0000u);
      }
    }
    __syncthreads();
    #pragma unroll 2
    for (int t=0;t<8;t++){
      float sc = sScale[nb*8+t];
      const float* cb = &sC[t*144 + half*36];
      float y0=0.f, y1=0.f;
      #pragma unroll
      for (int g=0;g<8;g++){
        float4 Cv = *(const float4*)(cb+g*4);
        y0 = fmaf(I0[g*4+0],Cv.x,y0); y1 = fmaf(I1[g*4+0],Cv.x,y1);
        y0 = fmaf(I0[g*4+1],Cv.y,y0); y1 = fmaf(I1[g*4+1],Cv.y,y1);
        y0 = fmaf(I0[g*4+2],Cv.z,y0); y1 = fmaf(I1[g*4+2],Cv.z,y1);
        y0 = fmaf(I0[g*4+3],Cv.w,y0); y1 = fmaf(I1[g*4+3],Cv.w,y1);
      }
      y0 += __shfl_xor(y0,1); y0 += __shfl_xor(y0,2);
      y1 += __shfl_xor(y1,1); y1 += __shfl_xor(y1,2);
      if (half==0){
        unsigned int* yp = (unsigned int*)(ys + (bl0+t)*DI + h*HD + p0);
        unsigned int old = *yp;
        float o0 = bf2f((bf16)(old&0xffffu)) + sc*y0;
        float o1 = bf2f((bf16)(old>>16)) + sc*y1;
        *yp = pack2bf(o0,o1);
      }
    }
  }
}

// ---------------- y = (ys + D*xh)*silu(z), RMSNorm*w, in place (bf16) ----------------
__global__ __launch_bounds__(256) void k_combine(bf16* __restrict__ ys, const bf16* __restrict__ xbc,
                         const bf16* __restrict__ z, const float* __restrict__ Dp,
                         const float* __restrict__ nw) {
  int bl = blockIdx.x;
  int tid = threadIdx.x;
  bf16* yrow = ys + (size_t)bl*DI;
  const bf16* xrow = xbc + (size_t)bl*CONVDIM;
  const bf16* zrow = z + (size_t)bl*DI;
  float v[2]; float ss = 0.f;
  #pragma unroll
  for (int i=0;i<2;i++) {
    int d = tid + i*256;
    float xh = bf2f(xrow[d]);
    float y = bf2f(yrow[d]) + Dp[d>>6]*xh;
    float zv = bf2f(zrow[d]);
    y *= zv / (1.f + expf(-zv));
    v[i] = y; ss += y*y;
  }
  #pragma unroll
  for (int off=1; off<64; off<<=1) ss += __shfl_xor(ss, off);
  __shared__ float sb[4];
  if ((tid&63)==0) sb[tid>>6]=ss;
  __syncthreads();
  float total = sb[0]+sb[1]+sb[2]+sb[3];
  float scale = rsqrtf(total * (1.f/512.f) + 1e-5f);
  #pragma unroll
  for (int i=0;i<2;i++) {
    int d = tid + i*256;
    yrow[d] = f2bf(v[i]*scale*nw[d]);
  }
}

extern "C" void kernel_launch(void* const* d_in, const int* in_sizes, int n_in,
                              void* d_out, int out_size, void* d_ws, size_t ws_size,
                              hipStream_t stream) {
  const float* x         = (const float*)d_in[0];
  const float* conv_w    = (const float*)d_in[1];
  const float* conv_b    = (const float*)d_in[2];
  const float* bn_gamma  = (const float*)d_in[3];
  const float* bn_beta   = (const float*)d_in[4];
  const float* patch_w   = (const float*)d_in[5];
  const float* patch_b   = (const float*)d_in[6];
  const float* in_proj_w = (const float*)d_in[7];
  const float* conv1d_w  = (const float*)d_in[8];
  const float* conv1d_b  = (const float*)d_in[9];
  const float* dt_bias   = (const float*)d_in[10];
  const float* A_log     = (const float*)d_in[11];
  const float* Dp        = (const float*)d_in[12];
  const float* norm_w    = (const float*)d_in[13];
  const float* out_proj_w= (const float*)d_in[14];
  const float* final_w   = (const float*)d_in[15];
  const float* final_b   = (const float*)d_in[16];
  float* out = (float*)d_out;

  // workspace layout (byte offsets); aliasing of time-disjoint buffers
  char* Wb = (char*)d_ws;
  float* h_buf = (float*)(Wb + 0);              //  8 MB f32, dead after k_patch
  bf16*  winb  = (bf16*)(Wb + 0);               //  0.72 MB bf16 (after k_patch, dead after mgemm0)
  bf16*  woutb = (bf16*)(Wb + 0);               //  0.26 MB bf16 (after combine)
  bf16*  xpost = (bf16*)(Wb + 0);               // 48 MB bf16, written at conv1d
  bf16*  tok   = (bf16*)(Wb + 50331648);        // 16 MB bf16, live until mgemm1
  bf16*  zbuf  = (bf16*)(Wb + 67108864);        // 32 MB bf16, dead after combine
  bf16*  y2b   = (bf16*)(Wb + 67108864);        // 16 MB bf16, written at mgemm1
  bf16*  xpre  = (bf16*)(Wb + 100663296);       // 48 MB bf16, dead after conv1d
  bf16*  ysb   = (bf16*)(Wb + 100663296);       // 32 MB bf16, written by scan1
  bf16*  Sst   = (bf16*)(Wb + 134217728);       // 16 MB bf16 chunk states
  float* dtv   = (float*)(Wb + 150994944);      //  1 MB
  float* dAv   = (float*)(Wb + 152043520);      //  1 MB
  float* stats = (float*)(Wb + 153092096);      //  256 B
  const size_t NEED = 153092352;
  if (ws_size < NEED) {
    hipMemsetAsync(d_out, 0, (size_t)out_size*sizeof(float), stream);
    return;
  }

  k_conv1<<<dim3((B_*CMID*HMID*WMID)/256), dim3(256), 0, stream>>>(x, conv_w, conv_b, h_buf);
  k_bnstats<<<dim3(16), dim3(256), 0, stream>>>(h_buf, stats);
  k_bngelu<<<dim3((B_*CMID*HMID*WMID)/256), dim3(256), 0, stream>>>(h_buf, stats, bn_gamma, bn_beta);
  k_patch<<<dim3(MTOK), dim3(256), 0, stream>>>(h_buf, patch_w, patch_b, tok);
  k_cvtw<<<dim3((NPADIN*DM)/256), dim3(256), 0, stream>>>(in_proj_w, winb, PROJ, 8, NPADIN*DM);
  k_mgemm<0><<<dim3(MTOK/128, NPADIN/128), dim3(256), 0, stream>>>(tok, winb, DM,
      zbuf, xpre, nullptr, nullptr, dt_bias, A_log, dtv, dAv);
  k_conv1d<<<dim3(3, MTOK), dim3(256), 0, stream>>>(xpre, conv1d_w, conv1d_b, xpost);
  k_scan1<<<dim3(B_*NH*NCH), dim3(128), 0, stream>>>(xpost, dtv, dAv, ysb, Sst);
  k_scan2<<<dim3(B_*NH*4), dim3(256), 0, stream>>>(Sst, dAv);
  k_scan3<<<dim3(B_*NH*NCH), dim3(128), 0, stream>>>(xpost, dAv, Sst, ysb);
  k_combine<<<dim3(MTOK), dim3(256), 0, stream>>>(ysb, xpost, zbuf, Dp, norm_w);
  k_cvtw<<<dim3((DM*DI)/256), dim3(256), 0, stream>>>(out_proj_w, woutb, DM, 9, DM*DI);
  k_mgemm<1><<<dim3(MTOK/128, DM/128), dim3(256), 0, stream>>>(ysb, woutb, DI,
      nullptr, nullptr, y2b, tok, nullptr, nullptr, nullptr, nullptr);
  k_gemm<2, bf16><<<dim3(1,512), dim3(256), 0, stream>>>(y2b, final_w, MTOK, 64, DM,
      out, final_b);
}

// Round 5
// 806.123 us; speedup vs baseline: 4.5717x; 1.3754x over previous
//
#include <hip/hip_runtime.h>
#include <math.h>

#define B_  8
#define CIN 3
#define HIN 256
#define WIN 256
#define CMID 16
#define HMID 128
#define WMID 128
#define DM 256
#define L_ 4096
#define DI 512
#define NH 8
#define HD 64
#define NS 128
#define KC 4
#define CONVDIM 768
#define PROJ 1288
#define NPADIN 1408
#define MTOK (B_*L_)

typedef unsigned short bf16;
typedef __attribute__((ext_vector_type(8))) short bf16x8;
typedef __attribute__((ext_vector_type(4))) float f32x4;

__device__ inline float bf2f(bf16 u) { return __uint_as_float(((unsigned int)u) << 16); }
__device__ inline bf16 f2bf(float f) {
  unsigned int x = __float_as_uint(f);
  return (bf16)((x + 0x7fffu + ((x >> 16) & 1u)) >> 16);
}
__device__ inline unsigned int pack2bf(float a, float b) {
  return (unsigned int)f2bf(a) | ((unsigned int)f2bf(b) << 16);
}

__device__ inline float4 ldA4(const float* p) { return *(const float4*)p; }
__device__ inline float4 ldA4(const bf16* p) {
  ushort4 u = *(const ushort4*)p;
  return make_float4(bf2f(u.x), bf2f(u.y), bf2f(u.z), bf2f(u.w));
}

// ---------------- conv 3x3 stride 2 pad 1 ----------------
__global__ void k_conv1(const float* __restrict__ x, const float* __restrict__ w,
                        const float* __restrict__ bias, float* __restrict__ out) {
  int idx = blockIdx.x*256 + threadIdx.x;
  if (idx >= B_*CMID*HMID*WMID) return;
  int xo = idx & 127, yo = (idx>>7)&127, co = (idx>>14)&15, b = idx>>18;
  float acc = bias[co];
  const float* xb = x + (size_t)b*CIN*HIN*WIN;
  const float* wc = w + co*CIN*9;
  #pragma unroll
  for (int ci=0; ci<CIN; ci++)
    #pragma unroll
    for (int ky=0; ky<3; ky++) {
      int yi = 2*yo - 1 + ky;
      if (yi < 0 || yi >= HIN) continue;
      #pragma unroll
      for (int kx=0; kx<3; kx++) {
        int xi = 2*xo - 1 + kx;
        if (xi < 0 || xi >= WIN) continue;
        acc += xb[(ci*HIN + yi)*WIN + xi] * wc[(ci*3+ky)*3+kx];
      }
    }
  out[idx] = acc;
}

// ---------------- batchnorm stats ----------------
__global__ void k_bnstats(const float* __restrict__ h, float* __restrict__ stats) {
  int c = blockIdx.x;
  int tid = threadIdx.x;
  const int NPC = B_*HMID*WMID;
  float s=0.f, s2=0.f;
  for (int i=tid; i<NPC; i+=256) {
    int b = i >> 14;
    int sp = i & 16383;
    float v = h[((size_t)(b*CMID + c))*16384 + sp];
    s += v; s2 += v*v;
  }
  #pragma unroll
  for (int off=1; off<64; off<<=1) { s += __shfl_xor(s, off); s2 += __shfl_xor(s2, off); }
  __shared__ float sb[2][4];
  int wv = tid>>6;
  if ((tid&63)==0) { sb[0][wv]=s; sb[1][wv]=s2; }
  __syncthreads();
  if (tid==0) {
    float S  = sb[0][0]+sb[0][1]+sb[0][2]+sb[0][3];
    float S2 = sb[1][0]+sb[1][1]+sb[1][2]+sb[1][3];
    float mean = S / (float)NPC;
    float var  = S2 / (float)NPC - mean*mean;
    stats[c]      = mean;
    stats[16 + c] = rsqrtf(var + 1e-5f);
  }
}

// ---------------- BN apply + exact GELU ----------------
__global__ void k_bngelu(float* __restrict__ h, const float* __restrict__ stats,
                         const float* __restrict__ gamma, const float* __restrict__ beta) {
  int idx = blockIdx.x*256 + threadIdx.x;
  if (idx >= B_*CMID*HMID*WMID) return;
  int c = (idx>>14)&15;
  float v = (h[idx] - stats[c]) * stats[16+c] * gamma[c] + beta[c];
  h[idx] = 0.5f * v * (1.f + erff(v * 0.70710678118654752f));
}

// ---------------- patch conv 2x2 s2 + bias + sincos -> tok (bf16) ----------------
// 8 tokens per block (same gy row); thread = output dim d, weight row held in regs.
__global__ __launch_bounds__(256) void k_patch(const float* __restrict__ h, const float* __restrict__ pw,
                       const float* __restrict__ pb, bf16* __restrict__ tok) {
  int grp = blockIdx.x;                 // MTOK/8 groups
  int b = grp >> 9, g8 = grp & 511;
  int g0 = g8 << 3;
  int gy = g0 >> 6, gx0 = g0 & 63;      // 8 tokens share gy (8 | 64)
  __shared__ float sh[8][64];
  int tid = threadIdx.x;
  {
    int tk = tid >> 5, jj = (tid & 31)*2;
    int ci = jj >> 2, p = (jj >> 1) & 1;
    const float* src = &h[((size_t)(b*CMID+ci)*HMID + 2*gy+p)*WMID + 2*(gx0+tk)];
    float2 xv = *(const float2*)src;
    sh[tk][jj] = xv.x; sh[tk][jj+1] = xv.y;
  }
  __syncthreads();
  int d = tid;
  float wr[64];
  #pragma unroll
  for (int i4=0;i4<16;i4++) *(float4*)&wr[i4*4] = *(const float4*)&pw[d*64 + i4*4];
  float bias = pb[d];
  int i = d & 63;
  float omega = expf(-(float)i * (9.210340371976184f/64.f));
  #pragma unroll
  for (int tk=0;tk<8;tk++){
    float acc = bias;
    #pragma unroll
    for (int j=0;j<64;j++) acc = fmaf(sh[tk][j], wr[j], acc);
    float gv = (d < 128) ? (float)(gx0+tk) : (float)gy;
    float ph = gv * omega;
    float pos = (d & 64) ? __cosf(ph) : __sinf(ph);
    tok[((size_t)((b<<12) + g0 + tk))*DM + d] = f2bf(acc + pos);
  }
}

// ---------------- weight f32 -> bf16 (with zero-padding to Npad rows) ----------------
__global__ void k_cvtw(const float* __restrict__ src, bf16* __restrict__ dst,
                       int N, int kshift, int total) {
  int idx = blockIdx.x*256 + threadIdx.x;
  if (idx >= total) return;
  int n = idx >> kshift;
  dst[idx] = (n < N) ? f2bf(src[idx]) : (bf16)0;
}

// ---------------- MFMA bf16 GEMM, 128x128 tile, C[m,n]=sum_k A[m,k]*Bw[n,k] ----------------
template<int EPI>
__global__ __launch_bounds__(256) void k_mgemm(
    const bf16* __restrict__ A, const bf16* __restrict__ Bw, int K,
    bf16* __restrict__ o_z, bf16* __restrict__ o_x,
    bf16* __restrict__ o_y, const bf16* __restrict__ res,
    const float* __restrict__ dt_bias, const float* __restrict__ A_log,
    float* __restrict__ dtv, float* __restrict__ dAv) {
  __shared__ __align__(16) bf16 sA[2][128*32];
  __shared__ __align__(16) bf16 sB[2][128*32];
  int tid = threadIdx.x;
  int lane = tid & 63, wid = tid >> 6;
  int wr = wid >> 1, wc = wid & 1;
  int m0 = blockIdx.x*128, n0 = blockIdx.y*128;
  int nk = K >> 5;
  f32x4 acc[4][4];
  #pragma unroll
  for (int i=0;i<4;i++)
    #pragma unroll
    for (int j=0;j<4;j++)
      acc[i][j] = (f32x4){0.f,0.f,0.f,0.f};

  auto stage = [&](int buf, int ks){
    int kk = ks << 5;
    #pragma unroll
    for (int i=0;i<2;i++){
      int j = i*256 + tid;
      int row = j >> 2, cc = j & 3;
      int kg = cc ^ (row & 3);
      unsigned ldsoff = (unsigned)((i*256 + wid*64) * 16);
      __builtin_amdgcn_global_load_lds(
        (const __attribute__((address_space(1))) void*)(A + (size_t)(m0+row)*K + kk + kg*8),
        (__attribute__((address_space(3))) void*)((char*)&sA[buf][0] + ldsoff), 16, 0, 0);
      __builtin_amdgcn_global_load_lds(
        (const __attribute__((address_space(1))) void*)(Bw + (size_t)(n0+row)*K + kk + kg*8),
        (__attribute__((address_space(3))) void*)((char*)&sB[buf][0] + ldsoff), 16, 0, 0);
    }
  };

  int r = lane & 15, q = lane >> 4;
  int kgo = (q ^ (r & 3)) << 3;

  stage(0, 0);
  for (int ks=0; ks<nk; ++ks){
    int cur = ks & 1;
    __syncthreads();
    if (ks+1 < nk) stage(cur^1, ks+1);
    bf16x8 af[4], bfv[4];
    #pragma unroll
    for (int mf=0;mf<4;mf++){
      int rowm = wr*64 + mf*16 + r;
      af[mf] = *(const bf16x8*)&sA[cur][rowm*32 + kgo];
    }
    #pragma unroll
    for (int nf=0;nf<4;nf++){
      int rown = wc*64 + nf*16 + r;
      bfv[nf] = *(const bf16x8*)&sB[cur][rown*32 + kgo];
    }
    #pragma unroll
    for (int mf=0;mf<4;mf++)
      #pragma unroll
      for (int nf=0;nf<4;nf++)
        acc[mf][nf] = __builtin_amdgcn_mfma_f32_16x16x32_bf16(af[mf], bfv[nf], acc[mf][nf], 0, 0, 0);
  }

  #pragma unroll
  for (int mf=0;mf<4;mf++){
    #pragma unroll
    for (int nf=0;nf<4;nf++){
      int n = n0 + wc*64 + nf*16 + r;
      int mbase = m0 + wr*64 + mf*16 + q*4;
      #pragma unroll
      for (int rr=0;rr<4;rr++){
        int m = mbase + rr;
        float val = acc[mf][nf][rr];
        if (EPI == 0){
          if (n < DI) {
            o_z[(size_t)m*DI + n] = f2bf(val);
          } else if (n < DI + CONVDIM) {
            o_x[(size_t)m*CONVDIM + (n - DI)] = f2bf(val);
          } else if (n < PROJ) {
            int hh = n - (DI + CONVDIM);
            float xv = val + dt_bias[hh];
            float dt = (xv > 20.f) ? xv : log1pf(expf(xv));
            dtv[(size_t)m*NH + hh] = dt;
            dAv[(size_t)m*NH + hh] = expf(-expf(A_log[hh]) * dt);
          }
        } else {
          o_y[(size_t)m*DM + n] = f2bf(val + bf2f(res[(size_t)m*DM + n]));
        }
      }
    }
  }
}

// ---------------- SIMT f32-accum GEMM (final layer): pixel-shuffle epilogue ----------------
template<int EPI, typename TA>
__global__ __launch_bounds__(256) void k_gemm(
    const TA* __restrict__ A, const float* __restrict__ Bw,
    int M, int N, int K,
    float* __restrict__ o_f, const float* __restrict__ bias) {
  __shared__ __align__(16) float As[16][64];
  __shared__ __align__(16) float Bs[16][64];
  int tid = threadIdx.x;
  int tx = tid & 15, ty = tid >> 4;
  int m0 = blockIdx.y*64, n0 = blockIdx.x*64;
  float acc[4][4] = {{0.f}};
  for (int k0=0; k0<K; k0+=16) {
    int rr = tid >> 2;
    int kq = (tid & 3) << 2;
    {
      float4 v = ldA4(A + (size_t)(m0+rr)*K + k0 + kq);
      As[kq+0][rr]=v.x; As[kq+1][rr]=v.y; As[kq+2][rr]=v.z; As[kq+3][rr]=v.w;
    }
    {
      int n = n0 + rr;
      float4 v = make_float4(0.f,0.f,0.f,0.f);
      if (n < N) v = *(const float4*)(Bw + (size_t)n*K + k0 + kq);
      Bs[kq+0][rr]=v.x; Bs[kq+1][rr]=v.y; Bs[kq+2][rr]=v.z; Bs[kq+3][rr]=v.w;
    }
    __syncthreads();
    #pragma unroll
    for (int k=0;k<16;k++) {
      float4 a  = *(const float4*)&As[k][ty*4];
      float4 bb = *(const float4*)&Bs[k][tx*4];
      float av[4] = {a.x,a.y,a.z,a.w};
      float bv[4] = {bb.x,bb.y,bb.z,bb.w};
      #pragma unroll
      for (int i=0;i<4;i++)
        #pragma unroll
        for (int j=0;j<4;j++)
          acc[i][j] = fmaf(av[i], bv[j], acc[i][j]);
    }
    __syncthreads();
  }
  #pragma unroll
  for (int i=0;i<4;i++) {
    int m = m0 + ty*4 + i;
    #pragma unroll
    for (int j=0;j<4;j++) {
      int n = n0 + tx*4 + j;
      if (n < N) {
        float vv = acc[i][j] + bias[n];
        int b = m >> 12, g = m & 4095;
        int gy = g >> 6, gx = g & 63;
        int p = n >> 5, qq = (n>>4)&1, c = n & 15;
        o_f[(((size_t)(b*CMID+c))*HMID + 2*gy+p)*WMID + (2*gx+qq)] = vv;
      }
    }
  }
}

// ---------------- causal depthwise conv1d (KC=4) + bias + silu, 8ch/thread ----------------
__global__ __launch_bounds__(256) void k_conv1d(const bf16* __restrict__ xpre, const float* __restrict__ cw,
                         const float* __restrict__ cb, bf16* __restrict__ xbc) {
  int idx = blockIdx.x*256 + threadIdx.x;     // MTOK*96 threads
  int gch = idx % 96;
  int bl  = idx / 96;
  int ch0 = gch*8;
  int l = bl & (L_-1);
  float acc[8];
  *(float4*)&acc[0] = *(const float4*)&cb[ch0];
  *(float4*)&acc[4] = *(const float4*)&cb[ch0+4];
  float wv[32];
  #pragma unroll
  for (int i=0;i<8;i++) *(float4*)&wv[i*4] = *(const float4*)&cw[ch0*KC + i*4];
  #pragma unroll
  for (int k=0;k<KC;k++){
    int lk = l - 3 + k;
    if (lk < 0) continue;
    const bf16* row = xpre + ((size_t)bl + (k-3))*CONVDIM + ch0;
    uint4 u = *(const uint4*)row;
    unsigned uu[4]={u.x,u.y,u.z,u.w};
    #pragma unroll
    for (int c2=0;c2<4;c2++){
      float lo = __uint_as_float(uu[c2]<<16);
      float hi = __uint_as_float(uu[c2]&0xffff0000u);
      acc[c2*2]   = fmaf(wv[(c2*2)*4 + k],   lo, acc[c2*2]);
      acc[c2*2+1] = fmaf(wv[(c2*2+1)*4 + k], hi, acc[c2*2+1]);
    }
  }
  unsigned out_u[4];
  #pragma unroll
  for (int c2=0;c2<4;c2++){
    float v0 = acc[c2*2], v1 = acc[c2*2+1];
    v0 = v0 / (1.f + __expf(-v0));
    v1 = v1 / (1.f + __expf(-v1));
    out_u[c2] = pack2bf(v0, v1);
  }
  *(uint4*)(xbc + (size_t)bl*CONVDIM + ch0) = make_uint4(out_u[0],out_u[1],out_u[2],out_u[3]);
}

// ================= chunked selective scan (templated on chunk count/length) =================
template<int NCHT, int QCHT>
__global__ __launch_bounds__(128) void k_scan1(const bf16* __restrict__ xbc,
    const float* __restrict__ dtv, const float* __restrict__ dAv,
    bf16* __restrict__ ys, bf16* __restrict__ Sst) {
  constexpr int LOGN = (NCHT==16)?4:5;
  int blk = blockIdx.x;
  int c = blk & (NCHT-1), h = (blk>>LOGN)&7, b = blk>>(LOGN+3);
  int tid = threadIdx.x;
  int half = tid & 3;
  int p0 = (tid>>2)*2;
  __shared__ __align__(16) float sBC[8*288];
  __shared__ __align__(16) float sX[8*64];
  __shared__ float sDT[16];
  float s0[32], s1[32];
  #pragma unroll
  for (int j=0;j<32;j++){ s0[j]=0.f; s1[j]=0.f; }
  size_t rowbase = (size_t)b*L_ + (size_t)c*QCHT;

  for (int nb=0; nb<QCHT/8; nb++){
    size_t bl0 = rowbase + nb*8;
    __syncthreads();
    {
      int t = tid>>4, seg = tid&15;
      const bf16* src = xbc + (bl0+t)*CONVDIM + DI + seg*16;
      uint4 u0 = *(const uint4*)src;
      uint4 u1 = *(const uint4*)(src+8);
      int n_abs = seg*16;
      float* w = &sBC[t*288 + (n_abs>>7)*144 + ((n_abs&127)>>5)*36 + (n_abs&31)];
      unsigned int uu[8] = {u0.x,u0.y,u0.z,u0.w,u1.x,u1.y,u1.z,u1.w};
      #pragma unroll
      for (int k=0;k<8;k++){
        w[2*k]   = __uint_as_float(uu[k]<<16);
        w[2*k+1] = __uint_as_float(uu[k]&0xffff0000u);
      }
      int col = (tid&15)*4;
      const bf16* xs = xbc + (bl0+t)*CONVDIM + h*HD + col;
      ushort4 xu = *(const ushort4*)xs;
      float* wx = &sX[t*64+col];
      wx[0]=bf2f(xu.x); wx[1]=bf2f(xu.y); wx[2]=bf2f(xu.z); wx[3]=bf2f(xu.w);
      if (tid < 8){
        sDT[tid*2]   = dtv[(bl0+tid)*NH + h];
        sDT[tid*2+1] = dAv[(bl0+tid)*NH + h];
      }
    }
    __syncthreads();
    #pragma unroll 2
    for (int t=0;t<8;t++){
      float dtt = sDT[t*2], da = sDT[t*2+1];
      float2 xv = *(const float2*)&sX[t*64+p0];
      float a0 = dtt*xv.x, a1 = dtt*xv.y;
      float y0=0.f, y1=0.f;
      const float* bb = &sBC[t*288 + half*36];
      const float* cb = bb + 144;
      #pragma unroll
      for (int g=0; g<8; g++){
        float4 Bv = *(const float4*)(bb + g*4);
        float4 Cv = *(const float4*)(cb + g*4);
        s0[g*4+0]=fmaf(s0[g*4+0],da,a0*Bv.x); y0=fmaf(s0[g*4+0],Cv.x,y0);
        s1[g*4+0]=fmaf(s1[g*4+0],da,a1*Bv.x); y1=fmaf(s1[g*4+0],Cv.x,y1);
        s0[g*4+1]=fmaf(s0[g*4+1],da,a0*Bv.y); y0=fmaf(s0[g*4+1],Cv.y,y0);
        s1[g*4+1]=fmaf(s1[g*4+1],da,a1*Bv.y); y1=fmaf(s1[g*4+1],Cv.y,y1);
        s0[g*4+2]=fmaf(s0[g*4+2],da,a0*Bv.z); y0=fmaf(s0[g*4+2],Cv.z,y0);
        s1[g*4+2]=fmaf(s1[g*4+2],da,a1*Bv.z); y1=fmaf(s1[g*4+2],Cv.z,y1);
        s0[g*4+3]=fmaf(s0[g*4+3],da,a0*Bv.w); y0=fmaf(s0[g*4+3],Cv.w,y0);
        s1[g*4+3]=fmaf(s1[g*4+3],da,a1*Bv.w); y1=fmaf(s1[g*4+3],Cv.w,y1);
      }
      y0 += __shfl_xor(y0,1); y0 += __shfl_xor(y0,2);
      y1 += __shfl_xor(y1,1); y1 += __shfl_xor(y1,2);
      if (half==0){
        *(unsigned int*)(ys + (bl0+t)*DI + h*HD + p0) = pack2bf(y0,y1);
      }
    }
  }
  size_t sb = (((size_t)(b*NH+h))*NCHT + c)*8192;
  unsigned int* dp0 = (unsigned int*)(Sst + sb + (size_t)p0*128 + half*32);
  unsigned int* dp1 = (unsigned int*)(Sst + sb + (size_t)(p0+1)*128 + half*32);
  #pragma unroll
  for (int k=0;k<16;k++){
    dp0[k] = pack2bf(s0[2*k], s0[2*k+1]);
    dp1[k] = pack2bf(s1[2*k], s1[2*k+1]);
  }
}

template<int NCHT, int QCHT>
__global__ __launch_bounds__(256) void k_scan2(bf16* __restrict__ Sst, const float* __restrict__ dAv) {
  constexpr int SEG = QCHT/16;
  int blk = blockIdx.x;
  int bh = blk>>2, q = blk&3;
  int b = bh>>3, h = bh&7;
  int tid = threadIdx.x;
  __shared__ float sP[NCHT];
  {
    int c = tid / SEG, seg = tid & (SEG-1);
    float prod = 1.f;
    size_t base = ((size_t)b*L_ + c*QCHT + seg*16)*NH + h;
    #pragma unroll
    for (int k=0;k<16;k++) prod *= dAv[base + (size_t)k*NH];
    #pragma unroll
    for (int off=1; off<SEG; off<<=1) prod *= __shfl_xor(prod, off);
    if (seg==0) sP[c] = prod;
  }
  __syncthreads();
  int e0 = q*2048 + tid*8;
  float acc[8];
  #pragma unroll
  for (int j=0;j<8;j++) acc[j]=0.f;
  size_t sbase = (size_t)bh*NCHT*8192 + e0;
  for (int c=0;c<NCHT;c++){
    bf16* ptr = Sst + sbase + (size_t)c*8192;
    uint4 u = *(const uint4*)ptr;
    unsigned int uu[4] = {u.x,u.y,u.z,u.w};
    float tv[8];
    #pragma unroll
    for (int k=0;k<4;k++){
      tv[2*k]   = __uint_as_float(uu[k]<<16);
      tv[2*k+1] = __uint_as_float(uu[k]&0xffff0000u);
    }
    uint4 o;
    o.x = pack2bf(acc[0],acc[1]); o.y = pack2bf(acc[2],acc[3]);
    o.z = pack2bf(acc[4],acc[5]); o.w = pack2bf(acc[6],acc[7]);
    asm volatile("s_waitcnt vmcnt(0)" ::: "memory");
    *(uint4*)ptr = o;
    float P = sP[c];
    #pragma unroll
    for (int j=0;j<8;j++) acc[j] = tv[j] + P*acc[j];
  }
}

template<int NCHT, int QCHT>
__global__ __launch_bounds__(128) void k_scan3(const bf16* __restrict__ xbc,
    const float* __restrict__ dAv, const bf16* __restrict__ Sst, bf16* __restrict__ ys) {
  constexpr int LOGN = (NCHT==16)?4:5;
  constexpr int E = QCHT/128;
  int blk = blockIdx.x;
  int c = blk & (NCHT-1), h=(blk>>LOGN)&7, b=blk>>(LOGN+3);
  int tid = threadIdx.x;
  int half = tid&3, p0 = (tid>>2)*2;
  __shared__ __align__(16) float sC[8*144];
  __shared__ float sScale[QCHT];
  __shared__ float sWT[2];
  int lane = tid & 63, w = tid>>6;
  size_t rowbase = (size_t)b*L_ + (size_t)c*QCHT;
  {
    float ae0 = dAv[(rowbase + tid*E)*NH + h];
    float ae1 = 1.f, pe;
    if (E==2) { ae1 = dAv[(rowbase + tid*E + 1)*NH + h]; pe = ae0*ae1; } else pe = ae0;
    float inc = pe;
    #pragma unroll
    for (int off=1; off<64; off<<=1){
      float u = __shfl_up(inc, off);
      if (lane>=off) inc *= u;
    }
    if (lane==63) sWT[w] = inc;
    __syncthreads();
    if (w==1) inc *= sWT[0];
    float exc = __shfl_up(inc,1);
    if (lane==0) exc = (w==0) ? 1.f : sWT[0];
    sScale[tid*E] = exc*ae0;
    if (E==2) sScale[tid*E+1] = exc*pe;
  }
  float I0[32], I1[32];
  size_t sb = (((size_t)(b*NH+h))*NCHT + c)*8192;
  {
    const bf16* q0 = Sst + sb + (size_t)p0*128 + half*32;
    #pragma unroll
    for (int rr=0;rr<4;rr++){
      uint4 u = *(const uint4*)(q0 + rr*8);
      uint4 v = *(const uint4*)(q0 + 128 + rr*8);
      unsigned int uu[4]={u.x,u.y,u.z,u.w}, vv[4]={v.x,v.y,v.z,v.w};
      #pragma unroll
      for (int k=0;k<4;k++){
        I0[rr*8+2*k]   = __uint_as_float(uu[k]<<16);
        I0[rr*8+2*k+1] = __uint_as_float(uu[k]&0xffff0000u);
        I1[rr*8+2*k]   = __uint_as_float(vv[k]<<16);
        I1[rr*8+2*k+1] = __uint_as_float(vv[k]&0xffff0000u);
      }
    }
  }
  for (int nb=0; nb<QCHT/8; nb++){
    size_t bl0 = rowbase + nb*8;
    __syncthreads();
    {
      int t = tid>>4, seg = tid&15;
      const bf16* src = xbc + (bl0+t)*CONVDIM + (DI+NS) + seg*8;
      uint4 u = *(const uint4*)src;
      int n = seg*8;
      float* wp = &sC[t*144 + (n>>5)*36 + (n&31)];
      unsigned int uu[4]={u.x,u.y,u.z,u.w};
      #pragma unroll
      for (int k=0;k<4;k++){
        wp[2*k]   = __uint_as_float(uu[k]<<16);
        wp[2*k+1] = __uint_as_float(uu[k]&0xffff0000u);
      }
    }
    __syncthreads();
    #pragma unroll 2
    for (int t=0;t<8;t++){
      float sc = sScale[nb*8+t];
      const float* cb = &sC[t*144 + half*36];
      float y0=0.f, y1=0.f;
      #pragma unroll
      for (int g=0;g<8;g++){
        float4 Cv = *(const float4*)(cb+g*4);
        y0 = fmaf(I0[g*4+0],Cv.x,y0); y1 = fmaf(I1[g*4+0],Cv.x,y1);
        y0 = fmaf(I0[g*4+1],Cv.y,y0); y1 = fmaf(I1[g*4+1],Cv.y,y1);
        y0 = fmaf(I0[g*4+2],Cv.z,y0); y1 = fmaf(I1[g*4+2],Cv.z,y1);
        y0 = fmaf(I0[g*4+3],Cv.w,y0); y1 = fmaf(I1[g*4+3],Cv.w,y1);
      }
      y0 += __shfl_xor(y0,1); y0 += __shfl_xor(y0,2);
      y1 += __shfl_xor(y1,1); y1 += __shfl_xor(y1,2);
      if (half==0){
        unsigned int* yp = (unsigned int*)(ys + (bl0+t)*DI + h*HD + p0);
        unsigned int old = *yp;
        float o0 = bf2f((bf16)(old&0xffffu)) + sc*y0;
        float o1 = bf2f((bf16)(old>>16)) + sc*y1;
        *yp = pack2bf(o0,o1);
      }
    }
  }
}

// ---------------- y = (ys + D*xh)*silu(z), RMSNorm*w, in place (bf16) ----------------
__global__ __launch_bounds__(256) void k_combine(bf16* __restrict__ ys, const bf16* __restrict__ xbc,
                         const bf16* __restrict__ z, const float* __restrict__ Dp,
                         const float* __restrict__ nw) {
  int bl = blockIdx.x;
  int tid = threadIdx.x;
  bf16* yrow = ys + (size_t)bl*DI;
  const bf16* xrow = xbc + (size_t)bl*CONVDIM;
  const bf16* zrow = z + (size_t)bl*DI;
  float v[2]; float ss = 0.f;
  #pragma unroll
  for (int i=0;i<2;i++) {
    int d = tid + i*256;
    float xh = bf2f(xrow[d]);
    float y = bf2f(yrow[d]) + Dp[d>>6]*xh;
    float zv = bf2f(zrow[d]);
    y *= zv / (1.f + expf(-zv));
    v[i] = y; ss += y*y;
  }
  #pragma unroll
  for (int off=1; off<64; off<<=1) ss += __shfl_xor(ss, off);
  __shared__ float sb[4];
  if ((tid&63)==0) sb[tid>>6]=ss;
  __syncthreads();
  float total = sb[0]+sb[1]+sb[2]+sb[3];
  float scale = rsqrtf(total * (1.f/512.f) + 1e-5f);
  #pragma unroll
  for (int i=0;i<2;i++) {
    int d = tid + i*256;
    yrow[d] = f2bf(v[i]*scale*nw[d]);
  }
}

extern "C" void kernel_launch(void* const* d_in, const int* in_sizes, int n_in,
                              void* d_out, int out_size, void* d_ws, size_t ws_size,
                              hipStream_t stream) {
  const float* x         = (const float*)d_in[0];
  const float* conv_w    = (const float*)d_in[1];
  const float* conv_b    = (const float*)d_in[2];
  const float* bn_gamma  = (const float*)d_in[3];
  const float* bn_beta   = (const float*)d_in[4];
  const float* patch_w   = (const float*)d_in[5];
  const float* patch_b   = (const float*)d_in[6];
  const float* in_proj_w = (const float*)d_in[7];
  const float* conv1d_w  = (const float*)d_in[8];
  const float* conv1d_b  = (const float*)d_in[9];
  const float* dt_bias   = (const float*)d_in[10];
  const float* A_log     = (const float*)d_in[11];
  const float* Dp        = (const float*)d_in[12];
  const float* norm_w    = (const float*)d_in[13];
  const float* out_proj_w= (const float*)d_in[14];
  const float* final_w   = (const float*)d_in[15];
  const float* final_b   = (const float*)d_in[16];
  float* out = (float*)d_out;

  // workspace layout (byte offsets); aliasing of time-disjoint buffers
  char* Wb = (char*)d_ws;
  float* h_buf = (float*)(Wb + 0);              //  8 MB f32, dead after k_patch
  bf16*  winb  = (bf16*)(Wb + 0);               //  bf16 in_proj (after patch, dead after mgemm0)
  bf16*  woutb = (bf16*)(Wb + 0);               //  bf16 out_proj (after combine)
  bf16*  xpost = (bf16*)(Wb + 0);               // 48 MB bf16, written at conv1d
  bf16*  tok   = (bf16*)(Wb + 50331648);        // 16 MB bf16, live until mgemm1
  bf16*  zbuf  = (bf16*)(Wb + 67108864);        // 32 MB bf16, dead after combine
  bf16*  y2b   = (bf16*)(Wb + 67108864);        // 16 MB bf16, written at mgemm1
  bf16*  xpre  = (bf16*)(Wb + 100663296);       // 48 MB bf16, dead after conv1d
  bf16*  ysb   = (bf16*)(Wb + 100663296);       // 32 MB bf16, written by scan1
  bf16*  Sst   = (bf16*)(Wb + 134217728);       // chunk states (16 or 32 MB)

  const size_t NEED16 = 134217728ull + 16777216 + 2097152 + 256;
  const size_t NEED32 = 134217728ull + 33554432 + 2097152 + 256;
  bool big = (ws_size >= NEED32);
  size_t sstBytes = big ? 33554432ull : 16777216ull;
  float* dtv   = (float*)(Wb + 134217728 + sstBytes);
  float* dAv   = dtv + 262144;
  float* stats = dAv + 262144;
  if (ws_size < NEED16) {
    hipMemsetAsync(d_out, 0, (size_t)out_size*sizeof(float), stream);
    return;
  }

  k_conv1<<<dim3((B_*CMID*HMID*WMID)/256), dim3(256), 0, stream>>>(x, conv_w, conv_b, h_buf);
  k_bnstats<<<dim3(16), dim3(256), 0, stream>>>(h_buf, stats);
  k_bngelu<<<dim3((B_*CMID*HMID*WMID)/256), dim3(256), 0, stream>>>(h_buf, stats, bn_gamma, bn_beta);
  k_patch<<<dim3(MTOK/8), dim3(256), 0, stream>>>(h_buf, patch_w, patch_b, tok);
  k_cvtw<<<dim3((NPADIN*DM)/256), dim3(256), 0, stream>>>(in_proj_w, winb, PROJ, 8, NPADIN*DM);
  k_mgemm<0><<<dim3(MTOK/128, NPADIN/128), dim3(256), 0, stream>>>(tok, winb, DM,
      zbuf, xpre, nullptr, nullptr, dt_bias, A_log, dtv, dAv);
  k_conv1d<<<dim3((MTOK*96)/256), dim3(256), 0, stream>>>(xpre, conv1d_w, conv1d_b, xpost);
  if (big) {
    k_scan1<32,128><<<dim3(B_*NH*32), dim3(128), 0, stream>>>(xpost, dtv, dAv, ysb, Sst);
    k_scan2<32,128><<<dim3(B_*NH*4), dim3(256), 0, stream>>>(Sst, dAv);
    k_scan3<32,128><<<dim3(B_*NH*32), dim3(128), 0, stream>>>(xpost, dAv, Sst, ysb);
  } else {
    k_scan1<16,256><<<dim3(B_*NH*16), dim3(128), 0, stream>>>(xpost, dtv, dAv, ysb, Sst);
    k_scan2<16,256><<<dim3(B_*NH*4), dim3(256), 0, stream>>>(Sst, dAv);
    k_scan3<16,256><<<dim3(B_*NH*16), dim3(128), 0, stream>>>(xpost, dAv, Sst, ysb);
  }
  k_combine<<<dim3(MTOK), dim3(256), 0, stream>>>(ysb, xpost, zbuf, Dp, norm_w);
  k_cvtw<<<dim3((DM*DI)/256), dim3(256), 0, stream>>>(out_proj_w, woutb, DM, 9, DM*DI);
  k_mgemm<1><<<dim3(MTOK/128, DM/128), dim3(256), 0, stream>>>(ysb, woutb, DI,
      nullptr, nullptr, y2b, tok, nullptr, nullptr, nullptr, nullptr);
  k_gemm<2, bf16><<<dim3(1,512), dim3(256), 0, stream>>>(y2b, final_w, MTOK, 64, DM,
      out, final_b);
}

// Round 6
// 613.028 us; speedup vs baseline: 6.0117x; 1.3150x over previous
//
#include <hip/hip_runtime.h>
#include <math.h>

#define B_  8
#define CIN 3
#define HIN 256
#define WIN 256
#define CMID 16
#define HMID 128
#define WMID 128
#define DM 256
#define L_ 4096
#define DI 512
#define NH 8
#define HD 64
#define NS 128
#define KC 4
#define CONVDIM 768
#define PROJ 1288
#define NPADIN 1408
#define MTOK (B_*L_)
#define QCH 128          // chunk length (SSD)
#define NCH 32           // number of chunks

typedef unsigned short bf16;
typedef __attribute__((ext_vector_type(8))) short bf16x8;
typedef __attribute__((ext_vector_type(4))) float f32x4;

__device__ inline float bf2f(bf16 u) { return __uint_as_float(((unsigned int)u) << 16); }
__device__ inline bf16 f2bf(float f) {
  unsigned int x = __float_as_uint(f);
  return (bf16)((x + 0x7fffu + ((x >> 16) & 1u)) >> 16);
}
__device__ inline unsigned int pack2bf(float a, float b) {
  return (unsigned int)f2bf(a) | ((unsigned int)f2bf(b) << 16);
}

__device__ inline float4 ldA4(const float* p) { return *(const float4*)p; }
__device__ inline float4 ldA4(const bf16* p) {
  ushort4 u = *(const ushort4*)p;
  return make_float4(bf2f(u.x), bf2f(u.y), bf2f(u.z), bf2f(u.w));
}

// ---------------- conv 3x3 stride 2 pad 1 ----------------
__global__ void k_conv1(const float* __restrict__ x, const float* __restrict__ w,
                        const float* __restrict__ bias, float* __restrict__ out) {
  int idx = blockIdx.x*256 + threadIdx.x;
  if (idx >= B_*CMID*HMID*WMID) return;
  int xo = idx & 127, yo = (idx>>7)&127, co = (idx>>14)&15, b = idx>>18;
  float acc = bias[co];
  const float* xb = x + (size_t)b*CIN*HIN*WIN;
  const float* wc = w + co*CIN*9;
  #pragma unroll
  for (int ci=0; ci<CIN; ci++)
    #pragma unroll
    for (int ky=0; ky<3; ky++) {
      int yi = 2*yo - 1 + ky;
      if (yi < 0 || yi >= HIN) continue;
      #pragma unroll
      for (int kx=0; kx<3; kx++) {
        int xi = 2*xo - 1 + kx;
        if (xi < 0 || xi >= WIN) continue;
        acc += xb[(ci*HIN + yi)*WIN + xi] * wc[(ci*3+ky)*3+kx];
      }
    }
  out[idx] = acc;
}

// ---------------- batchnorm stats ----------------
__global__ void k_bnstats(const float* __restrict__ h, float* __restrict__ stats) {
  int c = blockIdx.x;
  int tid = threadIdx.x;
  const int NPC = B_*HMID*WMID;
  float s=0.f, s2=0.f;
  for (int i=tid; i<NPC; i+=256) {
    int b = i >> 14;
    int sp = i & 16383;
    float v = h[((size_t)(b*CMID + c))*16384 + sp];
    s += v; s2 += v*v;
  }
  #pragma unroll
  for (int off=1; off<64; off<<=1) { s += __shfl_xor(s, off); s2 += __shfl_xor(s2, off); }
  __shared__ float sb[2][4];
  int wv = tid>>6;
  if ((tid&63)==0) { sb[0][wv]=s; sb[1][wv]=s2; }
  __syncthreads();
  if (tid==0) {
    float S  = sb[0][0]+sb[0][1]+sb[0][2]+sb[0][3];
    float S2 = sb[1][0]+sb[1][1]+sb[1][2]+sb[1][3];
    float mean = S / (float)NPC;
    float var  = S2 / (float)NPC - mean*mean;
    stats[c]      = mean;
    stats[16 + c] = rsqrtf(var + 1e-5f);
  }
}

// ---------------- BN apply + exact GELU ----------------
__global__ void k_bngelu(float* __restrict__ h, const float* __restrict__ stats,
                         const float* __restrict__ gamma, const float* __restrict__ beta) {
  int idx = blockIdx.x*256 + threadIdx.x;
  if (idx >= B_*CMID*HMID*WMID) return;
  int c = (idx>>14)&15;
  float v = (h[idx] - stats[c]) * stats[16+c] * gamma[c] + beta[c];
  h[idx] = 0.5f * v * (1.f + erff(v * 0.70710678118654752f));
}

// ---------------- patch conv 2x2 s2 + bias + sincos -> tok (bf16) ----------------
__global__ __launch_bounds__(256) void k_patch(const float* __restrict__ h, const float* __restrict__ pw,
                       const float* __restrict__ pb, bf16* __restrict__ tok) {
  int grp = blockIdx.x;
  int b = grp >> 9, g8 = grp & 511;
  int g0 = g8 << 3;
  int gy = g0 >> 6, gx0 = g0 & 63;
  __shared__ float sh[8][64];
  int tid = threadIdx.x;
  {
    int tk = tid >> 5, jj = (tid & 31)*2;
    int ci = jj >> 2, p = (jj >> 1) & 1;
    const float* src = &h[((size_t)(b*CMID+ci)*HMID + 2*gy+p)*WMID + 2*(gx0+tk)];
    float2 xv = *(const float2*)src;
    sh[tk][jj] = xv.x; sh[tk][jj+1] = xv.y;
  }
  __syncthreads();
  int d = tid;
  float wr[64];
  #pragma unroll
  for (int i4=0;i4<16;i4++) *(float4*)&wr[i4*4] = *(const float4*)&pw[d*64 + i4*4];
  float bias = pb[d];
  int i = d & 63;
  float omega = expf(-(float)i * (9.210340371976184f/64.f));
  #pragma unroll
  for (int tk=0;tk<8;tk++){
    float acc = bias;
    #pragma unroll
    for (int j=0;j<64;j++) acc = fmaf(sh[tk][j], wr[j], acc);
    float gv = (d < 128) ? (float)(gx0+tk) : (float)gy;
    float ph = gv * omega;
    float pos = (d & 64) ? __cosf(ph) : __sinf(ph);
    tok[((size_t)((b<<12) + g0 + tk))*DM + d] = f2bf(acc + pos);
  }
}

// ---------------- weight f32 -> bf16 (with zero-padding to Npad rows) ----------------
__global__ void k_cvtw(const float* __restrict__ src, bf16* __restrict__ dst,
                       int N, int kshift, int total) {
  int idx = blockIdx.x*256 + threadIdx.x;
  if (idx >= total) return;
  int n = idx >> kshift;
  dst[idx] = (n < N) ? f2bf(src[idx]) : (bf16)0;
}

// ---------------- MFMA bf16 GEMM, 128x128 tile, C[m,n]=sum_k A[m,k]*Bw[n,k] ----------------
template<int EPI>
__global__ __launch_bounds__(256) void k_mgemm(
    const bf16* __restrict__ A, const bf16* __restrict__ Bw, int K,
    bf16* __restrict__ o_z, bf16* __restrict__ o_x,
    bf16* __restrict__ o_y, const bf16* __restrict__ res,
    const float* __restrict__ dt_bias, const float* __restrict__ A_log,
    float* __restrict__ dtv, float* __restrict__ dAv) {
  __shared__ __align__(16) bf16 sA[2][128*32];
  __shared__ __align__(16) bf16 sB[2][128*32];
  int tid = threadIdx.x;
  int lane = tid & 63, wid = tid >> 6;
  int wr = wid >> 1, wc = wid & 1;
  int m0 = blockIdx.x*128, n0 = blockIdx.y*128;
  int nk = K >> 5;
  f32x4 acc[4][4];
  #pragma unroll
  for (int i=0;i<4;i++)
    #pragma unroll
    for (int j=0;j<4;j++)
      acc[i][j] = (f32x4){0.f,0.f,0.f,0.f};

  auto stage = [&](int buf, int ks){
    int kk = ks << 5;
    #pragma unroll
    for (int i=0;i<2;i++){
      int j = i*256 + tid;
      int row = j >> 2, cc = j & 3;
      int kg = cc ^ (row & 3);
      unsigned ldsoff = (unsigned)((i*256 + wid*64) * 16);
      __builtin_amdgcn_global_load_lds(
        (const __attribute__((address_space(1))) void*)(A + (size_t)(m0+row)*K + kk + kg*8),
        (__attribute__((address_space(3))) void*)((char*)&sA[buf][0] + ldsoff), 16, 0, 0);
      __builtin_amdgcn_global_load_lds(
        (const __attribute__((address_space(1))) void*)(Bw + (size_t)(n0+row)*K + kk + kg*8),
        (__attribute__((address_space(3))) void*)((char*)&sB[buf][0] + ldsoff), 16, 0, 0);
    }
  };

  int r = lane & 15, q = lane >> 4;
  int kgo = (q ^ (r & 3)) << 3;

  stage(0, 0);
  for (int ks=0; ks<nk; ++ks){
    int cur = ks & 1;
    __syncthreads();
    if (ks+1 < nk) stage(cur^1, ks+1);
    bf16x8 af[4], bfv[4];
    #pragma unroll
    for (int mf=0;mf<4;mf++){
      int rowm = wr*64 + mf*16 + r;
      af[mf] = *(const bf16x8*)&sA[cur][rowm*32 + kgo];
    }
    #pragma unroll
    for (int nf=0;nf<4;nf++){
      int rown = wc*64 + nf*16 + r;
      bfv[nf] = *(const bf16x8*)&sB[cur][rown*32 + kgo];
    }
    #pragma unroll
    for (int mf=0;mf<4;mf++)
      #pragma unroll
      for (int nf=0;nf<4;nf++)
        acc[mf][nf] = __builtin_amdgcn_mfma_f32_16x16x32_bf16(af[mf], bfv[nf], acc[mf][nf], 0, 0, 0);
  }

  #pragma unroll
  for (int mf=0;mf<4;mf++){
    #pragma unroll
    for (int nf=0;nf<4;nf++){
      int n = n0 + wc*64 + nf*16 + r;
      int mbase = m0 + wr*64 + mf*16 + q*4;
      #pragma unroll
      for (int rr=0;rr<4;rr++){
        int m = mbase + rr;
        float val = acc[mf][nf][rr];
        if (EPI == 0){
          if (n < DI) {
            o_z[(size_t)m*DI + n] = f2bf(val);
          } else if (n < DI + CONVDIM) {
            o_x[(size_t)m*CONVDIM + (n - DI)] = f2bf(val);
          } else if (n < PROJ) {
            int hh = n - (DI + CONVDIM);
            float xv = val + dt_bias[hh];
            float dt = (xv > 20.f) ? xv : log1pf(expf(xv));
            dtv[(size_t)m*NH + hh] = dt;
            dAv[(size_t)m*NH + hh] = expf(-expf(A_log[hh]) * dt);
          }
        } else {
          o_y[(size_t)m*DM + n] = f2bf(val + bf2f(res[(size_t)m*DM + n]));
        }
      }
    }
  }
}

// ---------------- SIMT f32-accum GEMM (final layer): pixel-shuffle epilogue ----------------
template<int EPI, typename TA>
__global__ __launch_bounds__(256) void k_gemm(
    const TA* __restrict__ A, const float* __restrict__ Bw,
    int M, int N, int K,
    float* __restrict__ o_f, const float* __restrict__ bias) {
  __shared__ __align__(16) float As[16][64];
  __shared__ __align__(16) float Bs[16][64];
  int tid = threadIdx.x;
  int tx = tid & 15, ty = tid >> 4;
  int m0 = blockIdx.y*64, n0 = blockIdx.x*64;
  float acc[4][4] = {{0.f}};
  for (int k0=0; k0<K; k0+=16) {
    int rr = tid >> 2;
    int kq = (tid & 3) << 2;
    {
      float4 v = ldA4(A + (size_t)(m0+rr)*K + k0 + kq);
      As[kq+0][rr]=v.x; As[kq+1][rr]=v.y; As[kq+2][rr]=v.z; As[kq+3][rr]=v.w;
    }
    {
      int n = n0 + rr;
      float4 v = make_float4(0.f,0.f,0.f,0.f);
      if (n < N) v = *(const float4*)(Bw + (size_t)n*K + k0 + kq);
      Bs[kq+0][rr]=v.x; Bs[kq+1][rr]=v.y; Bs[kq+2][rr]=v.z; Bs[kq+3][rr]=v.w;
    }
    __syncthreads();
    #pragma unroll
    for (int k=0;k<16;k++) {
      float4 a  = *(const float4*)&As[k][ty*4];
      float4 bb = *(const float4*)&Bs[k][tx*4];
      float av[4] = {a.x,a.y,a.z,a.w};
      float bv[4] = {bb.x,bb.y,bb.z,bb.w};
      #pragma unroll
      for (int i=0;i<4;i++)
        #pragma unroll
        for (int j=0;j<4;j++)
          acc[i][j] = fmaf(av[i], bv[j], acc[i][j]);
    }
    __syncthreads();
  }
  #pragma unroll
  for (int i=0;i<4;i++) {
    int m = m0 + ty*4 + i;
    #pragma unroll
    for (int j=0;j<4;j++) {
      int n = n0 + tx*4 + j;
      if (n < N) {
        float vv = acc[i][j] + bias[n];
        int b = m >> 12, g = m & 4095;
        int gy = g >> 6, gx = g & 63;
        int p = n >> 5, qq = (n>>4)&1, c = n & 15;
        o_f[(((size_t)(b*CMID+c))*HMID + 2*gy+p)*WMID + (2*gx+qq)] = vv;
      }
    }
  }
}

// ---------------- causal depthwise conv1d (KC=4) + bias + silu, 8ch/thread ----------------
__global__ __launch_bounds__(256) void k_conv1d(const bf16* __restrict__ xpre, const float* __restrict__ cw,
                         const float* __restrict__ cb, bf16* __restrict__ xbc) {
  int idx = blockIdx.x*256 + threadIdx.x;
  int gch = idx % 96;
  int bl  = idx / 96;
  int ch0 = gch*8;
  int l = bl & (L_-1);
  float acc[8];
  *(float4*)&acc[0] = *(const float4*)&cb[ch0];
  *(float4*)&acc[4] = *(const float4*)&cb[ch0+4];
  float wv[32];
  #pragma unroll
  for (int i=0;i<8;i++) *(float4*)&wv[i*4] = *(const float4*)&cw[ch0*KC + i*4];
  #pragma unroll
  for (int k=0;k<KC;k++){
    int lk = l - 3 + k;
    if (lk < 0) continue;
    const bf16* row = xpre + ((size_t)bl + (k-3))*CONVDIM + ch0;
    uint4 u = *(const uint4*)row;
    unsigned uu[4]={u.x,u.y,u.z,u.w};
    #pragma unroll
    for (int c2=0;c2<4;c2++){
      float lo = __uint_as_float(uu[c2]<<16);
      float hi = __uint_as_float(uu[c2]&0xffff0000u);
      acc[c2*2]   = fmaf(wv[(c2*2)*4 + k],   lo, acc[c2*2]);
      acc[c2*2+1] = fmaf(wv[(c2*2+1)*4 + k], hi, acc[c2*2+1]);
    }
  }
  unsigned out_u[4];
  #pragma unroll
  for (int c2=0;c2<4;c2++){
    float v0 = acc[c2*2], v1 = acc[c2*2+1];
    v0 = v0 / (1.f + __expf(-v0));
    v1 = v1 / (1.f + __expf(-v1));
    out_u[c2] = pack2bf(v0, v1);
  }
  *(uint4*)(xbc + (size_t)bl*CONVDIM + ch0) = make_uint4(out_u[0],out_u[1],out_u[2],out_u[3]);
}

// ================= SSD chunked scan, pass 1: intra-chunk Y + chunk state T_c =================
// block = (b,h,c); Q=128. GEMMs on MFMA:
//   G[t,s] = C_t.B_s ; W = mask(s<=t) * exp(L_t-L_s) * G  (bf16, LDS)
//   Y[t,p] = sum_s W[t,s] dtx[s,p]          (written to ys)
//   T^T[p,n] = sum_s dtx[s,p] * wB[s,n]     (wB = B_s * exp(L_last-L_s); written to Sst[p][n])
__global__ __launch_bounds__(256) void k_ssd1(const bf16* __restrict__ xbc,
    const float* __restrict__ dtv, const float* __restrict__ A_log,
    bf16* __restrict__ ys, bf16* __restrict__ Sst) {
  int blk = blockIdx.x;
  int c = blk & (NCH-1), h = (blk>>5)&7, b = blk>>8;
  int tid = threadIdx.x;
  int lane = tid & 63, wid = tid >> 6;
  int r = lane & 15, q = lane >> 4;
  size_t rowbase = (size_t)b*L_ + (size_t)c*QCH;
  float eA = __expf(A_log[h]);

  __shared__ __align__(16) bf16 sB[128*128];   // [s][n], cg^(s&15) swizzle
  __shared__ __align__(16) bf16 sC[128*128];   // [t][n]; reused as W[t][s] after G1
  __shared__ __align__(16) bf16 sDX[64*128];   // dtx^T [p][s], cg^(p&15)
  __shared__ __align__(16) bf16 sBT[128*128];  // wB^T [n][s], cg^(n&15)
  __shared__ float sDT[128];
  __shared__ float sL[128];
  __shared__ float sWS[128];
  __shared__ float sWT[2];

  // ---- stage B,C (128 rows x 32 16B-chunks) + dt ----
  #pragma unroll
  for (int i=0;i<16;i++){
    int id = i*256 + tid;
    int row = id >> 5, cg = id & 31;
    uint4 u = *(const uint4*)(xbc + (rowbase+row)*CONVDIM + DI + cg*8);
    if (cg < 16) *(uint4*)&sB[row*128 + ((cg ^ (row&15))<<3)] = u;
    else { int cg2 = cg-16; *(uint4*)&sC[row*128 + ((cg2 ^ (row&15))<<3)] = u; }
  }
  if (tid < 128) sDT[tid] = dtv[(rowbase+tid)*NH + h];
  __syncthreads();

  // ---- inclusive prefix sum of dt -> sL (two waves) ----
  float inc = 0.f;
  if (tid < 128){
    inc = sDT[tid];
    #pragma unroll
    for (int off=1; off<64; off<<=1){
      float u = __shfl_up(inc, off);
      if (lane >= off) inc += u;
    }
    if (lane==63) sWT[wid] = inc;
  }
  __syncthreads();
  if (tid < 128){
    if (wid==1) inc += sWT[0];
    sL[tid] = inc;
  }
  // ---- dtx^T staging: thread=(s=tid>>1, ph=tid&1), 32 p's each ----
  {
    int s = tid >> 1, ph = tid & 1;
    float dts = sDT[s];
    const bf16* xs = xbc + (rowbase+s)*CONVDIM + h*HD + ph*32;
    #pragma unroll
    for (int i8=0;i8<4;i8++){
      ushort4 u0 = *(const ushort4*)(xs + i8*8);
      ushort4 u1 = *(const ushort4*)(xs + i8*8 + 4);
      unsigned short uu[8] = {u0.x,u0.y,u0.z,u0.w,u1.x,u1.y,u1.z,u1.w};
      #pragma unroll
      for (int j=0;j<8;j++){
        int p = ph*32 + i8*8 + j;
        sDX[p*128 + (((s>>3) ^ (p&15))<<3) + (s&7)] = f2bf(dts * bf2f(uu[j]));
      }
    }
  }
  __syncthreads();

  // ---- G1: G = C x B^T, 4 waves, 64x64 quadrants ----
  int wr = wid >> 1, wc = wid & 1;
  f32x4 accG[4][4];
  #pragma unroll
  for (int i=0;i<4;i++)
    #pragma unroll
    for (int j=0;j<4;j++) accG[i][j] = (f32x4){0.f,0.f,0.f,0.f};
  #pragma unroll
  for (int ks=0; ks<4; ks++){
    bf16x8 af[4], bfv[4];
    #pragma unroll
    for (int mf=0;mf<4;mf++){
      int t = wr*64 + mf*16 + r;
      af[mf] = *(const bf16x8*)&sC[t*128 + (((ks*4+q) ^ (t&15))<<3)];
    }
    #pragma unroll
    for (int nf=0;nf<4;nf++){
      int s = wc*64 + nf*16 + r;
      bfv[nf] = *(const bf16x8*)&sB[s*128 + (((ks*4+q) ^ (s&15))<<3)];
    }
    #pragma unroll
    for (int mf=0;mf<4;mf++)
      #pragma unroll
      for (int nf=0;nf<4;nf++)
        accG[mf][nf] = __builtin_amdgcn_mfma_f32_16x16x32_bf16(af[mf], bfv[nf], accG[mf][nf], 0, 0, 0);
  }
  __syncthreads();   // all C reads done -> sC reusable as W

  // ---- W = mask*decay*G -> sC ; sWS = exp(L_last - L_s) ----
  bf16* sW = sC;
  #pragma unroll
  for (int mf=0;mf<4;mf++){
    #pragma unroll
    for (int nf=0;nf<4;nf++){
      int s = wc*64 + nf*16 + r;
      float Ls = sL[s];
      #pragma unroll
      for (int rr=0;rr<4;rr++){
        int t = wr*64 + mf*16 + q*4 + rr;
        float wvv = 0.f;
        if (s <= t) wvv = accG[mf][nf][rr] * __expf(-eA*(sL[t]-Ls));
        sW[t*128 + (((s>>3) ^ (t&15))<<3) + (s&7)] = f2bf(wvv);
      }
    }
  }
  if (tid < 128) sWS[tid] = __expf(-eA*(sL[127]-sL[tid]));
  __syncthreads();

  // ---- BtW staging: thread=(n=tid>>1, ph), read B column, packed b128 writes ----
  {
    int n = tid >> 1, ph = tid & 1;
    #pragma unroll
    for (int i8=0;i8<8;i8++){
      unsigned short vals[8];
      #pragma unroll
      for (int j=0;j<8;j++){
        int s = ph*64 + i8*8 + j;
        float bv = bf2f(sB[s*128 + (((n>>3) ^ (s&15))<<3) + (n&7)]);
        vals[j] = f2bf(bv * sWS[s]);
      }
      int s8 = ph*8 + i8;
      *(uint4*)&sBT[n*128 + ((s8 ^ (n&15))<<3)] = *(const uint4*)vals;
    }
  }
  __syncthreads();

  // ---- G2: Y = W x dtx  (M=128 t, N=64 p, K=128 s); wave tile 64x32 ----
  {
    int wr2 = wid >> 1, wc2 = wid & 1;
    f32x4 accY[4][2];
    #pragma unroll
    for (int i=0;i<4;i++){ accY[i][0]=(f32x4){0.f,0.f,0.f,0.f}; accY[i][1]=(f32x4){0.f,0.f,0.f,0.f}; }
    #pragma unroll
    for (int ks=0; ks<4; ks++){
      bf16x8 af[4], bfv[2];
      #pragma unroll
      for (int mf=0;mf<4;mf++){
        int t = wr2*64 + mf*16 + r;
        af[mf] = *(const bf16x8*)&sW[t*128 + (((ks*4+q) ^ (t&15))<<3)];
      }
      #pragma unroll
      for (int nf=0;nf<2;nf++){
        int p = wc2*32 + nf*16 + r;
        bfv[nf] = *(const bf16x8*)&sDX[p*128 + (((ks*4+q) ^ (p&15))<<3)];
      }
      #pragma unroll
      for (int mf=0;mf<4;mf++)
        #pragma unroll
        for (int nf=0;nf<2;nf++)
          accY[mf][nf] = __builtin_amdgcn_mfma_f32_16x16x32_bf16(af[mf], bfv[nf], accY[mf][nf], 0, 0, 0);
    }
    #pragma unroll
    for (int mf=0;mf<4;mf++){
      #pragma unroll
      for (int nf=0;nf<2;nf++){
        int p = wc2*32 + nf*16 + r;
        #pragma unroll
        for (int rr=0;rr<4;rr++){
          int t = wr2*64 + mf*16 + q*4 + rr;
          ys[(rowbase+t)*DI + h*HD + p] = f2bf(accY[mf][nf][rr]);
        }
      }
    }
  }

  // ---- G3: T^T = dtx^T x BtW  (M=64 p, N=128 n, K=128 s); wave tile 32x64 ----
  {
    int wrp = wid >> 1, wcn = wid & 1;
    f32x4 accT[2][4];
    #pragma unroll
    for (int i=0;i<2;i++)
      #pragma unroll
      for (int j=0;j<4;j++) accT[i][j] = (f32x4){0.f,0.f,0.f,0.f};
    #pragma unroll
    for (int ks=0; ks<4; ks++){
      bf16x8 af[2], bfv[4];
      #pragma unroll
      for (int mf=0;mf<2;mf++){
        int p = wrp*32 + mf*16 + r;
        af[mf] = *(const bf16x8*)&sDX[p*128 + (((ks*4+q) ^ (p&15))<<3)];
      }
      #pragma unroll
      for (int nf=0;nf<4;nf++){
        int n = wcn*64 + nf*16 + r;
        bfv[nf] = *(const bf16x8*)&sBT[n*128 + (((ks*4+q) ^ (n&15))<<3)];
      }
      #pragma unroll
      for (int mf=0;mf<2;mf++)
        #pragma unroll
        for (int nf=0;nf<4;nf++)
          accT[mf][nf] = __builtin_amdgcn_mfma_f32_16x16x32_bf16(af[mf], bfv[nf], accT[mf][nf], 0, 0, 0);
    }
    size_t sb = (((size_t)(b*NH+h))*NCH + c)*8192;
    #pragma unroll
    for (int mf=0;mf<2;mf++){
      #pragma unroll
      for (int nf=0;nf<4;nf++){
        int n = wcn*64 + nf*16 + r;
        #pragma unroll
        for (int rr=0;rr<4;rr++){
          int p = wrp*32 + mf*16 + q*4 + rr;
          Sst[sb + (size_t)p*128 + n] = f2bf(accT[mf][nf][rr]);
        }
      }
    }
  }
}

// ---------------- pass 2: prefix-combine chunk states T_c -> I_c (unchanged) ----------------
template<int NCHT, int QCHT>
__global__ __launch_bounds__(256) void k_scan2(bf16* __restrict__ Sst, const float* __restrict__ dAv) {
  constexpr int SEG = QCHT/16;
  int blk = blockIdx.x;
  int bh = blk>>2, q = blk&3;
  int b = bh>>3, h = bh&7;
  int tid = threadIdx.x;
  __shared__ float sP[NCHT];
  {
    int c = tid / SEG, seg = tid & (SEG-1);
    float prod = 1.f;
    size_t base = ((size_t)b*L_ + c*QCHT + seg*16)*NH + h;
    #pragma unroll
    for (int k=0;k<16;k++) prod *= dAv[base + (size_t)k*NH];
    #pragma unroll
    for (int off=1; off<SEG; off<<=1) prod *= __shfl_xor(prod, off);
    if (seg==0) sP[c] = prod;
  }
  __syncthreads();
  int e0 = q*2048 + tid*8;
  float acc[8];
  #pragma unroll
  for (int j=0;j<8;j++) acc[j]=0.f;
  size_t sbase = (size_t)bh*NCHT*8192 + e0;
  for (int c=0;c<NCHT;c++){
    bf16* ptr = Sst + sbase + (size_t)c*8192;
    uint4 u = *(const uint4*)ptr;
    unsigned int uu[4] = {u.x,u.y,u.z,u.w};
    float tv[8];
    #pragma unroll
    for (int k=0;k<4;k++){
      tv[2*k]   = __uint_as_float(uu[k]<<16);
      tv[2*k+1] = __uint_as_float(uu[k]&0xffff0000u);
    }
    uint4 o;
    o.x = pack2bf(acc[0],acc[1]); o.y = pack2bf(acc[2],acc[3]);
    o.z = pack2bf(acc[4],acc[5]); o.w = pack2bf(acc[6],acc[7]);
    asm volatile("s_waitcnt vmcnt(0)" ::: "memory");
    *(uint4*)ptr = o;
    float P = sP[c];
    #pragma unroll
    for (int j=0;j<8;j++) acc[j] = tv[j] + P*acc[j];
  }
}

// ================= SSD pass 3: Y += A_t * (C x I_c) =================
// block=(b,h,c). M=128 t, N=64 p, K=128 n. A = C_lds, B = I from global Sst[p][n].
__global__ __launch_bounds__(256) void k_ssd3(const bf16* __restrict__ xbc,
    const float* __restrict__ dtv, const float* __restrict__ A_log,
    const bf16* __restrict__ Sst, bf16* __restrict__ ys) {
  int blk = blockIdx.x;
  int c = blk & (NCH-1), h = (blk>>5)&7, b = blk>>8;
  int tid = threadIdx.x;
  int lane = tid & 63, wid = tid >> 6;
  int r = lane & 15, q = lane >> 4;
  size_t rowbase = (size_t)b*L_ + (size_t)c*QCH;
  float eA = __expf(A_log[h]);

  __shared__ __align__(16) bf16 sC[128*128];
  __shared__ float sDT[128];
  __shared__ float sL[128];
  __shared__ float sAt[128];
  __shared__ float sWT[2];

  #pragma unroll
  for (int i=0;i<8;i++){
    int id = i*256 + tid;
    int row = id >> 4, cg = id & 15;
    uint4 u = *(const uint4*)(xbc + (rowbase+row)*CONVDIM + DI + NS + cg*8);
    *(uint4*)&sC[row*128 + ((cg ^ (row&15))<<3)] = u;
  }
  if (tid < 128) sDT[tid] = dtv[(rowbase+tid)*NH + h];
  __syncthreads();
  float inc = 0.f;
  if (tid < 128){
    inc = sDT[tid];
    #pragma unroll
    for (int off=1; off<64; off<<=1){
      float u = __shfl_up(inc, off);
      if (lane >= off) inc += u;
    }
    if (lane==63) sWT[wid] = inc;
  }
  __syncthreads();
  if (tid < 128){
    if (wid==1) inc += sWT[0];
    sL[tid] = inc;
    sAt[tid] = __expf(-eA*inc);
  }
  __syncthreads();

  int wr2 = wid >> 1, wc2 = wid & 1;
  size_t sb = (((size_t)(b*NH+h))*NCH + c)*8192;
  f32x4 accP[4][2];
  #pragma unroll
  for (int i=0;i<4;i++){ accP[i][0]=(f32x4){0.f,0.f,0.f,0.f}; accP[i][1]=(f32x4){0.f,0.f,0.f,0.f}; }
  #pragma unroll
  for (int ks=0; ks<4; ks++){
    bf16x8 af[4], bfv[2];
    #pragma unroll
    for (int mf=0;mf<4;mf++){
      int t = wr2*64 + mf*16 + r;
      af[mf] = *(const bf16x8*)&sC[t*128 + (((ks*4+q) ^ (t&15))<<3)];
    }
    #pragma unroll
    for (int nf=0;nf<2;nf++){
      int p = wc2*32 + nf*16 + r;
      bfv[nf] = *(const bf16x8*)(Sst + sb + (size_t)p*128 + ks*32 + q*8);
    }
    #pragma unroll
    for (int mf=0;mf<4;mf++)
      #pragma unroll
      for (int nf=0;nf<2;nf++)
        accP[mf][nf] = __builtin_amdgcn_mfma_f32_16x16x32_bf16(af[mf], bfv[nf], accP[mf][nf], 0, 0, 0);
  }
  #pragma unroll
  for (int mf=0;mf<4;mf++){
    #pragma unroll
    for (int nf=0;nf<2;nf++){
      int p = wc2*32 + nf*16 + r;
      #pragma unroll
      for (int rr=0;rr<4;rr++){
        int t = wr2*64 + mf*16 + q*4 + rr;
        bf16* yp = ys + (rowbase+t)*DI + h*HD + p;
        *yp = f2bf(bf2f(*yp) + sAt[t]*accP[mf][nf][rr]);
      }
    }
  }
}

// ---------------- y = (ys + D*xh)*silu(z), RMSNorm*w, in place (bf16) ----------------
__global__ __launch_bounds__(256) void k_combine(bf16* __restrict__ ys, const bf16* __restrict__ xbc,
                         const bf16* __restrict__ z, const float* __restrict__ Dp,
                         const float* __restrict__ nw) {
  int bl = blockIdx.x;
  int tid = threadIdx.x;
  bf16* yrow = ys + (size_t)bl*DI;
  const bf16* xrow = xbc + (size_t)bl*CONVDIM;
  const bf16* zrow = z + (size_t)bl*DI;
  float v[2]; float ss = 0.f;
  #pragma unroll
  for (int i=0;i<2;i++) {
    int d = tid + i*256;
    float xh = bf2f(xrow[d]);
    float y = bf2f(yrow[d]) + Dp[d>>6]*xh;
    float zv = bf2f(zrow[d]);
    y *= zv / (1.f + expf(-zv));
    v[i] = y; ss += y*y;
  }
  #pragma unroll
  for (int off=1; off<64; off<<=1) ss += __shfl_xor(ss, off);
  __shared__ float sb[4];
  if ((tid&63)==0) sb[tid>>6]=ss;
  __syncthreads();
  float total = sb[0]+sb[1]+sb[2]+sb[3];
  float scale = rsqrtf(total * (1.f/512.f) + 1e-5f);
  #pragma unroll
  for (int i=0;i<2;i++) {
    int d = tid + i*256;
    yrow[d] = f2bf(v[i]*scale*nw[d]);
  }
}

extern "C" void kernel_launch(void* const* d_in, const int* in_sizes, int n_in,
                              void* d_out, int out_size, void* d_ws, size_t ws_size,
                              hipStream_t stream) {
  const float* x         = (const float*)d_in[0];
  const float* conv_w    = (const float*)d_in[1];
  const float* conv_b    = (const float*)d_in[2];
  const float* bn_gamma  = (const float*)d_in[3];
  const float* bn_beta   = (const float*)d_in[4];
  const float* patch_w   = (const float*)d_in[5];
  const float* patch_b   = (const float*)d_in[6];
  const float* in_proj_w = (const float*)d_in[7];
  const float* conv1d_w  = (const float*)d_in[8];
  const float* conv1d_b  = (const float*)d_in[9];
  const float* dt_bias   = (const float*)d_in[10];
  const float* A_log     = (const float*)d_in[11];
  const float* Dp        = (const float*)d_in[12];
  const float* norm_w    = (const float*)d_in[13];
  const float* out_proj_w= (const float*)d_in[14];
  const float* final_w   = (const float*)d_in[15];
  const float* final_b   = (const float*)d_in[16];
  float* out = (float*)d_out;

  char* Wb = (char*)d_ws;
  float* h_buf = (float*)(Wb + 0);
  bf16*  winb  = (bf16*)(Wb + 0);
  bf16*  woutb = (bf16*)(Wb + 0);
  bf16*  xpost = (bf16*)(Wb + 0);
  bf16*  tok   = (bf16*)(Wb + 50331648);
  bf16*  zbuf  = (bf16*)(Wb + 67108864);
  bf16*  y2b   = (bf16*)(Wb + 67108864);
  bf16*  xpre  = (bf16*)(Wb + 100663296);
  bf16*  ysb   = (bf16*)(Wb + 100663296);
  bf16*  Sst   = (bf16*)(Wb + 134217728);       // 32 MB chunk states (NCH=32)
  float* dtv   = (float*)(Wb + 134217728 + 33554432);
  float* dAv   = dtv + 262144;
  float* stats = dAv + 262144;
  const size_t NEED = 134217728ull + 33554432 + 2097152 + 256;
  if (ws_size < NEED) {
    hipMemsetAsync(d_out, 0, (size_t)out_size*sizeof(float), stream);
    return;
  }

  k_conv1<<<dim3((B_*CMID*HMID*WMID)/256), dim3(256), 0, stream>>>(x, conv_w, conv_b, h_buf);
  k_bnstats<<<dim3(16), dim3(256), 0, stream>>>(h_buf, stats);
  k_bngelu<<<dim3((B_*CMID*HMID*WMID)/256), dim3(256), 0, stream>>>(h_buf, stats, bn_gamma, bn_beta);
  k_patch<<<dim3(MTOK/8), dim3(256), 0, stream>>>(h_buf, patch_w, patch_b, tok);
  k_cvtw<<<dim3((NPADIN*DM)/256), dim3(256), 0, stream>>>(in_proj_w, winb, PROJ, 8, NPADIN*DM);
  k_mgemm<0><<<dim3(MTOK/128, NPADIN/128), dim3(256), 0, stream>>>(tok, winb, DM,
      zbuf, xpre, nullptr, nullptr, dt_bias, A_log, dtv, dAv);
  k_conv1d<<<dim3((MTOK*96)/256), dim3(256), 0, stream>>>(xpre, conv1d_w, conv1d_b, xpost);
  k_ssd1<<<dim3(B_*NH*NCH), dim3(256), 0, stream>>>(xpost, dtv, A_log, ysb, Sst);
  k_scan2<NCH,QCH><<<dim3(B_*NH*4), dim3(256), 0, stream>>>(Sst, dAv);
  k_ssd3<<<dim3(B_*NH*NCH), dim3(256), 0, stream>>>(xpost, dtv, A_log, Sst, ysb);
  k_combine<<<dim3(MTOK), dim3(256), 0, stream>>>(ysb, xpost, zbuf, Dp, norm_w);
  k_cvtw<<<dim3((DM*DI)/256), dim3(256), 0, stream>>>(out_proj_w, woutb, DM, 9, DM*DI);
  k_mgemm<1><<<dim3(MTOK/128, DM/128), dim3(256), 0, stream>>>(ysb, woutb, DI,
      nullptr, nullptr, y2b, tok, nullptr, nullptr, nullptr, nullptr);
  k_gemm<2, bf16><<<dim3(1,512), dim3(256), 0, stream>>>(y2b, final_w, MTOK, 64, DM,
      out, final_b);
}

// Round 7
// 466.512 us; speedup vs baseline: 7.8997x; 1.3141x over previous
//
#include <hip/hip_runtime.h>
#include <math.h>

#define B_  8
#define CIN 3
#define HIN 256
#define WIN 256
#define CMID 16
#define HMID 128
#define WMID 128
#define DM 256
#define L_ 4096
#define DI 512
#define NH 8
#define HD 64
#define NS 128
#define KC 4
#define CONVDIM 768
#define PROJ 1288
#define NPADIN 1408
#define MTOK (B_*L_)
#define QCH 128          // chunk length (SSD)
#define NCH 32           // number of chunks

typedef unsigned short bf16;
typedef __attribute__((ext_vector_type(8))) short bf16x8;
typedef __attribute__((ext_vector_type(4))) float f32x4;

__device__ inline float bf2f(bf16 u) { return __uint_as_float(((unsigned int)u) << 16); }
__device__ inline bf16 f2bf(float f) {
  unsigned int x = __float_as_uint(f);
  return (bf16)((x + 0x7fffu + ((x >> 16) & 1u)) >> 16);
}
__device__ inline unsigned int pack2bf(float a, float b) {
  return (unsigned int)f2bf(a) | ((unsigned int)f2bf(b) << 16);
}

__device__ inline float4 ldA4(const float* p) { return *(const float4*)p; }
__device__ inline float4 ldA4(const bf16* p) {
  ushort4 u = *(const ushort4*)p;
  return make_float4(bf2f(u.x), bf2f(u.y), bf2f(u.z), bf2f(u.w));
}

// ---------------- conv 3x3 stride 2 pad 1 ----------------
__global__ void k_conv1(const float* __restrict__ x, const float* __restrict__ w,
                        const float* __restrict__ bias, float* __restrict__ out) {
  int idx = blockIdx.x*256 + threadIdx.x;
  if (idx >= B_*CMID*HMID*WMID) return;
  int xo = idx & 127, yo = (idx>>7)&127, co = (idx>>14)&15, b = idx>>18;
  float acc = bias[co];
  const float* xb = x + (size_t)b*CIN*HIN*WIN;
  const float* wc = w + co*CIN*9;
  #pragma unroll
  for (int ci=0; ci<CIN; ci++)
    #pragma unroll
    for (int ky=0; ky<3; ky++) {
      int yi = 2*yo - 1 + ky;
      if (yi < 0 || yi >= HIN) continue;
      #pragma unroll
      for (int kx=0; kx<3; kx++) {
        int xi = 2*xo - 1 + kx;
        if (xi < 0 || xi >= WIN) continue;
        acc += xb[(ci*HIN + yi)*WIN + xi] * wc[(ci*3+ky)*3+kx];
      }
    }
  out[idx] = acc;
}

// ---------------- BN stats stage A: 512 blocks, partial (sum,sumsq) per 4K chunk ----------------
__global__ __launch_bounds__(256) void k_bnstatsA(const float* __restrict__ h, float2* __restrict__ part) {
  int blk = blockIdx.x;                 // 512 = 128 (b,c) * 4 chunks
  const float4* base = (const float4*)(h + ((size_t)(blk>>2))*16384 + (blk&3)*4096);
  int tid = threadIdx.x;
  float s=0.f, s2=0.f;
  #pragma unroll
  for (int i=0;i<4;i++){
    float4 v = base[i*256 + tid];
    s += v.x+v.y+v.z+v.w;
    s2 += v.x*v.x + v.y*v.y + v.z*v.z + v.w*v.w;
  }
  #pragma unroll
  for (int off=1; off<64; off<<=1) { s += __shfl_xor(s, off); s2 += __shfl_xor(s2, off); }
  __shared__ float sb[2][4];
  if ((tid&63)==0){ sb[0][tid>>6]=s; sb[1][tid>>6]=s2; }
  __syncthreads();
  if (tid==0) part[blk] = make_float2(sb[0][0]+sb[0][1]+sb[0][2]+sb[0][3],
                                      sb[1][0]+sb[1][1]+sb[1][2]+sb[1][3]);
}

// ---------------- BN stats stage B: one wave combines 32 partials/channel ----------------
__global__ void k_bnstatsB(const float2* __restrict__ part, float* __restrict__ stats) {
  int lane = threadIdx.x;               // 64 threads
  int c = lane >> 2, j0 = lane & 3;
  float s=0.f, s2=0.f;
  #pragma unroll
  for (int j=j0; j<32; j+=4){
    int b = j >> 2, chunk = j & 3;
    float2 p = part[(b*16+c)*4 + chunk];
    s += p.x; s2 += p.y;
  }
  s += __shfl_xor(s,1); s2 += __shfl_xor(s2,1);
  s += __shfl_xor(s,2); s2 += __shfl_xor(s2,2);
  if (j0==0){
    const float inv = 1.f/131072.f;
    float mean = s*inv;
    float var  = s2*inv - mean*mean;
    stats[c]      = mean;
    stats[16 + c] = rsqrtf(var + 1e-5f);
  }
}

// ---------------- patch conv 2x2 s2 (+fused BN+GELU on load) + bias + sincos -> tok ----------------
__global__ __launch_bounds__(256) void k_patch(const float* __restrict__ h, const float* __restrict__ pw,
                       const float* __restrict__ pb, const float* __restrict__ stats,
                       const float* __restrict__ gamma, const float* __restrict__ beta,
                       bf16* __restrict__ tok) {
  int grp = blockIdx.x;
  int b = grp >> 9, g8 = grp & 511;
  int g0 = g8 << 3;
  int gy = g0 >> 6, gx0 = g0 & 63;
  __shared__ float sh[8][64];
  int tid = threadIdx.x;
  {
    int tk = tid >> 5, jj = (tid & 31)*2;
    int ci = jj >> 2, p = (jj >> 1) & 1;
    const float* src = &h[((size_t)(b*CMID+ci)*HMID + 2*gy+p)*WMID + 2*(gx0+tk)];
    float2 xv = *(const float2*)src;
    float mean = stats[ci], rstd = stats[16+ci];
    float sc = rstd*gamma[ci], be = beta[ci] - mean*sc;
    float v0 = xv.x*sc + be;
    float v1 = xv.y*sc + be;
    v0 = 0.5f*v0*(1.f + erff(v0*0.70710678118654752f));
    v1 = 0.5f*v1*(1.f + erff(v1*0.70710678118654752f));
    sh[tk][jj] = v0; sh[tk][jj+1] = v1;
  }
  __syncthreads();
  int d = tid;
  float wr[64];
  #pragma unroll
  for (int i4=0;i4<16;i4++) *(float4*)&wr[i4*4] = *(const float4*)&pw[d*64 + i4*4];
  float bias = pb[d];
  int i = d & 63;
  float omega = expf(-(float)i * (9.210340371976184f/64.f));
  #pragma unroll
  for (int tk=0;tk<8;tk++){
    float acc = bias;
    #pragma unroll
    for (int j=0;j<64;j++) acc = fmaf(sh[tk][j], wr[j], acc);
    float gv = (d < 128) ? (float)(gx0+tk) : (float)gy;
    float ph = gv * omega;
    float pos = (d & 64) ? __cosf(ph) : __sinf(ph);
    tok[((size_t)((b<<12) + g0 + tk))*DM + d] = f2bf(acc + pos);
  }
}

// ---------------- weight f32 -> bf16 (with zero-padding to Npad rows) ----------------
__global__ void k_cvtw(const float* __restrict__ src, bf16* __restrict__ dst,
                       int N, int kshift, int total) {
  int idx = blockIdx.x*256 + threadIdx.x;
  if (idx >= total) return;
  int n = idx >> kshift;
  dst[idx] = (n < N) ? f2bf(src[idx]) : (bf16)0;
}

// ---------------- MFMA bf16 GEMM, 128x128 tile, C[m,n]=sum_k A[m,k]*Bw[n,k] ----------------
template<int EPI>
__global__ __launch_bounds__(256) void k_mgemm(
    const bf16* __restrict__ A, const bf16* __restrict__ Bw, int K,
    bf16* __restrict__ o_z, bf16* __restrict__ o_x,
    bf16* __restrict__ o_y, const bf16* __restrict__ res,
    const float* __restrict__ dt_bias, const float* __restrict__ A_log,
    float* __restrict__ dtv, float* __restrict__ dAv) {
  __shared__ __align__(16) bf16 sA[2][128*32];
  __shared__ __align__(16) bf16 sB[2][128*32];
  int tid = threadIdx.x;
  int lane = tid & 63, wid = tid >> 6;
  int wr = wid >> 1, wc = wid & 1;
  int m0 = blockIdx.x*128, n0 = blockIdx.y*128;
  int nk = K >> 5;
  f32x4 acc[4][4];
  #pragma unroll
  for (int i=0;i<4;i++)
    #pragma unroll
    for (int j=0;j<4;j++)
      acc[i][j] = (f32x4){0.f,0.f,0.f,0.f};

  auto stage = [&](int buf, int ks){
    int kk = ks << 5;
    #pragma unroll
    for (int i=0;i<2;i++){
      int j = i*256 + tid;
      int row = j >> 2, cc = j & 3;
      int kg = cc ^ (row & 3);
      unsigned ldsoff = (unsigned)((i*256 + wid*64) * 16);
      __builtin_amdgcn_global_load_lds(
        (const __attribute__((address_space(1))) void*)(A + (size_t)(m0+row)*K + kk + kg*8),
        (__attribute__((address_space(3))) void*)((char*)&sA[buf][0] + ldsoff), 16, 0, 0);
      __builtin_amdgcn_global_load_lds(
        (const __attribute__((address_space(1))) void*)(Bw + (size_t)(n0+row)*K + kk + kg*8),
        (__attribute__((address_space(3))) void*)((char*)&sB[buf][0] + ldsoff), 16, 0, 0);
    }
  };

  int r = lane & 15, q = lane >> 4;
  int kgo = (q ^ (r & 3)) << 3;

  stage(0, 0);
  for (int ks=0; ks<nk; ++ks){
    int cur = ks & 1;
    __syncthreads();
    if (ks+1 < nk) stage(cur^1, ks+1);
    bf16x8 af[4], bfv[4];
    #pragma unroll
    for (int mf=0;mf<4;mf++){
      int rowm = wr*64 + mf*16 + r;
      af[mf] = *(const bf16x8*)&sA[cur][rowm*32 + kgo];
    }
    #pragma unroll
    for (int nf=0;nf<4;nf++){
      int rown = wc*64 + nf*16 + r;
      bfv[nf] = *(const bf16x8*)&sB[cur][rown*32 + kgo];
    }
    #pragma unroll
    for (int mf=0;mf<4;mf++)
      #pragma unroll
      for (int nf=0;nf<4;nf++)
        acc[mf][nf] = __builtin_amdgcn_mfma_f32_16x16x32_bf16(af[mf], bfv[nf], acc[mf][nf], 0, 0, 0);
  }

  #pragma unroll
  for (int mf=0;mf<4;mf++){
    #pragma unroll
    for (int nf=0;nf<4;nf++){
      int n = n0 + wc*64 + nf*16 + r;
      int mbase = m0 + wr*64 + mf*16 + q*4;
      #pragma unroll
      for (int rr=0;rr<4;rr++){
        int m = mbase + rr;
        float val = acc[mf][nf][rr];
        if (EPI == 0){
          if (n < DI) {
            o_z[(size_t)m*DI + n] = f2bf(val);
          } else if (n < DI + CONVDIM) {
            o_x[(size_t)m*CONVDIM + (n - DI)] = f2bf(val);
          } else if (n < PROJ) {
            int hh = n - (DI + CONVDIM);
            float xv = val + dt_bias[hh];
            float dt = (xv > 20.f) ? xv : log1pf(expf(xv));
            dtv[(size_t)m*NH + hh] = dt;
            dAv[(size_t)m*NH + hh] = expf(-expf(A_log[hh]) * dt);
          }
        } else {
          o_y[(size_t)m*DM + n] = f2bf(val + bf2f(res[(size_t)m*DM + n]));
        }
      }
    }
  }
}

// ---------------- SIMT f32-accum GEMM (final layer): pixel-shuffle epilogue ----------------
template<int EPI, typename TA>
__global__ __launch_bounds__(256) void k_gemm(
    const TA* __restrict__ A, const float* __restrict__ Bw,
    int M, int N, int K,
    float* __restrict__ o_f, const float* __restrict__ bias) {
  __shared__ __align__(16) float As[16][64];
  __shared__ __align__(16) float Bs[16][64];
  int tid = threadIdx.x;
  int tx = tid & 15, ty = tid >> 4;
  int m0 = blockIdx.y*64, n0 = blockIdx.x*64;
  float acc[4][4] = {{0.f}};
  for (int k0=0; k0<K; k0+=16) {
    int rr = tid >> 2;
    int kq = (tid & 3) << 2;
    {
      float4 v = ldA4(A + (size_t)(m0+rr)*K + k0 + kq);
      As[kq+0][rr]=v.x; As[kq+1][rr]=v.y; As[kq+2][rr]=v.z; As[kq+3][rr]=v.w;
    }
    {
      int n = n0 + rr;
      float4 v = make_float4(0.f,0.f,0.f,0.f);
      if (n < N) v = *(const float4*)(Bw + (size_t)n*K + k0 + kq);
      Bs[kq+0][rr]=v.x; Bs[kq+1][rr]=v.y; Bs[kq+2][rr]=v.z; Bs[kq+3][rr]=v.w;
    }
    __syncthreads();
    #pragma unroll
    for (int k=0;k<16;k++) {
      float4 a  = *(const float4*)&As[k][ty*4];
      float4 bb = *(const float4*)&Bs[k][tx*4];
      float av[4] = {a.x,a.y,a.z,a.w};
      float bv[4] = {bb.x,bb.y,bb.z,bb.w};
      #pragma unroll
      for (int i=0;i<4;i++)
        #pragma unroll
        for (int j=0;j<4;j++)
          acc[i][j] = fmaf(av[i], bv[j], acc[i][j]);
    }
    __syncthreads();
  }
  #pragma unroll
  for (int i=0;i<4;i++) {
    int m = m0 + ty*4 + i;
    #pragma unroll
    for (int j=0;j<4;j++) {
      int n = n0 + tx*4 + j;
      if (n < N) {
        float vv = acc[i][j] + bias[n];
        int b = m >> 12, g = m & 4095;
        int gy = g >> 6, gx = g & 63;
        int p = n >> 5, qq = (n>>4)&1, c = n & 15;
        o_f[(((size_t)(b*CMID+c))*HMID + 2*gy+p)*WMID + (2*gx+qq)] = vv;
      }
    }
  }
}

// ---------------- causal depthwise conv1d (KC=4) + bias + silu, 8ch/thread ----------------
__global__ __launch_bounds__(256) void k_conv1d(const bf16* __restrict__ xpre, const float* __restrict__ cw,
                         const float* __restrict__ cb, bf16* __restrict__ xbc) {
  int idx = blockIdx.x*256 + threadIdx.x;
  int gch = idx % 96;
  int bl  = idx / 96;
  int ch0 = gch*8;
  int l = bl & (L_-1);
  float acc[8];
  *(float4*)&acc[0] = *(const float4*)&cb[ch0];
  *(float4*)&acc[4] = *(const float4*)&cb[ch0+4];
  float wv[32];
  #pragma unroll
  for (int i=0;i<8;i++) *(float4*)&wv[i*4] = *(const float4*)&cw[ch0*KC + i*4];
  #pragma unroll
  for (int k=0;k<KC;k++){
    int lk = l - 3 + k;
    if (lk < 0) continue;
    const bf16* row = xpre + ((size_t)bl + (k-3))*CONVDIM + ch0;
    uint4 u = *(const uint4*)row;
    unsigned uu[4]={u.x,u.y,u.z,u.w};
    #pragma unroll
    for (int c2=0;c2<4;c2++){
      float lo = __uint_as_float(uu[c2]<<16);
      float hi = __uint_as_float(uu[c2]&0xffff0000u);
      acc[c2*2]   = fmaf(wv[(c2*2)*4 + k],   lo, acc[c2*2]);
      acc[c2*2+1] = fmaf(wv[(c2*2+1)*4 + k], hi, acc[c2*2+1]);
    }
  }
  unsigned out_u[4];
  #pragma unroll
  for (int c2=0;c2<4;c2++){
    float v0 = acc[c2*2], v1 = acc[c2*2+1];
    v0 = v0 / (1.f + __expf(-v0));
    v1 = v1 / (1.f + __expf(-v1));
    out_u[c2] = pack2bf(v0, v1);
  }
  *(uint4*)(xbc + (size_t)bl*CONVDIM + ch0) = make_uint4(out_u[0],out_u[1],out_u[2],out_u[3]);
}

// ================= SSD chunked scan, pass 1: intra-chunk Y + chunk state T_c =================
__global__ __launch_bounds__(256) void k_ssd1(const bf16* __restrict__ xbc,
    const float* __restrict__ dtv, const float* __restrict__ A_log,
    bf16* __restrict__ ys, bf16* __restrict__ Sst) {
  int blk = blockIdx.x;
  int c = blk & (NCH-1), h = (blk>>5)&7, b = blk>>8;
  int tid = threadIdx.x;
  int lane = tid & 63, wid = tid >> 6;
  int r = lane & 15, q = lane >> 4;
  size_t rowbase = (size_t)b*L_ + (size_t)c*QCH;
  float eA = __expf(A_log[h]);

  __shared__ __align__(16) bf16 sB[128*128];
  __shared__ __align__(16) bf16 sC[128*128];
  __shared__ __align__(16) bf16 sDX[64*128];
  __shared__ __align__(16) bf16 sBT[128*128];
  __shared__ float sDT[128];
  __shared__ float sL[128];
  __shared__ float sWS[128];
  __shared__ float sWT[2];

  #pragma unroll
  for (int i=0;i<16;i++){
    int id = i*256 + tid;
    int row = id >> 5, cg = id & 31;
    uint4 u = *(const uint4*)(xbc + (rowbase+row)*CONVDIM + DI + cg*8);
    if (cg < 16) *(uint4*)&sB[row*128 + ((cg ^ (row&15))<<3)] = u;
    else { int cg2 = cg-16; *(uint4*)&sC[row*128 + ((cg2 ^ (row&15))<<3)] = u; }
  }
  if (tid < 128) sDT[tid] = dtv[(rowbase+tid)*NH + h];
  __syncthreads();

  float inc = 0.f;
  if (tid < 128){
    inc = sDT[tid];
    #pragma unroll
    for (int off=1; off<64; off<<=1){
      float u = __shfl_up(inc, off);
      if (lane >= off) inc += u;
    }
    if (lane==63) sWT[wid] = inc;
  }
  __syncthreads();
  if (tid < 128){
    if (wid==1) inc += sWT[0];
    sL[tid] = inc;
  }
  {
    int s = tid >> 1, ph = tid & 1;
    float dts = sDT[s];
    const bf16* xs = xbc + (rowbase+s)*CONVDIM + h*HD + ph*32;
    #pragma unroll
    for (int i8=0;i8<4;i8++){
      ushort4 u0 = *(const ushort4*)(xs + i8*8);
      ushort4 u1 = *(const ushort4*)(xs + i8*8 + 4);
      unsigned short uu[8] = {u0.x,u0.y,u0.z,u0.w,u1.x,u1.y,u1.z,u1.w};
      #pragma unroll
      for (int j=0;j<8;j++){
        int p = ph*32 + i8*8 + j;
        sDX[p*128 + (((s>>3) ^ (p&15))<<3) + (s&7)] = f2bf(dts * bf2f(uu[j]));
      }
    }
  }
  __syncthreads();

  int wr = wid >> 1, wc = wid & 1;
  f32x4 accG[4][4];
  #pragma unroll
  for (int i=0;i<4;i++)
    #pragma unroll
    for (int j=0;j<4;j++) accG[i][j] = (f32x4){0.f,0.f,0.f,0.f};
  #pragma unroll
  for (int ks=0; ks<4; ks++){
    bf16x8 af[4], bfv[4];
    #pragma unroll
    for (int mf=0;mf<4;mf++){
      int t = wr*64 + mf*16 + r;
      af[mf] = *(const bf16x8*)&sC[t*128 + (((ks*4+q) ^ (t&15))<<3)];
    }
    #pragma unroll
    for (int nf=0;nf<4;nf++){
      int s = wc*64 + nf*16 + r;
      bfv[nf] = *(const bf16x8*)&sB[s*128 + (((ks*4+q) ^ (s&15))<<3)];
    }
    #pragma unroll
    for (int mf=0;mf<4;mf++)
      #pragma unroll
      for (int nf=0;nf<4;nf++)
        accG[mf][nf] = __builtin_amdgcn_mfma_f32_16x16x32_bf16(af[mf], bfv[nf], accG[mf][nf], 0, 0, 0);
  }
  __syncthreads();

  bf16* sW = sC;
  #pragma unroll
  for (int mf=0;mf<4;mf++){
    #pragma unroll
    for (int nf=0;nf<4;nf++){
      int s = wc*64 + nf*16 + r;
      float Ls = sL[s];
      #pragma unroll
      for (int rr=0;rr<4;rr++){
        int t = wr*64 + mf*16 + q*4 + rr;
        float wvv = 0.f;
        if (s <= t) wvv = accG[mf][nf][rr] * __expf(-eA*(sL[t]-Ls));
        sW[t*128 + (((s>>3) ^ (t&15))<<3) + (s&7)] = f2bf(wvv);
      }
    }
  }
  if (tid < 128) sWS[tid] = __expf(-eA*(sL[127]-sL[tid]));
  __syncthreads();

  {
    int n = tid >> 1, ph = tid & 1;
    #pragma unroll
    for (int i8=0;i8<8;i8++){
      unsigned short vals[8];
      #pragma unroll
      for (int j=0;j<8;j++){
        int s = ph*64 + i8*8 + j;
        float bv = bf2f(sB[s*128 + (((n>>3) ^ (s&15))<<3) + (n&7)]);
        vals[j] = f2bf(bv * sWS[s]);
      }
      int s8 = ph*8 + i8;
      *(uint4*)&sBT[n*128 + ((s8 ^ (n&15))<<3)] = *(const uint4*)vals;
    }
  }
  __syncthreads();

  {
    int wr2 = wid >> 1, wc2 = wid & 1;
    f32x4 accY[4][2];
    #pragma unroll
    for (int i=0;i<4;i++){ accY[i][0]=(f32x4){0.f,0.f,0.f,0.f}; accY[i][1]=(f32x4){0.f,0.f,0.f,0.f}; }
    #pragma unroll
    for (int ks=0; ks<4; ks++){
      bf16x8 af[4], bfv[2];
      #pragma unroll
      for (int mf=0;mf<4;mf++){
        int t = wr2*64 + mf*16 + r;
        af[mf] = *(const bf16x8*)&sW[t*128 + (((ks*4+q) ^ (t&15))<<3)];
      }
      #pragma unroll
      for (int nf=0;nf<2;nf++){
        int p = wc2*32 + nf*16 + r;
        bfv[nf] = *(const bf16x8*)&sDX[p*128 + (((ks*4+q) ^ (p&15))<<3)];
      }
      #pragma unroll
      for (int mf=0;mf<4;mf++)
        #pragma unroll
        for (int nf=0;nf<2;nf++)
          accY[mf][nf] = __builtin_amdgcn_mfma_f32_16x16x32_bf16(af[mf], bfv[nf], accY[mf][nf], 0, 0, 0);
    }
    #pragma unroll
    for (int mf=0;mf<4;mf++){
      #pragma unroll
      for (int nf=0;nf<2;nf++){
        int p = wc2*32 + nf*16 + r;
        #pragma unroll
        for (int rr=0;rr<4;rr++){
          int t = wr2*64 + mf*16 + q*4 + rr;
          ys[(rowbase+t)*DI + h*HD + p] = f2bf(accY[mf][nf][rr]);
        }
      }
    }
  }

  {
    int wrp = wid >> 1, wcn = wid & 1;
    f32x4 accT[2][4];
    #pragma unroll
    for (int i=0;i<2;i++)
      #pragma unroll
      for (int j=0;j<4;j++) accT[i][j] = (f32x4){0.f,0.f,0.f,0.f};
    #pragma unroll
    for (int ks=0; ks<4; ks++){
      bf16x8 af[2], bfv[4];
      #pragma unroll
      for (int mf=0;mf<2;mf++){
        int p = wrp*32 + mf*16 + r;
        af[mf] = *(const bf16x8*)&sDX[p*128 + (((ks*4+q) ^ (p&15))<<3)];
      }
      #pragma unroll
      for (int nf=0;nf<4;nf++){
        int n = wcn*64 + nf*16 + r;
        bfv[nf] = *(const bf16x8*)&sBT[n*128 + (((ks*4+q) ^ (n&15))<<3)];
      }
      #pragma unroll
      for (int mf=0;mf<2;mf++)
        #pragma unroll
        for (int nf=0;nf<4;nf++)
          accT[mf][nf] = __builtin_amdgcn_mfma_f32_16x16x32_bf16(af[mf], bfv[nf], accT[mf][nf], 0, 0, 0);
    }
    size_t sb = (((size_t)(b*NH+h))*NCH + c)*8192;
    #pragma unroll
    for (int mf=0;mf<2;mf++){
      #pragma unroll
      for (int nf=0;nf<4;nf++){
        int n = wcn*64 + nf*16 + r;
        #pragma unroll
        for (int rr=0;rr<4;rr++){
          int p = wrp*32 + mf*16 + q*4 + rr;
          Sst[sb + (size_t)p*128 + n] = f2bf(accT[mf][nf][rr]);
        }
      }
    }
  }
}

// ---------------- pass 2: prefix-combine chunk states T_c -> I_c ----------------
template<int NCHT, int QCHT>
__global__ __launch_bounds__(256) void k_scan2(bf16* __restrict__ Sst, const float* __restrict__ dAv) {
  constexpr int SEG = QCHT/16;
  int blk = blockIdx.x;
  int bh = blk>>2, q = blk&3;
  int b = bh>>3, h = bh&7;
  int tid = threadIdx.x;
  __shared__ float sP[NCHT];
  {
    int c = tid / SEG, seg = tid & (SEG-1);
    float prod = 1.f;
    size_t base = ((size_t)b*L_ + c*QCHT + seg*16)*NH + h;
    #pragma unroll
    for (int k=0;k<16;k++) prod *= dAv[base + (size_t)k*NH];
    #pragma unroll
    for (int off=1; off<SEG; off<<=1) prod *= __shfl_xor(prod, off);
    if (seg==0) sP[c] = prod;
  }
  __syncthreads();
  int e0 = q*2048 + tid*8;
  float acc[8];
  #pragma unroll
  for (int j=0;j<8;j++) acc[j]=0.f;
  size_t sbase = (size_t)bh*NCHT*8192 + e0;
  for (int c=0;c<NCHT;c++){
    bf16* ptr = Sst + sbase + (size_t)c*8192;
    uint4 u = *(const uint4*)ptr;
    unsigned int uu[4] = {u.x,u.y,u.z,u.w};
    float tv[8];
    #pragma unroll
    for (int k=0;k<4;k++){
      tv[2*k]   = __uint_as_float(uu[k]<<16);
      tv[2*k+1] = __uint_as_float(uu[k]&0xffff0000u);
    }
    uint4 o;
    o.x = pack2bf(acc[0],acc[1]); o.y = pack2bf(acc[2],acc[3]);
    o.z = pack2bf(acc[4],acc[5]); o.w = pack2bf(acc[6],acc[7]);
    asm volatile("s_waitcnt vmcnt(0)" ::: "memory");
    *(uint4*)ptr = o;
    float P = sP[c];
    #pragma unroll
    for (int j=0;j<8;j++) acc[j] = tv[j] + P*acc[j];
  }
}

// ================= SSD pass 3: Y += A_t * (C x I_c) =================
__global__ __launch_bounds__(256) void k_ssd3(const bf16* __restrict__ xbc,
    const float* __restrict__ dtv, const float* __restrict__ A_log,
    const bf16* __restrict__ Sst, bf16* __restrict__ ys) {
  int blk = blockIdx.x;
  int c = blk & (NCH-1), h = (blk>>5)&7, b = blk>>8;
  int tid = threadIdx.x;
  int lane = tid & 63, wid = tid >> 6;
  int r = lane & 15, q = lane >> 4;
  size_t rowbase = (size_t)b*L_ + (size_t)c*QCH;
  float eA = __expf(A_log[h]);

  __shared__ __align__(16) bf16 sC[128*128];
  __shared__ float sDT[128];
  __shared__ float sL[128];
  __shared__ float sAt[128];
  __shared__ float sWT[2];

  #pragma unroll
  for (int i=0;i<8;i++){
    int id = i*256 + tid;
    int row = id >> 4, cg = id & 15;
    uint4 u = *(const uint4*)(xbc + (rowbase+row)*CONVDIM + DI + NS + cg*8);
    *(uint4*)&sC[row*128 + ((cg ^ (row&15))<<3)] = u;
  }
  if (tid < 128) sDT[tid] = dtv[(rowbase+tid)*NH + h];
  __syncthreads();
  float inc = 0.f;
  if (tid < 128){
    inc = sDT[tid];
    #pragma unroll
    for (int off=1; off<64; off<<=1){
      float u = __shfl_up(inc, off);
      if (lane >= off) inc += u;
    }
    if (lane==63) sWT[wid] = inc;
  }
  __syncthreads();
  if (tid < 128){
    if (wid==1) inc += sWT[0];
    sL[tid] = inc;
    sAt[tid] = __expf(-eA*inc);
  }
  __syncthreads();

  int wr2 = wid >> 1, wc2 = wid & 1;
  size_t sb = (((size_t)(b*NH+h))*NCH + c)*8192;
  f32x4 accP[4][2];
  #pragma unroll
  for (int i=0;i<4;i++){ accP[i][0]=(f32x4){0.f,0.f,0.f,0.f}; accP[i][1]=(f32x4){0.f,0.f,0.f,0.f}; }
  #pragma unroll
  for (int ks=0; ks<4; ks++){
    bf16x8 af[4], bfv[2];
    #pragma unroll
    for (int mf=0;mf<4;mf++){
      int t = wr2*64 + mf*16 + r;
      af[mf] = *(const bf16x8*)&sC[t*128 + (((ks*4+q) ^ (t&15))<<3)];
    }
    #pragma unroll
    for (int nf=0;nf<2;nf++){
      int p = wc2*32 + nf*16 + r;
      bfv[nf] = *(const bf16x8*)(Sst + sb + (size_t)p*128 + ks*32 + q*8);
    }
    #pragma unroll
    for (int mf=0;mf<4;mf++)
      #pragma unroll
      for (int nf=0;nf<2;nf++)
        accP[mf][nf] = __builtin_amdgcn_mfma_f32_16x16x32_bf16(af[mf], bfv[nf], accP[mf][nf], 0, 0, 0);
  }
  #pragma unroll
  for (int mf=0;mf<4;mf++){
    #pragma unroll
    for (int nf=0;nf<2;nf++){
      int p = wc2*32 + nf*16 + r;
      #pragma unroll
      for (int rr=0;rr<4;rr++){
        int t = wr2*64 + mf*16 + q*4 + rr;
        bf16* yp = ys + (rowbase+t)*DI + h*HD + p;
        *yp = f2bf(bf2f(*yp) + sAt[t]*accP[mf][nf][rr]);
      }
    }
  }
}

// ---------------- y = (ys + D*xh)*silu(z), RMSNorm*w, in place (bf16) ----------------
__global__ __launch_bounds__(256) void k_combine(bf16* __restrict__ ys, const bf16* __restrict__ xbc,
                         const bf16* __restrict__ z, const float* __restrict__ Dp,
                         const float* __restrict__ nw) {
  int bl = blockIdx.x;
  int tid = threadIdx.x;
  bf16* yrow = ys + (size_t)bl*DI;
  const bf16* xrow = xbc + (size_t)bl*CONVDIM;
  const bf16* zrow = z + (size_t)bl*DI;
  float v[2]; float ss = 0.f;
  #pragma unroll
  for (int i=0;i<2;i++) {
    int d = tid + i*256;
    float xh = bf2f(xrow[d]);
    float y = bf2f(yrow[d]) + Dp[d>>6]*xh;
    float zv = bf2f(zrow[d]);
    y *= zv / (1.f + expf(-zv));
    v[i] = y; ss += y*y;
  }
  #pragma unroll
  for (int off=1; off<64; off<<=1) ss += __shfl_xor(ss, off);
  __shared__ float sb[4];
  if ((tid&63)==0) sb[tid>>6]=ss;
  __syncthreads();
  float total = sb[0]+sb[1]+sb[2]+sb[3];
  float scale = rsqrtf(total * (1.f/512.f) + 1e-5f);
  #pragma unroll
  for (int i=0;i<2;i++) {
    int d = tid + i*256;
    yrow[d] = f2bf(v[i]*scale*nw[d]);
  }
}

extern "C" void kernel_launch(void* const* d_in, const int* in_sizes, int n_in,
                              void* d_out, int out_size, void* d_ws, size_t ws_size,
                              hipStream_t stream) {
  const float* x         = (const float*)d_in[0];
  const float* conv_w    = (const float*)d_in[1];
  const float* conv_b    = (const float*)d_in[2];
  const float* bn_gamma  = (const float*)d_in[3];
  const float* bn_beta   = (const float*)d_in[4];
  const float* patch_w   = (const float*)d_in[5];
  const float* patch_b   = (const float*)d_in[6];
  const float* in_proj_w = (const float*)d_in[7];
  const float* conv1d_w  = (const float*)d_in[8];
  const float* conv1d_b  = (const float*)d_in[9];
  const float* dt_bias   = (const float*)d_in[10];
  const float* A_log     = (const float*)d_in[11];
  const float* Dp        = (const float*)d_in[12];
  const float* norm_w    = (const float*)d_in[13];
  const float* out_proj_w= (const float*)d_in[14];
  const float* final_w   = (const float*)d_in[15];
  const float* final_b   = (const float*)d_in[16];
  float* out = (float*)d_out;

  char* Wb = (char*)d_ws;
  float* h_buf = (float*)(Wb + 0);
  bf16*  winb  = (bf16*)(Wb + 0);
  bf16*  woutb = (bf16*)(Wb + 0);
  bf16*  xpost = (bf16*)(Wb + 0);
  float2* part = (float2*)(Wb + 50331648);     // 4 KB partials in tok region (pre-patch)
  bf16*  tok   = (bf16*)(Wb + 50331648);
  bf16*  zbuf  = (bf16*)(Wb + 67108864);
  bf16*  y2b   = (bf16*)(Wb + 67108864);
  bf16*  xpre  = (bf16*)(Wb + 100663296);
  bf16*  ysb   = (bf16*)(Wb + 100663296);
  bf16*  Sst   = (bf16*)(Wb + 134217728);       // 32 MB chunk states (NCH=32)
  float* dtv   = (float*)(Wb + 134217728 + 33554432);
  float* dAv   = dtv + 262144;
  float* stats = dAv + 262144;
  const size_t NEED = 134217728ull + 33554432 + 2097152 + 256;
  if (ws_size < NEED) {
    hipMemsetAsync(d_out, 0, (size_t)out_size*sizeof(float), stream);
    return;
  }

  k_conv1<<<dim3((B_*CMID*HMID*WMID)/256), dim3(256), 0, stream>>>(x, conv_w, conv_b, h_buf);
  k_bnstatsA<<<dim3(512), dim3(256), 0, stream>>>(h_buf, part);
  k_bnstatsB<<<dim3(1), dim3(64), 0, stream>>>(part, stats);
  k_patch<<<dim3(MTOK/8), dim3(256), 0, stream>>>(h_buf, patch_w, patch_b, stats, bn_gamma, bn_beta, tok);
  k_cvtw<<<dim3((NPADIN*DM)/256), dim3(256), 0, stream>>>(in_proj_w, winb, PROJ, 8, NPADIN*DM);
  k_mgemm<0><<<dim3(MTOK/128, NPADIN/128), dim3(256), 0, stream>>>(tok, winb, DM,
      zbuf, xpre, nullptr, nullptr, dt_bias, A_log, dtv, dAv);
  k_conv1d<<<dim3((MTOK*96)/256), dim3(256), 0, stream>>>(xpre, conv1d_w, conv1d_b, xpost);
  k_ssd1<<<dim3(B_*NH*NCH), dim3(256), 0, stream>>>(xpost, dtv, A_log, ysb, Sst);
  k_scan2<NCH,QCH><<<dim3(B_*NH*4), dim3(256), 0, stream>>>(Sst, dAv);
  k_ssd3<<<dim3(B_*NH*NCH), dim3(256), 0, stream>>>(xpost, dtv, A_log, Sst, ysb);
  k_combine<<<dim3(MTOK), dim3(256), 0, stream>>>(ysb, xpost, zbuf, Dp, norm_w);
  k_cvtw<<<dim3((DM*DI)/256), dim3(256), 0, stream>>>(out_proj_w, woutb, DM, 9, DM*DI);
  k_mgemm<1><<<dim3(MTOK/128, DM/128), dim3(256), 0, stream>>>(ysb, woutb, DI,
      nullptr, nullptr, y2b, tok, nullptr, nullptr, nullptr, nullptr);
  k_gemm<2, bf16><<<dim3(1,512), dim3(256), 0, stream>>>(y2b, final_w, MTOK, 64, DM,
      out, final_b);
}

// Round 8
// 383.763 us; speedup vs baseline: 9.6031x; 1.2156x over previous
//
#include <hip/hip_runtime.h>
#include <math.h>

#define B_  8
#define CIN 3
#define HIN 256
#define WIN 256
#define CMID 16
#define HMID 128
#define WMID 128
#define DM 256
#define L_ 4096
#define DI 512
#define NH 8
#define HD 64
#define NS 128
#define KC 4
#define CONVDIM 768
#define PROJ 1288
#define NPADIN 1408
#define MTOK (B_*L_)
#define QCH 128          // chunk length (SSD)
#define NCH 32           // number of chunks

typedef unsigned short bf16;
typedef __attribute__((ext_vector_type(8))) short bf16x8;
typedef __attribute__((ext_vector_type(4))) float f32x4;

__device__ inline float bf2f(bf16 u) { return __uint_as_float(((unsigned int)u) << 16); }
__device__ inline bf16 f2bf(float f) {
  unsigned int x = __float_as_uint(f);
  return (bf16)((x + 0x7fffu + ((x >> 16) & 1u)) >> 16);
}
__device__ inline unsigned int pack2bf(float a, float b) {
  return (unsigned int)f2bf(a) | ((unsigned int)f2bf(b) << 16);
}

// ---------------- conv 3x3 stride 2 pad 1 ----------------
__global__ void k_conv1(const float* __restrict__ x, const float* __restrict__ w,
                        const float* __restrict__ bias, float* __restrict__ out) {
  int idx = blockIdx.x*256 + threadIdx.x;
  if (idx >= B_*CMID*HMID*WMID) return;
  int xo = idx & 127, yo = (idx>>7)&127, co = (idx>>14)&15, b = idx>>18;
  float acc = bias[co];
  const float* xb = x + (size_t)b*CIN*HIN*WIN;
  const float* wc = w + co*CIN*9;
  #pragma unroll
  for (int ci=0; ci<CIN; ci++)
    #pragma unroll
    for (int ky=0; ky<3; ky++) {
      int yi = 2*yo - 1 + ky;
      if (yi < 0 || yi >= HIN) continue;
      #pragma unroll
      for (int kx=0; kx<3; kx++) {
        int xi = 2*xo - 1 + kx;
        if (xi < 0 || xi >= WIN) continue;
        acc += xb[(ci*HIN + yi)*WIN + xi] * wc[(ci*3+ky)*3+kx];
      }
    }
  out[idx] = acc;
}

// ---------------- BN stats stage A ----------------
__global__ __launch_bounds__(256) void k_bnstatsA(const float* __restrict__ h, float2* __restrict__ part) {
  int blk = blockIdx.x;
  const float4* base = (const float4*)(h + ((size_t)(blk>>2))*16384 + (blk&3)*4096);
  int tid = threadIdx.x;
  float s=0.f, s2=0.f;
  #pragma unroll
  for (int i=0;i<4;i++){
    float4 v = base[i*256 + tid];
    s += v.x+v.y+v.z+v.w;
    s2 += v.x*v.x + v.y*v.y + v.z*v.z + v.w*v.w;
  }
  #pragma unroll
  for (int off=1; off<64; off<<=1) { s += __shfl_xor(s, off); s2 += __shfl_xor(s2, off); }
  __shared__ float sb[2][4];
  if ((tid&63)==0){ sb[0][tid>>6]=s; sb[1][tid>>6]=s2; }
  __syncthreads();
  if (tid==0) part[blk] = make_float2(sb[0][0]+sb[0][1]+sb[0][2]+sb[0][3],
                                      sb[1][0]+sb[1][1]+sb[1][2]+sb[1][3]);
}

// ---------------- BN stats stage B ----------------
__global__ void k_bnstatsB(const float2* __restrict__ part, float* __restrict__ stats) {
  int lane = threadIdx.x;
  int c = lane >> 2, j0 = lane & 3;
  float s=0.f, s2=0.f;
  #pragma unroll
  for (int j=j0; j<32; j+=4){
    int b = j >> 2, chunk = j & 3;
    float2 p = part[(b*16+c)*4 + chunk];
    s += p.x; s2 += p.y;
  }
  s += __shfl_xor(s,1); s2 += __shfl_xor(s2,1);
  s += __shfl_xor(s,2); s2 += __shfl_xor(s2,2);
  if (j0==0){
    const float inv = 1.f/131072.f;
    float mean = s*inv;
    float var  = s2*inv - mean*mean;
    stats[c]      = mean;
    stats[16 + c] = rsqrtf(var + 1e-5f);
  }
}

// ---------------- patch conv 2x2 s2 (+fused BN+GELU) + bias + sincos -> tok ----------------
__global__ __launch_bounds__(256) void k_patch(const float* __restrict__ h, const float* __restrict__ pw,
                       const float* __restrict__ pb, const float* __restrict__ stats,
                       const float* __restrict__ gamma, const float* __restrict__ beta,
                       bf16* __restrict__ tok) {
  int grp = blockIdx.x;
  int b = grp >> 9, g8 = grp & 511;
  int g0 = g8 << 3;
  int gy = g0 >> 6, gx0 = g0 & 63;
  __shared__ float sh[8][64];
  int tid = threadIdx.x;
  {
    int tk = tid >> 5, jj = (tid & 31)*2;
    int ci = jj >> 2, p = (jj >> 1) & 1;
    const float* src = &h[((size_t)(b*CMID+ci)*HMID + 2*gy+p)*WMID + 2*(gx0+tk)];
    float2 xv = *(const float2*)src;
    float mean = stats[ci], rstd = stats[16+ci];
    float sc = rstd*gamma[ci], be = beta[ci] - mean*sc;
    float v0 = xv.x*sc + be;
    float v1 = xv.y*sc + be;
    v0 = 0.5f*v0*(1.f + erff(v0*0.70710678118654752f));
    v1 = 0.5f*v1*(1.f + erff(v1*0.70710678118654752f));
    sh[tk][jj] = v0; sh[tk][jj+1] = v1;
  }
  __syncthreads();
  int d = tid;
  float wr[64];
  #pragma unroll
  for (int i4=0;i4<16;i4++) *(float4*)&wr[i4*4] = *(const float4*)&pw[d*64 + i4*4];
  float bias = pb[d];
  int i = d & 63;
  float omega = expf(-(float)i * (9.210340371976184f/64.f));
  #pragma unroll
  for (int tk=0;tk<8;tk++){
    float acc = bias;
    #pragma unroll
    for (int j=0;j<64;j++) acc = fmaf(sh[tk][j], wr[j], acc);
    float gv = (d < 128) ? (float)(gx0+tk) : (float)gy;
    float ph = gv * omega;
    float pos = (d & 64) ? __cosf(ph) : __sinf(ph);
    tok[((size_t)((b<<12) + g0 + tk))*DM + d] = f2bf(acc + pos);
  }
}

// ---------------- weight f32 -> bf16 (with zero-padding to Npad rows) ----------------
__global__ void k_cvtw(const float* __restrict__ src, bf16* __restrict__ dst,
                       int N, int kshift, int total) {
  int idx = blockIdx.x*256 + threadIdx.x;
  if (idx >= total) return;
  int n = idx >> kshift;
  dst[idx] = (n < N) ? f2bf(src[idx]) : (bf16)0;
}

// ---------------- MFMA bf16 GEMM, 128x128 tile, C[m,n]=sum_k A[m,k]*Bw[n,k] ----------------
// EPI 0: in_proj routing; EPI 1: +res -> o_y; EPI 2: +fbias, pixel-shuffle scatter -> o_f
template<int EPI>
__global__ __launch_bounds__(256) void k_mgemm(
    const bf16* __restrict__ A, const bf16* __restrict__ Bw, int K,
    bf16* __restrict__ o_z, bf16* __restrict__ o_x,
    bf16* __restrict__ o_y, const bf16* __restrict__ res,
    const float* __restrict__ dt_bias, const float* __restrict__ A_log,
    float* __restrict__ dtv, float* __restrict__ dAv,
    float* __restrict__ o_f, const float* __restrict__ fbias) {
  __shared__ __align__(16) bf16 sA[2][128*32];
  __shared__ __align__(16) bf16 sB[2][128*32];
  int tid = threadIdx.x;
  int lane = tid & 63, wid = tid >> 6;
  int wr = wid >> 1, wc = wid & 1;
  int m0 = blockIdx.x*128, n0 = blockIdx.y*128;
  int nk = K >> 5;
  f32x4 acc[4][4];
  #pragma unroll
  for (int i=0;i<4;i++)
    #pragma unroll
    for (int j=0;j<4;j++)
      acc[i][j] = (f32x4){0.f,0.f,0.f,0.f};

  auto stage = [&](int buf, int ks){
    int kk = ks << 5;
    #pragma unroll
    for (int i=0;i<2;i++){
      int j = i*256 + tid;
      int row = j >> 2, cc = j & 3;
      int kg = cc ^ (row & 3);
      unsigned ldsoff = (unsigned)((i*256 + wid*64) * 16);
      __builtin_amdgcn_global_load_lds(
        (const __attribute__((address_space(1))) void*)(A + (size_t)(m0+row)*K + kk + kg*8),
        (__attribute__((address_space(3))) void*)((char*)&sA[buf][0] + ldsoff), 16, 0, 0);
      __builtin_amdgcn_global_load_lds(
        (const __attribute__((address_space(1))) void*)(Bw + (size_t)(n0+row)*K + kk + kg*8),
        (__attribute__((address_space(3))) void*)((char*)&sB[buf][0] + ldsoff), 16, 0, 0);
    }
  };

  int r = lane & 15, q = lane >> 4;
  int kgo = (q ^ (r & 3)) << 3;

  stage(0, 0);
  for (int ks=0; ks<nk; ++ks){
    int cur = ks & 1;
    __syncthreads();
    if (ks+1 < nk) stage(cur^1, ks+1);
    bf16x8 af[4], bfv[4];
    #pragma unroll
    for (int mf=0;mf<4;mf++){
      int rowm = wr*64 + mf*16 + r;
      af[mf] = *(const bf16x8*)&sA[cur][rowm*32 + kgo];
    }
    #pragma unroll
    for (int nf=0;nf<4;nf++){
      int rown = wc*64 + nf*16 + r;
      bfv[nf] = *(const bf16x8*)&sB[cur][rown*32 + kgo];
    }
    #pragma unroll
    for (int mf=0;mf<4;mf++)
      #pragma unroll
      for (int nf=0;nf<4;nf++)
        acc[mf][nf] = __builtin_amdgcn_mfma_f32_16x16x32_bf16(af[mf], bfv[nf], acc[mf][nf], 0, 0, 0);
  }

  #pragma unroll
  for (int mf=0;mf<4;mf++){
    #pragma unroll
    for (int nf=0;nf<4;nf++){
      int n = n0 + wc*64 + nf*16 + r;
      int mbase = m0 + wr*64 + mf*16 + q*4;
      #pragma unroll
      for (int rr=0;rr<4;rr++){
        int m = mbase + rr;
        float val = acc[mf][nf][rr];
        if (EPI == 0){
          if (n < DI) {
            o_z[(size_t)m*DI + n] = f2bf(val);
          } else if (n < DI + CONVDIM) {
            o_x[(size_t)m*CONVDIM + (n - DI)] = f2bf(val);
          } else if (n < PROJ) {
            int hh = n - (DI + CONVDIM);
            float xv = val + dt_bias[hh];
            float dt = (xv > 20.f) ? xv : log1pf(expf(xv));
            dtv[(size_t)m*NH + hh] = dt;
            dAv[(size_t)m*NH + hh] = expf(-expf(A_log[hh]) * dt);
          }
        } else if (EPI == 1) {
          o_y[(size_t)m*DM + n] = f2bf(val + bf2f(res[(size_t)m*DM + n]));
        } else {
          if (n < 64) {
            float vv = val + fbias[n];
            int b = m >> 12, g = m & 4095;
            int gy = g >> 6, gx = g & 63;
            int p = n >> 5, qq = (n>>4)&1, cc2 = n & 15;
            o_f[(((size_t)(b*CMID+cc2))*HMID + 2*gy+p)*WMID + (2*gx+qq)] = vv;
          }
        }
      }
    }
  }
}

// ---------------- causal depthwise conv1d (KC=4) + bias + silu ----------------
// 8 tokens x 8 channels per thread, sliding-window row reuse, weights loaded once.
__global__ __launch_bounds__(256) void k_conv1d(const bf16* __restrict__ xpre, const float* __restrict__ cw,
                         const float* __restrict__ cb, bf16* __restrict__ xbc) {
  int idx = blockIdx.x*256 + threadIdx.x;     // (MTOK/8)*96 threads
  int gch = idx % 96;
  int tb  = idx / 96;
  int ch0 = gch*8;
  int bl0 = tb*8;
  int l0 = bl0 & (L_-1);
  float wv[32];
  #pragma unroll
  for (int i=0;i<8;i++) *(float4*)&wv[i*4] = *(const float4*)&cw[ch0*KC + i*4];
  float bs[8];
  *(float4*)&bs[0] = *(const float4*)&cb[ch0];
  *(float4*)&bs[4] = *(const float4*)&cb[ch0+4];
  uint4 rows[11];
  #pragma unroll
  for (int j=0;j<11;j++){
    int lk = l0 - 3 + j;
    if (lk < 0) rows[j] = make_uint4(0u,0u,0u,0u);
    else rows[j] = *(const uint4*)(xpre + ((size_t)bl0 - 3 + j)*CONVDIM + ch0);
  }
  #pragma unroll
  for (int t=0;t<8;t++){
    float acc[8];
    #pragma unroll
    for (int i=0;i<8;i++) acc[i] = bs[i];
    #pragma unroll
    for (int k=0;k<KC;k++){
      uint4 u = rows[t+k];
      unsigned uu[4]={u.x,u.y,u.z,u.w};
      #pragma unroll
      for (int c2=0;c2<4;c2++){
        float lo = __uint_as_float(uu[c2]<<16);
        float hi = __uint_as_float(uu[c2]&0xffff0000u);
        acc[c2*2]   = fmaf(wv[(c2*2)*4 + k],   lo, acc[c2*2]);
        acc[c2*2+1] = fmaf(wv[(c2*2+1)*4 + k], hi, acc[c2*2+1]);
      }
    }
    unsigned ou[4];
    #pragma unroll
    for (int c2=0;c2<4;c2++){
      float v0 = acc[c2*2], v1 = acc[c2*2+1];
      v0 = v0 / (1.f + __expf(-v0));
      v1 = v1 / (1.f + __expf(-v1));
      ou[c2] = pack2bf(v0, v1);
    }
    *(uint4*)(xbc + (size_t)(bl0+t)*CONVDIM + ch0) = make_uint4(ou[0],ou[1],ou[2],ou[3]);
  }
}

// ================= SSD chunked scan, pass 1 =================
__global__ __launch_bounds__(256) void k_ssd1(const bf16* __restrict__ xbc,
    const float* __restrict__ dtv, const float* __restrict__ A_log,
    bf16* __restrict__ ys, bf16* __restrict__ Sst) {
  int blk = blockIdx.x;
  int c = blk & (NCH-1), h = (blk>>5)&7, b = blk>>8;
  int tid = threadIdx.x;
  int lane = tid & 63, wid = tid >> 6;
  int r = lane & 15, q = lane >> 4;
  size_t rowbase = (size_t)b*L_ + (size_t)c*QCH;
  float eA = __expf(A_log[h]);

  __shared__ __align__(16) bf16 sB[128*128];
  __shared__ __align__(16) bf16 sC[128*128];
  __shared__ __align__(16) bf16 sDX[64*128];
  __shared__ __align__(16) bf16 sBT[128*128];
  __shared__ float sDT[128];
  __shared__ float sL[128];
  __shared__ float sWS[128];
  __shared__ float sWT[2];

  #pragma unroll
  for (int i=0;i<16;i++){
    int id = i*256 + tid;
    int row = id >> 5, cg = id & 31;
    uint4 u = *(const uint4*)(xbc + (rowbase+row)*CONVDIM + DI + cg*8);
    if (cg < 16) *(uint4*)&sB[row*128 + ((cg ^ (row&15))<<3)] = u;
    else { int cg2 = cg-16; *(uint4*)&sC[row*128 + ((cg2 ^ (row&15))<<3)] = u; }
  }
  if (tid < 128) sDT[tid] = dtv[(rowbase+tid)*NH + h];
  __syncthreads();

  float inc = 0.f;
  if (tid < 128){
    inc = sDT[tid];
    #pragma unroll
    for (int off=1; off<64; off<<=1){
      float u = __shfl_up(inc, off);
      if (lane >= off) inc += u;
    }
    if (lane==63) sWT[wid] = inc;
  }
  __syncthreads();
  if (tid < 128){
    if (wid==1) inc += sWT[0];
    sL[tid] = inc;
  }
  {
    int s = tid >> 1, ph = tid & 1;
    float dts = sDT[s];
    const bf16* xs = xbc + (rowbase+s)*CONVDIM + h*HD + ph*32;
    #pragma unroll
    for (int i8=0;i8<4;i8++){
      ushort4 u0 = *(const ushort4*)(xs + i8*8);
      ushort4 u1 = *(const ushort4*)(xs + i8*8 + 4);
      unsigned short uu[8] = {u0.x,u0.y,u0.z,u0.w,u1.x,u1.y,u1.z,u1.w};
      #pragma unroll
      for (int j=0;j<8;j++){
        int p = ph*32 + i8*8 + j;
        sDX[p*128 + (((s>>3) ^ (p&15))<<3) + (s&7)] = f2bf(dts * bf2f(uu[j]));
      }
    }
  }
  __syncthreads();

  int wr = wid >> 1, wc = wid & 1;
  f32x4 accG[4][4];
  #pragma unroll
  for (int i=0;i<4;i++)
    #pragma unroll
    for (int j=0;j<4;j++) accG[i][j] = (f32x4){0.f,0.f,0.f,0.f};
  #pragma unroll
  for (int ks=0; ks<4; ks++){
    bf16x8 af[4], bfv[4];
    #pragma unroll
    for (int mf=0;mf<4;mf++){
      int t = wr*64 + mf*16 + r;
      af[mf] = *(const bf16x8*)&sC[t*128 + (((ks*4+q) ^ (t&15))<<3)];
    }
    #pragma unroll
    for (int nf=0;nf<4;nf++){
      int s = wc*64 + nf*16 + r;
      bfv[nf] = *(const bf16x8*)&sB[s*128 + (((ks*4+q) ^ (s&15))<<3)];
    }
    #pragma unroll
    for (int mf=0;mf<4;mf++)
      #pragma unroll
      for (int nf=0;nf<4;nf++)
        accG[mf][nf] = __builtin_amdgcn_mfma_f32_16x16x32_bf16(af[mf], bfv[nf], accG[mf][nf], 0, 0, 0);
  }
  __syncthreads();

  bf16* sW = sC;
  #pragma unroll
  for (int mf=0;mf<4;mf++){
    #pragma unroll
    for (int nf=0;nf<4;nf++){
      int s = wc*64 + nf*16 + r;
      float Ls = sL[s];
      #pragma unroll
      for (int rr=0;rr<4;rr++){
        int t = wr*64 + mf*16 + q*4 + rr;
        float wvv = 0.f;
        if (s <= t) wvv = accG[mf][nf][rr] * __expf(-eA*(sL[t]-Ls));
        sW[t*128 + (((s>>3) ^ (t&15))<<3) + (s&7)] = f2bf(wvv);
      }
    }
  }
  if (tid < 128) sWS[tid] = __expf(-eA*(sL[127]-sL[tid]));
  __syncthreads();

  {
    int n = tid >> 1, ph = tid & 1;
    #pragma unroll
    for (int i8=0;i8<8;i8++){
      unsigned short vals[8];
      #pragma unroll
      for (int j=0;j<8;j++){
        int s = ph*64 + i8*8 + j;
        float bv = bf2f(sB[s*128 + (((n>>3) ^ (s&15))<<3) + (n&7)]);
        vals[j] = f2bf(bv * sWS[s]);
      }
      int s8 = ph*8 + i8;
      *(uint4*)&sBT[n*128 + ((s8 ^ (n&15))<<3)] = *(const uint4*)vals;
    }
  }
  __syncthreads();

  {
    int wr2 = wid >> 1, wc2 = wid & 1;
    f32x4 accY[4][2];
    #pragma unroll
    for (int i=0;i<4;i++){ accY[i][0]=(f32x4){0.f,0.f,0.f,0.f}; accY[i][1]=(f32x4){0.f,0.f,0.f,0.f}; }
    #pragma unroll
    for (int ks=0; ks<4; ks++){
      bf16x8 af[4], bfv[2];
      #pragma unroll
      for (int mf=0;mf<4;mf++){
        int t = wr2*64 + mf*16 + r;
        af[mf] = *(const bf16x8*)&sW[t*128 + (((ks*4+q) ^ (t&15))<<3)];
      }
      #pragma unroll
      for (int nf=0;nf<2;nf++){
        int p = wc2*32 + nf*16 + r;
        bfv[nf] = *(const bf16x8*)&sDX[p*128 + (((ks*4+q) ^ (p&15))<<3)];
      }
      #pragma unroll
      for (int mf=0;mf<4;mf++)
        #pragma unroll
        for (int nf=0;nf<2;nf++)
          accY[mf][nf] = __builtin_amdgcn_mfma_f32_16x16x32_bf16(af[mf], bfv[nf], accY[mf][nf], 0, 0, 0);
    }
    #pragma unroll
    for (int mf=0;mf<4;mf++){
      #pragma unroll
      for (int nf=0;nf<2;nf++){
        int p = wc2*32 + nf*16 + r;
        #pragma unroll
        for (int rr=0;rr<4;rr++){
          int t = wr2*64 + mf*16 + q*4 + rr;
          ys[(rowbase+t)*DI + h*HD + p] = f2bf(accY[mf][nf][rr]);
        }
      }
    }
  }

  {
    int wrp = wid >> 1, wcn = wid & 1;
    f32x4 accT[2][4];
    #pragma unroll
    for (int i=0;i<2;i++)
      #pragma unroll
      for (int j=0;j<4;j++) accT[i][j] = (f32x4){0.f,0.f,0.f,0.f};
    #pragma unroll
    for (int ks=0; ks<4; ks++){
      bf16x8 af[2], bfv[4];
      #pragma unroll
      for (int mf=0;mf<2;mf++){
        int p = wrp*32 + mf*16 + r;
        af[mf] = *(const bf16x8*)&sDX[p*128 + (((ks*4+q) ^ (p&15))<<3)];
      }
      #pragma unroll
      for (int nf=0;nf<4;nf++){
        int n = wcn*64 + nf*16 + r;
        bfv[nf] = *(const bf16x8*)&sBT[n*128 + (((ks*4+q) ^ (n&15))<<3)];
      }
      #pragma unroll
      for (int mf=0;mf<2;mf++)
        #pragma unroll
        for (int nf=0;nf<4;nf++)
          accT[mf][nf] = __builtin_amdgcn_mfma_f32_16x16x32_bf16(af[mf], bfv[nf], accT[mf][nf], 0, 0, 0);
    }
    size_t sb = (((size_t)(b*NH+h))*NCH + c)*8192;
    #pragma unroll
    for (int mf=0;mf<2;mf++){
      #pragma unroll
      for (int nf=0;nf<4;nf++){
        int n = wcn*64 + nf*16 + r;
        #pragma unroll
        for (int rr=0;rr<4;rr++){
          int p = wrp*32 + mf*16 + q*4 + rr;
          Sst[sb + (size_t)p*128 + n] = f2bf(accT[mf][nf][rr]);
        }
      }
    }
  }
}

// ---------------- pass 2: prefix-combine chunk states ----------------
template<int NCHT, int QCHT>
__global__ __launch_bounds__(256) void k_scan2(bf16* __restrict__ Sst, const float* __restrict__ dAv) {
  constexpr int SEG = QCHT/16;
  int blk = blockIdx.x;
  int bh = blk>>2, q = blk&3;
  int b = bh>>3, h = bh&7;
  int tid = threadIdx.x;
  __shared__ float sP[NCHT];
  {
    int c = tid / SEG, seg = tid & (SEG-1);
    float prod = 1.f;
    size_t base = ((size_t)b*L_ + c*QCHT + seg*16)*NH + h;
    #pragma unroll
    for (int k=0;k<16;k++) prod *= dAv[base + (size_t)k*NH];
    #pragma unroll
    for (int off=1; off<SEG; off<<=1) prod *= __shfl_xor(prod, off);
    if (seg==0) sP[c] = prod;
  }
  __syncthreads();
  int e0 = q*2048 + tid*8;
  float acc[8];
  #pragma unroll
  for (int j=0;j<8;j++) acc[j]=0.f;
  size_t sbase = (size_t)bh*NCHT*8192 + e0;
  for (int c=0;c<NCHT;c++){
    bf16* ptr = Sst + sbase + (size_t)c*8192;
    uint4 u = *(const uint4*)ptr;
    unsigned int uu[4] = {u.x,u.y,u.z,u.w};
    float tv[8];
    #pragma unroll
    for (int k=0;k<4;k++){
      tv[2*k]   = __uint_as_float(uu[k]<<16);
      tv[2*k+1] = __uint_as_float(uu[k]&0xffff0000u);
    }
    uint4 o;
    o.x = pack2bf(acc[0],acc[1]); o.y = pack2bf(acc[2],acc[3]);
    o.z = pack2bf(acc[4],acc[5]); o.w = pack2bf(acc[6],acc[7]);
    asm volatile("s_waitcnt vmcnt(0)" ::: "memory");
    *(uint4*)ptr = o;
    float P = sP[c];
    #pragma unroll
    for (int j=0;j<8;j++) acc[j] = tv[j] + P*acc[j];
  }
}

// ================= SSD pass 3: Y += A_t * (C x I_c) =================
__global__ __launch_bounds__(256) void k_ssd3(const bf16* __restrict__ xbc,
    const float* __restrict__ dtv, const float* __restrict__ A_log,
    const bf16* __restrict__ Sst, bf16* __restrict__ ys) {
  int blk = blockIdx.x;
  int c = blk & (NCH-1), h = (blk>>5)&7, b = blk>>8;
  int tid = threadIdx.x;
  int lane = tid & 63, wid = tid >> 6;
  int r = lane & 15, q = lane >> 4;
  size_t rowbase = (size_t)b*L_ + (size_t)c*QCH;
  float eA = __expf(A_log[h]);

  __shared__ __align__(16) bf16 sC[128*128];
  __shared__ float sDT[128];
  __shared__ float sL[128];
  __shared__ float sAt[128];
  __shared__ float sWT[2];

  #pragma unroll
  for (int i=0;i<8;i++){
    int id = i*256 + tid;
    int row = id >> 4, cg = id & 15;
    uint4 u = *(const uint4*)(xbc + (rowbase+row)*CONVDIM + DI + NS + cg*8);
    *(uint4*)&sC[row*128 + ((cg ^ (row&15))<<3)] = u;
  }
  if (tid < 128) sDT[tid] = dtv[(rowbase+tid)*NH + h];
  __syncthreads();
  float inc = 0.f;
  if (tid < 128){
    inc = sDT[tid];
    #pragma unroll
    for (int off=1; off<64; off<<=1){
      float u = __shfl_up(inc, off);
      if (lane >= off) inc += u;
    }
    if (lane==63) sWT[wid] = inc;
  }
  __syncthreads();
  if (tid < 128){
    if (wid==1) inc += sWT[0];
    sL[tid] = inc;
    sAt[tid] = __expf(-eA*inc);
  }
  __syncthreads();

  int wr2 = wid >> 1, wc2 = wid & 1;
  size_t sb = (((size_t)(b*NH+h))*NCH + c)*8192;
  f32x4 accP[4][2];
  #pragma unroll
  for (int i=0;i<4;i++){ accP[i][0]=(f32x4){0.f,0.f,0.f,0.f}; accP[i][1]=(f32x4){0.f,0.f,0.f,0.f}; }
  #pragma unroll
  for (int ks=0; ks<4; ks++){
    bf16x8 af[4], bfv[2];
    #pragma unroll
    for (int mf=0;mf<4;mf++){
      int t = wr2*64 + mf*16 + r;
      af[mf] = *(const bf16x8*)&sC[t*128 + (((ks*4+q) ^ (t&15))<<3)];
    }
    #pragma unroll
    for (int nf=0;nf<2;nf++){
      int p = wc2*32 + nf*16 + r;
      bfv[nf] = *(const bf16x8*)(Sst + sb + (size_t)p*128 + ks*32 + q*8);
    }
    #pragma unroll
    for (int mf=0;mf<4;mf++)
      #pragma unroll
      for (int nf=0;nf<2;nf++)
        accP[mf][nf] = __builtin_amdgcn_mfma_f32_16x16x32_bf16(af[mf], bfv[nf], accP[mf][nf], 0, 0, 0);
  }
  #pragma unroll
  for (int mf=0;mf<4;mf++){
    #pragma unroll
    for (int nf=0;nf<2;nf++){
      int p = wc2*32 + nf*16 + r;
      #pragma unroll
      for (int rr=0;rr<4;rr++){
        int t = wr2*64 + mf*16 + q*4 + rr;
        bf16* yp = ys + (rowbase+t)*DI + h*HD + p;
        *yp = f2bf(bf2f(*yp) + sAt[t]*accP[mf][nf][rr]);
      }
    }
  }
}

// ---------------- y = (ys + D*xh)*silu(z), RMSNorm*w, in place (bf16) ----------------
__global__ __launch_bounds__(256) void k_combine(bf16* __restrict__ ys, const bf16* __restrict__ xbc,
                         const bf16* __restrict__ z, const float* __restrict__ Dp,
                         const float* __restrict__ nw) {
  int bl = blockIdx.x;
  int tid = threadIdx.x;
  bf16* yrow = ys + (size_t)bl*DI;
  const bf16* xrow = xbc + (size_t)bl*CONVDIM;
  const bf16* zrow = z + (size_t)bl*DI;
  float v[2]; float ss = 0.f;
  #pragma unroll
  for (int i=0;i<2;i++) {
    int d = tid + i*256;
    float xh = bf2f(xrow[d]);
    float y = bf2f(yrow[d]) + Dp[d>>6]*xh;
    float zv = bf2f(zrow[d]);
    y *= zv / (1.f + expf(-zv));
    v[i] = y; ss += y*y;
  }
  #pragma unroll
  for (int off=1; off<64; off<<=1) ss += __shfl_xor(ss, off);
  __shared__ float sb[4];
  if ((tid&63)==0) sb[tid>>6]=ss;
  __syncthreads();
  float total = sb[0]+sb[1]+sb[2]+sb[3];
  float scale = rsqrtf(total * (1.f/512.f) + 1e-5f);
  #pragma unroll
  for (int i=0;i<2;i++) {
    int d = tid + i*256;
    yrow[d] = f2bf(v[i]*scale*nw[d]);
  }
}

extern "C" void kernel_launch(void* const* d_in, const int* in_sizes, int n_in,
                              void* d_out, int out_size, void* d_ws, size_t ws_size,
                              hipStream_t stream) {
  const float* x         = (const float*)d_in[0];
  const float* conv_w    = (const float*)d_in[1];
  const float* conv_b    = (const float*)d_in[2];
  const float* bn_gamma  = (const float*)d_in[3];
  const float* bn_beta   = (const float*)d_in[4];
  const float* patch_w   = (const float*)d_in[5];
  const float* patch_b   = (const float*)d_in[6];
  const float* in_proj_w = (const float*)d_in[7];
  const float* conv1d_w  = (const float*)d_in[8];
  const float* conv1d_b  = (const float*)d_in[9];
  const float* dt_bias   = (const float*)d_in[10];
  const float* A_log     = (const float*)d_in[11];
  const float* Dp        = (const float*)d_in[12];
  const float* norm_w    = (const float*)d_in[13];
  const float* out_proj_w= (const float*)d_in[14];
  const float* final_w   = (const float*)d_in[15];
  const float* final_b   = (const float*)d_in[16];
  float* out = (float*)d_out;

  char* Wb = (char*)d_ws;
  float* h_buf = (float*)(Wb + 0);
  bf16*  winb  = (bf16*)(Wb + 0);
  bf16*  woutb = (bf16*)(Wb + 0);              // 256 KB (after combine, xpost region head)
  bf16*  wfinb = (bf16*)(Wb + 262144);         // 64 KB bf16 final_w padded to 128 rows
  bf16*  xpost = (bf16*)(Wb + 0);
  float2* part = (float2*)(Wb + 50331648);
  bf16*  tok   = (bf16*)(Wb + 50331648);
  bf16*  zbuf  = (bf16*)(Wb + 67108864);
  bf16*  y2b   = (bf16*)(Wb + 67108864);
  bf16*  xpre  = (bf16*)(Wb + 100663296);
  bf16*  ysb   = (bf16*)(Wb + 100663296);
  bf16*  Sst   = (bf16*)(Wb + 134217728);
  float* dtv   = (float*)(Wb + 134217728 + 33554432);
  float* dAv   = dtv + 262144;
  float* stats = dAv + 262144;
  const size_t NEED = 134217728ull + 33554432 + 2097152 + 256;
  if (ws_size < NEED) {
    hipMemsetAsync(d_out, 0, (size_t)out_size*sizeof(float), stream);
    return;
  }

  k_conv1<<<dim3((B_*CMID*HMID*WMID)/256), dim3(256), 0, stream>>>(x, conv_w, conv_b, h_buf);
  k_bnstatsA<<<dim3(512), dim3(256), 0, stream>>>(h_buf, part);
  k_bnstatsB<<<dim3(1), dim3(64), 0, stream>>>(part, stats);
  k_patch<<<dim3(MTOK/8), dim3(256), 0, stream>>>(h_buf, patch_w, patch_b, stats, bn_gamma, bn_beta, tok);
  k_cvtw<<<dim3((NPADIN*DM)/256), dim3(256), 0, stream>>>(in_proj_w, winb, PROJ, 8, NPADIN*DM);
  k_mgemm<0><<<dim3(MTOK/128, NPADIN/128), dim3(256), 0, stream>>>(tok, winb, DM,
      zbuf, xpre, nullptr, nullptr, dt_bias, A_log, dtv, dAv, nullptr, nullptr);
  k_conv1d<<<dim3((MTOK/8*96)/256), dim3(256), 0, stream>>>(xpre, conv1d_w, conv1d_b, xpost);
  k_ssd1<<<dim3(B_*NH*NCH), dim3(256), 0, stream>>>(xpost, dtv, A_log, ysb, Sst);
  k_scan2<NCH,QCH><<<dim3(B_*NH*4), dim3(256), 0, stream>>>(Sst, dAv);
  k_ssd3<<<dim3(B_*NH*NCH), dim3(256), 0, stream>>>(xpost, dtv, A_log, Sst, ysb);
  k_combine<<<dim3(MTOK), dim3(256), 0, stream>>>(ysb, xpost, zbuf, Dp, norm_w);
  k_cvtw<<<dim3((DM*DI)/256), dim3(256), 0, stream>>>(out_proj_w, woutb, DM, 9, DM*DI);
  k_cvtw<<<dim3((128*DM)/256), dim3(256), 0, stream>>>(final_w, wfinb, 64, 8, 128*DM);
  k_mgemm<1><<<dim3(MTOK/128, DM/128), dim3(256), 0, stream>>>(ysb, woutb, DI,
      nullptr, nullptr, y2b, tok, nullptr, nullptr, nullptr, nullptr, nullptr, nullptr);
  k_mgemm<2><<<dim3(MTOK/128, 1), dim3(256), 0, stream>>>(y2b, wfinb, DM,
      nullptr, nullptr, nullptr, nullptr, nullptr, nullptr, nullptr, nullptr, out, final_b);
}

// Round 9
// 363.366 us; speedup vs baseline: 10.1422x; 1.0561x over previous
//
#include <hip/hip_runtime.h>
#include <math.h>

#define B_  8
#define CIN 3
#define HIN 256
#define WIN 256
#define CMID 16
#define HMID 128
#define WMID 128
#define DM 256
#define L_ 4096
#define DI 512
#define NH 8
#define HD 64
#define NS 128
#define KC 4
#define CONVDIM 768
#define PROJ 1288
#define NPADIN 1408
#define MTOK (B_*L_)
#define QCH 128          // chunk length (SSD)
#define NCH 32           // number of chunks

typedef unsigned short bf16;
typedef __attribute__((ext_vector_type(8))) short bf16x8;
typedef __attribute__((ext_vector_type(4))) float f32x4;

__device__ inline float bf2f(bf16 u) { return __uint_as_float(((unsigned int)u) << 16); }
__device__ inline bf16 f2bf(float f) {
  unsigned int x = __float_as_uint(f);
  return (bf16)((x + 0x7fffu + ((x >> 16) & 1u)) >> 16);
}
__device__ inline unsigned int pack2bf(float a, float b) {
  return (unsigned int)f2bf(a) | ((unsigned int)f2bf(b) << 16);
}

// ---------------- conv 3x3 stride 2 pad 1 ----------------
__global__ void k_conv1(const float* __restrict__ x, const float* __restrict__ w,
                        const float* __restrict__ bias, float* __restrict__ out) {
  int idx = blockIdx.x*256 + threadIdx.x;
  if (idx >= B_*CMID*HMID*WMID) return;
  int xo = idx & 127, yo = (idx>>7)&127, co = (idx>>14)&15, b = idx>>18;
  float acc = bias[co];
  const float* xb = x + (size_t)b*CIN*HIN*WIN;
  const float* wc = w + co*CIN*9;
  #pragma unroll
  for (int ci=0; ci<CIN; ci++)
    #pragma unroll
    for (int ky=0; ky<3; ky++) {
      int yi = 2*yo - 1 + ky;
      if (yi < 0 || yi >= HIN) continue;
      #pragma unroll
      for (int kx=0; kx<3; kx++) {
        int xi = 2*xo - 1 + kx;
        if (xi < 0 || xi >= WIN) continue;
        acc += xb[(ci*HIN + yi)*WIN + xi] * wc[(ci*3+ky)*3+kx];
      }
    }
  out[idx] = acc;
}

// ---------------- BN stats stage A ----------------
__global__ __launch_bounds__(256) void k_bnstatsA(const float* __restrict__ h, float2* __restrict__ part) {
  int blk = blockIdx.x;
  const float4* base = (const float4*)(h + ((size_t)(blk>>2))*16384 + (blk&3)*4096);
  int tid = threadIdx.x;
  float s=0.f, s2=0.f;
  #pragma unroll
  for (int i=0;i<4;i++){
    float4 v = base[i*256 + tid];
    s += v.x+v.y+v.z+v.w;
    s2 += v.x*v.x + v.y*v.y + v.z*v.z + v.w*v.w;
  }
  #pragma unroll
  for (int off=1; off<64; off<<=1) { s += __shfl_xor(s, off); s2 += __shfl_xor(s2, off); }
  __shared__ float sb[2][4];
  if ((tid&63)==0){ sb[0][tid>>6]=s; sb[1][tid>>6]=s2; }
  __syncthreads();
  if (tid==0) part[blk] = make_float2(sb[0][0]+sb[0][1]+sb[0][2]+sb[0][3],
                                      sb[1][0]+sb[1][1]+sb[1][2]+sb[1][3]);
}

// ---------------- BN stats stage B ----------------
__global__ void k_bnstatsB(const float2* __restrict__ part, float* __restrict__ stats) {
  int lane = threadIdx.x;
  int c = lane >> 2, j0 = lane & 3;
  float s=0.f, s2=0.f;
  #pragma unroll
  for (int j=j0; j<32; j+=4){
    int b = j >> 2, chunk = j & 3;
    float2 p = part[(b*16+c)*4 + chunk];
    s += p.x; s2 += p.y;
  }
  s += __shfl_xor(s,1); s2 += __shfl_xor(s2,1);
  s += __shfl_xor(s,2); s2 += __shfl_xor(s2,2);
  if (j0==0){
    const float inv = 1.f/131072.f;
    float mean = s*inv;
    float var  = s2*inv - mean*mean;
    stats[c]      = mean;
    stats[16 + c] = rsqrtf(var + 1e-5f);
  }
}

// ---------------- patch conv 2x2 s2 (+fused BN+GELU) + bias + sincos -> tok ----------------
__global__ __launch_bounds__(256) void k_patch(const float* __restrict__ h, const float* __restrict__ pw,
                       const float* __restrict__ pb, const float* __restrict__ stats,
                       const float* __restrict__ gamma, const float* __restrict__ beta,
                       bf16* __restrict__ tok) {
  int grp = blockIdx.x;
  int b = grp >> 9, g8 = grp & 511;
  int g0 = g8 << 3;
  int gy = g0 >> 6, gx0 = g0 & 63;
  __shared__ float sh[8][64];
  int tid = threadIdx.x;
  {
    int tk = tid >> 5, jj = (tid & 31)*2;
    int ci = jj >> 2, p = (jj >> 1) & 1;
    const float* src = &h[((size_t)(b*CMID+ci)*HMID + 2*gy+p)*WMID + 2*(gx0+tk)];
    float2 xv = *(const float2*)src;
    float mean = stats[ci], rstd = stats[16+ci];
    float sc = rstd*gamma[ci], be = beta[ci] - mean*sc;
    float v0 = xv.x*sc + be;
    float v1 = xv.y*sc + be;
    v0 = 0.5f*v0*(1.f + erff(v0*0.70710678118654752f));
    v1 = 0.5f*v1*(1.f + erff(v1*0.70710678118654752f));
    sh[tk][jj] = v0; sh[tk][jj+1] = v1;
  }
  __syncthreads();
  int d = tid;
  float wr[64];
  #pragma unroll
  for (int i4=0;i4<16;i4++) *(float4*)&wr[i4*4] = *(const float4*)&pw[d*64 + i4*4];
  float bias = pb[d];
  int i = d & 63;
  float omega = expf(-(float)i * (9.210340371976184f/64.f));
  #pragma unroll
  for (int tk=0;tk<8;tk++){
    float acc = bias;
    #pragma unroll
    for (int j=0;j<64;j++) acc = fmaf(sh[tk][j], wr[j], acc);
    float gv = (d < 128) ? (float)(gx0+tk) : (float)gy;
    float ph = gv * omega;
    float pos = (d & 64) ? __cosf(ph) : __sinf(ph);
    tok[((size_t)((b<<12) + g0 + tk))*DM + d] = f2bf(acc + pos);
  }
}

// ---------------- weight f32 -> bf16 (with zero-padding to Npad rows) ----------------
__global__ void k_cvtw(const float* __restrict__ src, bf16* __restrict__ dst,
                       int N, int kshift, int total) {
  int idx = blockIdx.x*256 + threadIdx.x;
  if (idx >= total) return;
  int n = idx >> kshift;
  dst[idx] = (n < N) ? f2bf(src[idx]) : (bf16)0;
}

// ---------------- MFMA bf16 GEMM, 128x128 tile ----------------
template<int EPI>
__global__ __launch_bounds__(256) void k_mgemm(
    const bf16* __restrict__ A, const bf16* __restrict__ Bw, int K,
    bf16* __restrict__ o_z, bf16* __restrict__ o_x,
    bf16* __restrict__ o_y, const bf16* __restrict__ res,
    const float* __restrict__ dt_bias, const float* __restrict__ A_log,
    float* __restrict__ dtv, float* __restrict__ dAv,
    float* __restrict__ o_f, const float* __restrict__ fbias) {
  __shared__ __align__(16) bf16 sA[2][128*32];
  __shared__ __align__(16) bf16 sB[2][128*32];
  int tid = threadIdx.x;
  int lane = tid & 63, wid = tid >> 6;
  int wr = wid >> 1, wc = wid & 1;
  int m0 = blockIdx.x*128, n0 = blockIdx.y*128;
  int nk = K >> 5;
  f32x4 acc[4][4];
  #pragma unroll
  for (int i=0;i<4;i++)
    #pragma unroll
    for (int j=0;j<4;j++)
      acc[i][j] = (f32x4){0.f,0.f,0.f,0.f};

  auto stage = [&](int buf, int ks){
    int kk = ks << 5;
    #pragma unroll
    for (int i=0;i<2;i++){
      int j = i*256 + tid;
      int row = j >> 2, cc = j & 3;
      int kg = cc ^ (row & 3);
      unsigned ldsoff = (unsigned)((i*256 + wid*64) * 16);
      __builtin_amdgcn_global_load_lds(
        (const __attribute__((address_space(1))) void*)(A + (size_t)(m0+row)*K + kk + kg*8),
        (__attribute__((address_space(3))) void*)((char*)&sA[buf][0] + ldsoff), 16, 0, 0);
      __builtin_amdgcn_global_load_lds(
        (const __attribute__((address_space(1))) void*)(Bw + (size_t)(n0+row)*K + kk + kg*8),
        (__attribute__((address_space(3))) void*)((char*)&sB[buf][0] + ldsoff), 16, 0, 0);
    }
  };

  int r = lane & 15, q = lane >> 4;
  int kgo = (q ^ (r & 3)) << 3;

  stage(0, 0);
  for (int ks=0; ks<nk; ++ks){
    int cur = ks & 1;
    __syncthreads();
    if (ks+1 < nk) stage(cur^1, ks+1);
    bf16x8 af[4], bfv[4];
    #pragma unroll
    for (int mf=0;mf<4;mf++){
      int rowm = wr*64 + mf*16 + r;
      af[mf] = *(const bf16x8*)&sA[cur][rowm*32 + kgo];
    }
    #pragma unroll
    for (int nf=0;nf<4;nf++){
      int rown = wc*64 + nf*16 + r;
      bfv[nf] = *(const bf16x8*)&sB[cur][rown*32 + kgo];
    }
    #pragma unroll
    for (int mf=0;mf<4;mf++)
      #pragma unroll
      for (int nf=0;nf<4;nf++)
        acc[mf][nf] = __builtin_amdgcn_mfma_f32_16x16x32_bf16(af[mf], bfv[nf], acc[mf][nf], 0, 0, 0);
  }

  #pragma unroll
  for (int mf=0;mf<4;mf++){
    #pragma unroll
    for (int nf=0;nf<4;nf++){
      int n = n0 + wc*64 + nf*16 + r;
      int mbase = m0 + wr*64 + mf*16 + q*4;
      #pragma unroll
      for (int rr=0;rr<4;rr++){
        int m = mbase + rr;
        float val = acc[mf][nf][rr];
        if (EPI == 0){
          if (n < DI) {
            o_z[(size_t)m*DI + n] = f2bf(val);
          } else if (n < DI + CONVDIM) {
            o_x[(size_t)m*CONVDIM + (n - DI)] = f2bf(val);
          } else if (n < PROJ) {
            int hh = n - (DI + CONVDIM);
            float xv = val + dt_bias[hh];
            float dt = (xv > 20.f) ? xv : log1pf(expf(xv));
            dtv[(size_t)m*NH + hh] = dt;
            dAv[(size_t)m*NH + hh] = expf(-expf(A_log[hh]) * dt);
          }
        } else if (EPI == 1) {
          o_y[(size_t)m*DM + n] = f2bf(val + bf2f(res[(size_t)m*DM + n]));
        } else {
          if (n < 64) {
            float vv = val + fbias[n];
            int b = m >> 12, g = m & 4095;
            int gy = g >> 6, gx = g & 63;
            int p = n >> 5, qq = (n>>4)&1, cc2 = n & 15;
            o_f[(((size_t)(b*CMID+cc2))*HMID + 2*gy+p)*WMID + (2*gx+qq)] = vv;
          }
        }
      }
    }
  }
}

// ---------------- causal depthwise conv1d (KC=4) + bias + silu ----------------
__global__ __launch_bounds__(256) void k_conv1d(const bf16* __restrict__ xpre, const float* __restrict__ cw,
                         const float* __restrict__ cb, bf16* __restrict__ xbc) {
  int idx = blockIdx.x*256 + threadIdx.x;
  int gch = idx % 96;
  int tb  = idx / 96;
  int ch0 = gch*8;
  int bl0 = tb*8;
  int l0 = bl0 & (L_-1);
  float wv[32];
  #pragma unroll
  for (int i=0;i<8;i++) *(float4*)&wv[i*4] = *(const float4*)&cw[ch0*KC + i*4];
  float bs[8];
  *(float4*)&bs[0] = *(const float4*)&cb[ch0];
  *(float4*)&bs[4] = *(const float4*)&cb[ch0+4];
  uint4 rows[11];
  #pragma unroll
  for (int j=0;j<11;j++){
    int lk = l0 - 3 + j;
    if (lk < 0) rows[j] = make_uint4(0u,0u,0u,0u);
    else rows[j] = *(const uint4*)(xpre + ((size_t)bl0 - 3 + j)*CONVDIM + ch0);
  }
  #pragma unroll
  for (int t=0;t<8;t++){
    float acc[8];
    #pragma unroll
    for (int i=0;i<8;i++) acc[i] = bs[i];
    #pragma unroll
    for (int k=0;k<KC;k++){
      uint4 u = rows[t+k];
      unsigned uu[4]={u.x,u.y,u.z,u.w};
      #pragma unroll
      for (int c2=0;c2<4;c2++){
        float lo = __uint_as_float(uu[c2]<<16);
        float hi = __uint_as_float(uu[c2]&0xffff0000u);
        acc[c2*2]   = fmaf(wv[(c2*2)*4 + k],   lo, acc[c2*2]);
        acc[c2*2+1] = fmaf(wv[(c2*2+1)*4 + k], hi, acc[c2*2+1]);
      }
    }
    unsigned ou[4];
    #pragma unroll
    for (int c2=0;c2<4;c2++){
      float v0 = acc[c2*2], v1 = acc[c2*2+1];
      v0 = v0 / (1.f + __expf(-v0));
      v1 = v1 / (1.f + __expf(-v1));
      ou[c2] = pack2bf(v0, v1);
    }
    *(uint4*)(xbc + (size_t)(bl0+t)*CONVDIM + ch0) = make_uint4(ou[0],ou[1],ou[2],ou[3]);
  }
}

// ================= SSD pass 1 (512 thr, operand-swapped GEMMs, packed I/O) =================
// G1: accG[s,t] = B_s.C_t ; W[t][s] = mask*dt_s*decay*accG (b64 LDS writes)
// G2: D[p,t] = sum_s xT[p,s]*W[t,s] -> ys b64 stores
// G3: D[n,p] = sum_s BT[n,s]*xT[p,s] -> Sst b64 stores   (BT = dt*decay-to-end * B, transposed)
__global__ __launch_bounds__(512) void k_ssd1(const bf16* __restrict__ xbc,
    const float* __restrict__ dtv, const float* __restrict__ A_log,
    bf16* __restrict__ ys, bf16* __restrict__ Sst) {
  int blk = blockIdx.x;
  int c = blk & (NCH-1), h = (blk>>5)&7, b = blk>>8;
  int tid = threadIdx.x;
  int lane = tid & 63, wid = tid >> 6;     // 8 waves
  int r = lane & 15, q = lane >> 4;
  size_t rowbase = (size_t)b*L_ + (size_t)c*QCH;
  float eA = __expf(A_log[h]);

  __shared__ __align__(16) bf16 sB[128*128];   // B [s][n], chunk^(s&15)
  __shared__ __align__(16) bf16 sC[128*128];   // C [t][n]; reused as W [t][s]
  __shared__ __align__(16) bf16 sDX[64*128];   // x^T [p][s], chunk^(p&15)
  __shared__ __align__(16) bf16 sBT[128*128];  // BT [n][s], chunk^(n&15)
  __shared__ float sDT[128];
  __shared__ float sL[128];
  __shared__ float sWS[128];
  __shared__ float sWT[2];

  // ---- phase 1: stage B, C, x^T, dt ----
  #pragma unroll
  for (int i=0;i<8;i++){
    int id = i*512 + tid;
    int row = id >> 5, cg = id & 31;
    uint4 u = *(const uint4*)(xbc + (rowbase+row)*CONVDIM + DI + cg*8);
    if (cg < 16) *(uint4*)&sB[row*128 + ((cg ^ (row&15))<<3)] = u;
    else { int cg2 = cg-16; *(uint4*)&sC[row*128 + ((cg2 ^ (row&15))<<3)] = u; }
  }
  {
    int s0 = (tid >> 3)*2;            // even s
    int p0 = (tid & 7)*8;
    const bf16* x0 = xbc + (rowbase+s0)*CONVDIM + h*HD + p0;
    uint4 u0 = *(const uint4*)x0;
    uint4 u1 = *(const uint4*)(x0 + CONVDIM);
    unsigned a0[4]={u0.x,u0.y,u0.z,u0.w}, a1[4]={u1.x,u1.y,u1.z,u1.w};
    int cb2 = s0 >> 3, se = s0 & 7;
    #pragma unroll
    for (int jp=0;jp<4;jp++){
      unsigned w0=a0[jp], w1=a1[jp];
      unsigned lo = (w0 & 0xffffu) | (w1 << 16);
      unsigned hi = (w0 >> 16) | (w1 & 0xffff0000u);
      int pA = p0 + jp*2, pB = pA+1;
      *(unsigned*)&sDX[pA*128 + ((cb2 ^ (pA&15))<<3) + se] = lo;
      *(unsigned*)&sDX[pB*128 + ((cb2 ^ (pB&15))<<3) + se] = hi;
    }
  }
  if (tid < 128) sDT[tid] = dtv[(rowbase+tid)*NH + h];
  __syncthreads();

  // ---- prefix sum dt -> sL ----
  float inc = 0.f;
  if (tid < 128){
    inc = sDT[tid];
    #pragma unroll
    for (int off=1; off<64; off<<=1){
      float u = __shfl_up(inc, off);
      if (lane >= off) inc += u;
    }
    if (lane==63) sWT[wid] = inc;
  }
  __syncthreads();
  if (tid < 128){
    if (wid==1) inc += sWT[0];
    sL[tid] = inc;
  }

  // ---- G1: accG[s,t] = sum_n B[s,n]*C[t,n]; waves 4(s)x2(t), tile 32x64 ----
  int wr = wid >> 1, wc = wid & 1;
  f32x4 accG[2][4];
  #pragma unroll
  for (int i=0;i<2;i++)
    #pragma unroll
    for (int j=0;j<4;j++) accG[i][j] = (f32x4){0.f,0.f,0.f,0.f};
  #pragma unroll
  for (int ks=0; ks<4; ks++){
    bf16x8 af[2], bfv[4];
    #pragma unroll
    for (int mf=0;mf<2;mf++){
      int s = wr*32 + mf*16 + r;
      af[mf] = *(const bf16x8*)&sB[s*128 + (((ks*4+q) ^ (s&15))<<3)];
    }
    #pragma unroll
    for (int nf=0;nf<4;nf++){
      int t = wc*64 + nf*16 + r;
      bfv[nf] = *(const bf16x8*)&sC[t*128 + (((ks*4+q) ^ (t&15))<<3)];
    }
    #pragma unroll
    for (int mf=0;mf<2;mf++)
      #pragma unroll
      for (int nf=0;nf<4;nf++)
        accG[mf][nf] = __builtin_amdgcn_mfma_f32_16x16x32_bf16(af[mf], bfv[nf], accG[mf][nf], 0, 0, 0);
  }
  __syncthreads();   // sC reads done; sL ready

  // ---- W[t][s] = mask * dt_s * exp(-eA(Lt-Ls)) * G ; b64 writes into sC ----
  bf16* sW = sC;
  #pragma unroll
  for (int mf=0;mf<2;mf++){
    int sb4 = wr*32 + mf*16 + q*4;
    int cb4 = sb4 >> 3, se4 = sb4 & 7;
    #pragma unroll
    for (int nf=0;nf<4;nf++){
      int t = wc*64 + nf*16 + r;
      float Lt = sL[t];
      float w[4];
      #pragma unroll
      for (int rr=0;rr<4;rr++){
        int s = sb4 + rr;
        float v = 0.f;
        if (s <= t) v = accG[mf][nf][rr] * sDT[s] * __expf(-eA*(Lt - sL[s]));
        w[rr] = v;
      }
      *(uint2*)&sW[t*128 + ((cb4 ^ (t&15))<<3) + se4] =
          make_uint2(pack2bf(w[0],w[1]), pack2bf(w[2],w[3]));
    }
  }
  if (tid < 128) sWS[tid] = sDT[tid]*__expf(-eA*(sL[127]-sL[tid]));
  __syncthreads();

  // ---- BT[n][s] = B[s][n]*sWS[s] ----
  {
    int n = tid >> 2, sg = tid & 3;
    #pragma unroll
    for (int i8=0;i8<4;i8++){
      unsigned short vals[8];
      #pragma unroll
      for (int j=0;j<8;j++){
        int s = sg*32 + i8*8 + j;
        float bv = bf2f(sB[s*128 + (((n>>3) ^ (s&15))<<3) + (n&7)]);
        vals[j] = f2bf(bv * sWS[s]);
      }
      int s8 = sg*4 + i8;
      *(uint4*)&sBT[n*128 + ((s8 ^ (n&15))<<3)] = *(const uint4*)vals;
    }
  }
  __syncthreads();

  // ---- G2: D[p,t] = sum_s xT[p,s]*W[t,s]; waves 2(p)x4(t), tile 32x32 ----
  {
    int wrp = wid >> 2, wct = wid & 3;
    f32x4 acc2[2][2];
    #pragma unroll
    for (int i=0;i<2;i++){ acc2[i][0]=(f32x4){0.f,0.f,0.f,0.f}; acc2[i][1]=(f32x4){0.f,0.f,0.f,0.f}; }
    #pragma unroll
    for (int ks=0; ks<4; ks++){
      bf16x8 af[2], bfv[2];
      #pragma unroll
      for (int mf=0;mf<2;mf++){
        int p = wrp*32 + mf*16 + r;
        af[mf] = *(const bf16x8*)&sDX[p*128 + (((ks*4+q) ^ (p&15))<<3)];
      }
      #pragma unroll
      for (int nf=0;nf<2;nf++){
        int t = wct*32 + nf*16 + r;
        bfv[nf] = *(const bf16x8*)&sW[t*128 + (((ks*4+q) ^ (t&15))<<3)];
      }
      #pragma unroll
      for (int mf=0;mf<2;mf++)
        #pragma unroll
        for (int nf=0;nf<2;nf++)
          acc2[mf][nf] = __builtin_amdgcn_mfma_f32_16x16x32_bf16(af[mf], bfv[nf], acc2[mf][nf], 0, 0, 0);
    }
    #pragma unroll
    for (int mf=0;mf<2;mf++){
      int pb = wrp*32 + mf*16 + q*4;
      #pragma unroll
      for (int nf=0;nf<2;nf++){
        int t = wct*32 + nf*16 + r;
        f32x4 v = acc2[mf][nf];
        *(uint2*)(ys + (rowbase+t)*DI + h*HD + pb) =
            make_uint2(pack2bf(v[0],v[1]), pack2bf(v[2],v[3]));
      }
    }
  }

  // ---- G3: D[n,p] = sum_s BT[n,s]*xT[p,s]; waves 4(n)x2(p), tile 32x32 ----
  {
    int wrn = wid >> 1, wcp = wid & 1;
    f32x4 acc3[2][2];
    #pragma unroll
    for (int i=0;i<2;i++){ acc3[i][0]=(f32x4){0.f,0.f,0.f,0.f}; acc3[i][1]=(f32x4){0.f,0.f,0.f,0.f}; }
    #pragma unroll
    for (int ks=0; ks<4; ks++){
      bf16x8 af[2], bfv[2];
      #pragma unroll
      for (int mf=0;mf<2;mf++){
        int n = wrn*32 + mf*16 + r;
        af[mf] = *(const bf16x8*)&sBT[n*128 + (((ks*4+q) ^ (n&15))<<3)];
      }
      #pragma unroll
      for (int nf=0;nf<2;nf++){
        int p = wcp*32 + nf*16 + r;
        bfv[nf] = *(const bf16x8*)&sDX[p*128 + (((ks*4+q) ^ (p&15))<<3)];
      }
      #pragma unroll
      for (int mf=0;mf<2;mf++)
        #pragma unroll
        for (int nf=0;nf<2;nf++)
          acc3[mf][nf] = __builtin_amdgcn_mfma_f32_16x16x32_bf16(af[mf], bfv[nf], acc3[mf][nf], 0, 0, 0);
    }
    size_t sb = (((size_t)(b*NH+h))*NCH + c)*8192;
    #pragma unroll
    for (int mf=0;mf<2;mf++){
      int nb = wrn*32 + mf*16 + q*4;
      #pragma unroll
      for (int nf=0;nf<2;nf++){
        int p = wcp*32 + nf*16 + r;
        f32x4 v = acc3[mf][nf];
        *(uint2*)(Sst + sb + (size_t)p*128 + nb) =
            make_uint2(pack2bf(v[0],v[1]), pack2bf(v[2],v[3]));
      }
    }
  }
}

// ---------------- pass 2: prefix-combine chunk states ----------------
template<int NCHT, int QCHT>
__global__ __launch_bounds__(256) void k_scan2(bf16* __restrict__ Sst, const float* __restrict__ dAv) {
  constexpr int SEG = QCHT/16;
  int blk = blockIdx.x;
  int bh = blk>>2, q = blk&3;
  int b = bh>>3, h = bh&7;
  int tid = threadIdx.x;
  __shared__ float sP[NCHT];
  {
    int c = tid / SEG, seg = tid & (SEG-1);
    float prod = 1.f;
    size_t base = ((size_t)b*L_ + c*QCHT + seg*16)*NH + h;
    #pragma unroll
    for (int k=0;k<16;k++) prod *= dAv[base + (size_t)k*NH];
    #pragma unroll
    for (int off=1; off<SEG; off<<=1) prod *= __shfl_xor(prod, off);
    if (seg==0) sP[c] = prod;
  }
  __syncthreads();
  int e0 = q*2048 + tid*8;
  float acc[8];
  #pragma unroll
  for (int j=0;j<8;j++) acc[j]=0.f;
  size_t sbase = (size_t)bh*NCHT*8192 + e0;
  for (int c=0;c<NCHT;c++){
    bf16* ptr = Sst + sbase + (size_t)c*8192;
    uint4 u = *(const uint4*)ptr;
    unsigned int uu[4] = {u.x,u.y,u.z,u.w};
    float tv[8];
    #pragma unroll
    for (int k=0;k<4;k++){
      tv[2*k]   = __uint_as_float(uu[k]<<16);
      tv[2*k+1] = __uint_as_float(uu[k]&0xffff0000u);
    }
    uint4 o;
    o.x = pack2bf(acc[0],acc[1]); o.y = pack2bf(acc[2],acc[3]);
    o.z = pack2bf(acc[4],acc[5]); o.w = pack2bf(acc[6],acc[7]);
    asm volatile("s_waitcnt vmcnt(0)" ::: "memory");
    *(uint4*)ptr = o;
    float P = sP[c];
    #pragma unroll
    for (int j=0;j<8;j++) acc[j] = tv[j] + P*acc[j];
  }
}

// ================= SSD pass 3: Y += exp(-eA*L_t) * (C x I_c), swapped (b64 RMW) =================
__global__ __launch_bounds__(256) void k_ssd3(const bf16* __restrict__ xbc,
    const float* __restrict__ dtv, const float* __restrict__ A_log,
    const bf16* __restrict__ Sst, bf16* __restrict__ ys) {
  int blk = blockIdx.x;
  int c = blk & (NCH-1), h = (blk>>5)&7, b = blk>>8;
  int tid = threadIdx.x;
  int lane = tid & 63, wid = tid >> 6;
  int r = lane & 15, q = lane >> 4;
  size_t rowbase = (size_t)b*L_ + (size_t)c*QCH;
  float eA = __expf(A_log[h]);

  __shared__ __align__(16) bf16 sC[128*128];
  __shared__ float sDT[128];
  __shared__ float sAt[128];
  __shared__ float sWT[2];

  #pragma unroll
  for (int i=0;i<8;i++){
    int id = i*256 + tid;
    int row = id >> 4, cg = id & 15;
    uint4 u = *(const uint4*)(xbc + (rowbase+row)*CONVDIM + DI + NS + cg*8);
    *(uint4*)&sC[row*128 + ((cg ^ (row&15))<<3)] = u;
  }
  if (tid < 128) sDT[tid] = dtv[(rowbase+tid)*NH + h];
  __syncthreads();
  float inc = 0.f;
  if (tid < 128){
    inc = sDT[tid];
    #pragma unroll
    for (int off=1; off<64; off<<=1){
      float u = __shfl_up(inc, off);
      if (lane >= off) inc += u;
    }
    if (lane==63) sWT[wid] = inc;
  }
  __syncthreads();
  if (tid < 128){
    if (wid==1) inc += sWT[0];
    sAt[tid] = __expf(-eA*inc);
  }
  __syncthreads();

  // D[p,t] = sum_n I[p,n]*C[t,n]; waves 2(p)x2(t-64), tile 32x64
  int wrp = wid >> 1, wct = wid & 1;
  size_t sb = (((size_t)(b*NH+h))*NCH + c)*8192;
  f32x4 accP[2][4];
  #pragma unroll
  for (int i=0;i<2;i++)
    #pragma unroll
    for (int j=0;j<4;j++) accP[i][j] = (f32x4){0.f,0.f,0.f,0.f};
  #pragma unroll
  for (int ks=0; ks<4; ks++){
    bf16x8 af[2], bfv[4];
    #pragma unroll
    for (int mf=0;mf<2;mf++){
      int p = wrp*32 + mf*16 + r;
      af[mf] = *(const bf16x8*)(Sst + sb + (size_t)p*128 + ks*32 + q*8);
    }
    #pragma unroll
    for (int nf=0;nf<4;nf++){
      int t = wct*64 + nf*16 + r;
      bfv[nf] = *(const bf16x8*)&sC[t*128 + (((ks*4+q) ^ (t&15))<<3)];
    }
    #pragma unroll
    for (int mf=0;mf<2;mf++)
      #pragma unroll
      for (int nf=0;nf<4;nf++)
        accP[mf][nf] = __builtin_amdgcn_mfma_f32_16x16x32_bf16(af[mf], bfv[nf], accP[mf][nf], 0, 0, 0);
  }
  #pragma unroll
  for (int mf=0;mf<2;mf++){
    int pb = wrp*32 + mf*16 + q*4;
    #pragma unroll
    for (int nf=0;nf<4;nf++){
      int t = wct*64 + nf*16 + r;
      float at = sAt[t];
      bf16* yp = ys + (rowbase+t)*DI + h*HD + pb;
      uint2 old = *(uint2*)yp;
      float o0 = bf2f((bf16)(old.x & 0xffffu))  + at*accP[mf][nf][0];
      float o1 = bf2f((bf16)(old.x >> 16))      + at*accP[mf][nf][1];
      float o2 = bf2f((bf16)(old.y & 0xffffu))  + at*accP[mf][nf][2];
      float o3 = bf2f((bf16)(old.y >> 16))      + at*accP[mf][nf][3];
      *(uint2*)yp = make_uint2(pack2bf(o0,o1), pack2bf(o2,o3));
    }
  }
}

// ---------------- y = (ys + D*xh)*silu(z), RMSNorm*w, in place (bf16) ----------------
__global__ __launch_bounds__(256) void k_combine(bf16* __restrict__ ys, const bf16* __restrict__ xbc,
                         const bf16* __restrict__ z, const float* __restrict__ Dp,
                         const float* __restrict__ nw) {
  int bl = blockIdx.x;
  int tid = threadIdx.x;
  bf16* yrow = ys + (size_t)bl*DI;
  const bf16* xrow = xbc + (size_t)bl*CONVDIM;
  const bf16* zrow = z + (size_t)bl*DI;
  float v[2]; float ss = 0.f;
  #pragma unroll
  for (int i=0;i<2;i++) {
    int d = tid + i*256;
    float xh = bf2f(xrow[d]);
    float y = bf2f(yrow[d]) + Dp[d>>6]*xh;
    float zv = bf2f(zrow[d]);
    y *= zv / (1.f + expf(-zv));
    v[i] = y; ss += y*y;
  }
  #pragma unroll
  for (int off=1; off<64; off<<=1) ss += __shfl_xor(ss, off);
  __shared__ float sb[4];
  if ((tid&63)==0) sb[tid>>6]=ss;
  __syncthreads();
  float total = sb[0]+sb[1]+sb[2]+sb[3];
  float scale = rsqrtf(total * (1.f/512.f) + 1e-5f);
  #pragma unroll
  for (int i=0;i<2;i++) {
    int d = tid + i*256;
    yrow[d] = f2bf(v[i]*scale*nw[d]);
  }
}

extern "C" void kernel_launch(void* const* d_in, const int* in_sizes, int n_in,
                              void* d_out, int out_size, void* d_ws, size_t ws_size,
                              hipStream_t stream) {
  const float* x         = (const float*)d_in[0];
  const float* conv_w    = (const float*)d_in[1];
  const float* conv_b    = (const float*)d_in[2];
  const float* bn_gamma  = (const float*)d_in[3];
  const float* bn_beta   = (const float*)d_in[4];
  const float* patch_w   = (const float*)d_in[5];
  const float* patch_b   = (const float*)d_in[6];
  const float* in_proj_w = (const float*)d_in[7];
  const float* conv1d_w  = (const float*)d_in[8];
  const float* conv1d_b  = (const float*)d_in[9];
  const float* dt_bias   = (const float*)d_in[10];
  const float* A_log     = (const float*)d_in[11];
  const float* Dp        = (const float*)d_in[12];
  const float* norm_w    = (const float*)d_in[13];
  const float* out_proj_w= (const float*)d_in[14];
  const float* final_w   = (const float*)d_in[15];
  const float* final_b   = (const float*)d_in[16];
  float* out = (float*)d_out;

  char* Wb = (char*)d_ws;
  float* h_buf = (float*)(Wb + 0);
  bf16*  winb  = (bf16*)(Wb + 0);
  bf16*  woutb = (bf16*)(Wb + 0);
  bf16*  wfinb = (bf16*)(Wb + 262144);
  bf16*  xpost = (bf16*)(Wb + 0);
  float2* part = (float2*)(Wb + 50331648);
  bf16*  tok   = (bf16*)(Wb + 50331648);
  bf16*  zbuf  = (bf16*)(Wb + 67108864);
  bf16*  y2b   = (bf16*)(Wb + 67108864);
  bf16*  xpre  = (bf16*)(Wb + 100663296);
  bf16*  ysb   = (bf16*)(Wb + 100663296);
  bf16*  Sst   = (bf16*)(Wb + 134217728);
  float* dtv   = (float*)(Wb + 134217728 + 33554432);
  float* dAv   = dtv + 262144;
  float* stats = dAv + 262144;
  const size_t NEED = 134217728ull + 33554432 + 2097152 + 256;
  if (ws_size < NEED) {
    hipMemsetAsync(d_out, 0, (size_t)out_size*sizeof(float), stream);
    return;
  }

  k_conv1<<<dim3((B_*CMID*HMID*WMID)/256), dim3(256), 0, stream>>>(x, conv_w, conv_b, h_buf);
  k_bnstatsA<<<dim3(512), dim3(256), 0, stream>>>(h_buf, part);
  k_bnstatsB<<<dim3(1), dim3(64), 0, stream>>>(part, stats);
  k_patch<<<dim3(MTOK/8), dim3(256), 0, stream>>>(h_buf, patch_w, patch_b, stats, bn_gamma, bn_beta, tok);
  k_cvtw<<<dim3((NPADIN*DM)/256), dim3(256), 0, stream>>>(in_proj_w, winb, PROJ, 8, NPADIN*DM);
  k_mgemm<0><<<dim3(MTOK/128, NPADIN/128), dim3(256), 0, stream>>>(tok, winb, DM,
      zbuf, xpre, nullptr, nullptr, dt_bias, A_log, dtv, dAv, nullptr, nullptr);
  k_conv1d<<<dim3((MTOK/8*96)/256), dim3(256), 0, stream>>>(xpre, conv1d_w, conv1d_b, xpost);
  k_ssd1<<<dim3(B_*NH*NCH), dim3(512), 0, stream>>>(xpost, dtv, A_log, ysb, Sst);
  k_scan2<NCH,QCH><<<dim3(B_*NH*4), dim3(256), 0, stream>>>(Sst, dAv);
  k_ssd3<<<dim3(B_*NH*NCH), dim3(256), 0, stream>>>(xpost, dtv, A_log, Sst, ysb);
  k_combine<<<dim3(MTOK), dim3(256), 0, stream>>>(ysb, xpost, zbuf, Dp, norm_w);
  k_cvtw<<<dim3((DM*DI)/256), dim3(256), 0, stream>>>(out_proj_w, woutb, DM, 9, DM*DI);
  k_cvtw<<<dim3((128*DM)/256), dim3(256), 0, stream>>>(final_w, wfinb, 64, 8, 128*DM);
  k_mgemm<1><<<dim3(MTOK/128, DM/128), dim3(256), 0, stream>>>(ysb, woutb, DI,
      nullptr, nullptr, y2b, tok, nullptr, nullptr, nullptr, nullptr, nullptr, nullptr);
  k_mgemm<2><<<dim3(MTOK/128, 1), dim3(256), 0, stream>>>(y2b, wfinb, DM,
      nullptr, nullptr, nullptr, nullptr, nullptr, nullptr, nullptr, nullptr, out, final_b);
}

// Round 10
// 345.138 us; speedup vs baseline: 10.6778x; 1.0528x over previous
//
#include <hip/hip_runtime.h>
#include <math.h>

#define B_  8
#define CIN 3
#define HIN 256
#define WIN 256
#define CMID 16
#define HMID 128
#define WMID 128
#define DM 256
#define L_ 4096
#define DI 512
#define NH 8
#define HD 64
#define NS 128
#define KC 4
#define CONVDIM 768
#define PROJ 1288
#define NPADIN 1408
#define MTOK (B_*L_)
#define QCH 128          // chunk length (SSD)
#define NCH 32           // number of chunks

typedef unsigned short bf16;
typedef __attribute__((ext_vector_type(8))) short bf16x8;
typedef __attribute__((ext_vector_type(4))) float f32x4;

__device__ inline float bf2f(bf16 u) { return __uint_as_float(((unsigned int)u) << 16); }
__device__ inline bf16 f2bf(float f) {
  unsigned int x = __float_as_uint(f);
  return (bf16)((x + 0x7fffu + ((x >> 16) & 1u)) >> 16);
}
__device__ inline unsigned int pack2bf(float a, float b) {
  return (unsigned int)f2bf(a) | ((unsigned int)f2bf(b) << 16);
}

// ---------------- conv 3x3 stride 2 pad 1 ----------------
__global__ void k_conv1(const float* __restrict__ x, const float* __restrict__ w,
                        const float* __restrict__ bias, float* __restrict__ out) {
  int idx = blockIdx.x*256 + threadIdx.x;
  if (idx >= B_*CMID*HMID*WMID) return;
  int xo = idx & 127, yo = (idx>>7)&127, co = (idx>>14)&15, b = idx>>18;
  float acc = bias[co];
  const float* xb = x + (size_t)b*CIN*HIN*WIN;
  const float* wc = w + co*CIN*9;
  #pragma unroll
  for (int ci=0; ci<CIN; ci++)
    #pragma unroll
    for (int ky=0; ky<3; ky++) {
      int yi = 2*yo - 1 + ky;
      if (yi < 0 || yi >= HIN) continue;
      #pragma unroll
      for (int kx=0; kx<3; kx++) {
        int xi = 2*xo - 1 + kx;
        if (xi < 0 || xi >= WIN) continue;
        acc += xb[(ci*HIN + yi)*WIN + xi] * wc[(ci*3+ky)*3+kx];
      }
    }
  out[idx] = acc;
}

// ---------------- BN stats stage A ----------------
__global__ __launch_bounds__(256) void k_bnstatsA(const float* __restrict__ h, float2* __restrict__ part) {
  int blk = blockIdx.x;
  const float4* base = (const float4*)(h + ((size_t)(blk>>2))*16384 + (blk&3)*4096);
  int tid = threadIdx.x;
  float s=0.f, s2=0.f;
  #pragma unroll
  for (int i=0;i<4;i++){
    float4 v = base[i*256 + tid];
    s += v.x+v.y+v.z+v.w;
    s2 += v.x*v.x + v.y*v.y + v.z*v.z + v.w*v.w;
  }
  #pragma unroll
  for (int off=1; off<64; off<<=1) { s += __shfl_xor(s, off); s2 += __shfl_xor(s2, off); }
  __shared__ float sb[2][4];
  if ((tid&63)==0){ sb[0][tid>>6]=s; sb[1][tid>>6]=s2; }
  __syncthreads();
  if (tid==0) part[blk] = make_float2(sb[0][0]+sb[0][1]+sb[0][2]+sb[0][3],
                                      sb[1][0]+sb[1][1]+sb[1][2]+sb[1][3]);
}

// ---------------- BN stats stage B ----------------
__global__ void k_bnstatsB(const float2* __restrict__ part, float* __restrict__ stats) {
  int lane = threadIdx.x;
  int c = lane >> 2, j0 = lane & 3;
  float s=0.f, s2=0.f;
  #pragma unroll
  for (int j=j0; j<32; j+=4){
    int b = j >> 2, chunk = j & 3;
    float2 p = part[(b*16+c)*4 + chunk];
    s += p.x; s2 += p.y;
  }
  s += __shfl_xor(s,1); s2 += __shfl_xor(s2,1);
  s += __shfl_xor(s,2); s2 += __shfl_xor(s2,2);
  if (j0==0){
    const float inv = 1.f/131072.f;
    float mean = s*inv;
    float var  = s2*inv - mean*mean;
    stats[c]      = mean;
    stats[16 + c] = rsqrtf(var + 1e-5f);
  }
}

// ---------------- patch conv 2x2 s2 (+fused BN+GELU) + bias + sincos -> tok ----------------
__global__ __launch_bounds__(256) void k_patch(const float* __restrict__ h, const float* __restrict__ pw,
                       const float* __restrict__ pb, const float* __restrict__ stats,
                       const float* __restrict__ gamma, const float* __restrict__ beta,
                       bf16* __restrict__ tok) {
  int grp = blockIdx.x;
  int b = grp >> 9, g8 = grp & 511;
  int g0 = g8 << 3;
  int gy = g0 >> 6, gx0 = g0 & 63;
  __shared__ float sh[8][64];
  int tid = threadIdx.x;
  {
    int tk = tid >> 5, jj = (tid & 31)*2;
    int ci = jj >> 2, p = (jj >> 1) & 1;
    const float* src = &h[((size_t)(b*CMID+ci)*HMID + 2*gy+p)*WMID + 2*(gx0+tk)];
    float2 xv = *(const float2*)src;
    float mean = stats[ci], rstd = stats[16+ci];
    float sc = rstd*gamma[ci], be = beta[ci] - mean*sc;
    float v0 = xv.x*sc + be;
    float v1 = xv.y*sc + be;
    v0 = 0.5f*v0*(1.f + erff(v0*0.70710678118654752f));
    v1 = 0.5f*v1*(1.f + erff(v1*0.70710678118654752f));
    sh[tk][jj] = v0; sh[tk][jj+1] = v1;
  }
  __syncthreads();
  int d = tid;
  float wr[64];
  #pragma unroll
  for (int i4=0;i4<16;i4++) *(float4*)&wr[i4*4] = *(const float4*)&pw[d*64 + i4*4];
  float bias = pb[d];
  int i = d & 63;
  float omega = expf(-(float)i * (9.210340371976184f/64.f));
  #pragma unroll
  for (int tk=0;tk<8;tk++){
    float acc = bias;
    #pragma unroll
    for (int j=0;j<64;j++) acc = fmaf(sh[tk][j], wr[j], acc);
    float gv = (d < 128) ? (float)(gx0+tk) : (float)gy;
    float ph = gv * omega;
    float pos = (d & 64) ? __cosf(ph) : __sinf(ph);
    tok[((size_t)((b<<12) + g0 + tk))*DM + d] = f2bf(acc + pos);
  }
}

// ---------------- weight f32 -> bf16 (with zero-padding to Npad rows) ----------------
__global__ void k_cvtw(const float* __restrict__ src, bf16* __restrict__ dst,
                       int N, int kshift, int total) {
  int idx = blockIdx.x*256 + threadIdx.x;
  if (idx >= total) return;
  int n = idx >> kshift;
  dst[idx] = (n < N) ? f2bf(src[idx]) : (bf16)0;
}

// ---------------- MFMA bf16 GEMM, 128x128 tile, OPERAND-SWAPPED (n-in-register) ----------------
// af = Bw fragments (n-rows), bfv = A fragments (m-rows) -> acc row(q*4+rr)=n, col(lane&15)=m.
// Epilogue writes 4-consecutive-n quads per lane (b64 packed).
template<int EPI>
__global__ __launch_bounds__(256) void k_mgemm(
    const bf16* __restrict__ A, const bf16* __restrict__ Bw, int K,
    bf16* __restrict__ o_z, bf16* __restrict__ o_x,
    bf16* __restrict__ o_y, const bf16* __restrict__ res,
    const float* __restrict__ dt_bias, const float* __restrict__ A_log,
    float* __restrict__ dtv, float* __restrict__ dAv,
    float* __restrict__ o_f, const float* __restrict__ fbias) {
  __shared__ __align__(16) bf16 sA[2][128*32];
  __shared__ __align__(16) bf16 sB[2][128*32];
  int tid = threadIdx.x;
  int lane = tid & 63, wid = tid >> 6;
  int wr = wid >> 1, wc = wid & 1;     // wr: m wave-tile, wc: n wave-tile
  int m0 = blockIdx.x*128, n0 = blockIdx.y*128;
  int nk = K >> 5;
  f32x4 acc[4][4];   // [a over n][b over m]
  #pragma unroll
  for (int i=0;i<4;i++)
    #pragma unroll
    for (int j=0;j<4;j++)
      acc[i][j] = (f32x4){0.f,0.f,0.f,0.f};

  auto stage = [&](int buf, int ks){
    int kk = ks << 5;
    #pragma unroll
    for (int i=0;i<2;i++){
      int j = i*256 + tid;
      int row = j >> 2, cc = j & 3;
      int kg = cc ^ (row & 3);
      unsigned ldsoff = (unsigned)((i*256 + wid*64) * 16);
      __builtin_amdgcn_global_load_lds(
        (const __attribute__((address_space(1))) void*)(A + (size_t)(m0+row)*K + kk + kg*8),
        (__attribute__((address_space(3))) void*)((char*)&sA[buf][0] + ldsoff), 16, 0, 0);
      __builtin_amdgcn_global_load_lds(
        (const __attribute__((address_space(1))) void*)(Bw + (size_t)(n0+row)*K + kk + kg*8),
        (__attribute__((address_space(3))) void*)((char*)&sB[buf][0] + ldsoff), 16, 0, 0);
    }
  };

  int r = lane & 15, q = lane >> 4;
  int kgo = (q ^ (r & 3)) << 3;

  stage(0, 0);
  for (int ks=0; ks<nk; ++ks){
    int cur = ks & 1;
    __syncthreads();
    if (ks+1 < nk) stage(cur^1, ks+1);
    bf16x8 af[4], bfv[4];
    #pragma unroll
    for (int a=0;a<4;a++){
      int rown = wc*64 + a*16 + r;
      af[a] = *(const bf16x8*)&sB[cur][rown*32 + kgo];
    }
    #pragma unroll
    for (int bfr=0;bfr<4;bfr++){
      int rowm = wr*64 + bfr*16 + r;
      bfv[bfr] = *(const bf16x8*)&sA[cur][rowm*32 + kgo];
    }
    #pragma unroll
    for (int a=0;a<4;a++)
      #pragma unroll
      for (int bfr=0;bfr<4;bfr++)
        acc[a][bfr] = __builtin_amdgcn_mfma_f32_16x16x32_bf16(af[a], bfv[bfr], acc[a][bfr], 0, 0, 0);
  }

  // epilogue: m = m0+wr*64+b*16+r (lane col), n quad = n0+wc*64+a*16+q*4 (rows)
  #pragma unroll
  for (int a=0;a<4;a++){
    int n4 = n0 + wc*64 + a*16 + q*4;
    #pragma unroll
    for (int bfr=0;bfr<4;bfr++){
      int m = m0 + wr*64 + bfr*16 + r;
      f32x4 v = acc[a][bfr];
      if (EPI == 0){
        if (n4 < DI) {
          *(uint2*)(o_z + (size_t)m*DI + n4) = make_uint2(pack2bf(v[0],v[1]), pack2bf(v[2],v[3]));
        } else if (n4 < DI + CONVDIM) {
          *(uint2*)(o_x + (size_t)m*CONVDIM + (n4 - DI)) = make_uint2(pack2bf(v[0],v[1]), pack2bf(v[2],v[3]));
        } else if (n4 < PROJ) {
          #pragma unroll
          for (int rr=0;rr<4;rr++){
            int hh = n4 + rr - (DI + CONVDIM);
            float xv = v[rr] + dt_bias[hh];
            float dt = (xv > 20.f) ? xv : log1pf(expf(xv));
            dtv[(size_t)m*NH + hh] = dt;
            dAv[(size_t)m*NH + hh] = expf(-expf(A_log[hh]) * dt);
          }
        }
      } else if (EPI == 1) {
        uint2 rv = *(const uint2*)(res + (size_t)m*DM + n4);
        float r0 = bf2f((bf16)(rv.x & 0xffffu)), r1 = bf2f((bf16)(rv.x >> 16));
        float r2 = bf2f((bf16)(rv.y & 0xffffu)), r3 = bf2f((bf16)(rv.y >> 16));
        *(uint2*)(o_y + (size_t)m*DM + n4) =
            make_uint2(pack2bf(v[0]+r0, v[1]+r1), pack2bf(v[2]+r2, v[3]+r3));
      } else {
        #pragma unroll
        for (int rr=0;rr<4;rr++){
          int n = n4 + rr;
          if (n < 64) {
            float vv = v[rr] + fbias[n];
            int b = m >> 12, g = m & 4095;
            int gy = g >> 6, gx = g & 63;
            int p = n >> 5, qq = (n>>4)&1, cc2 = n & 15;
            o_f[(((size_t)(b*CMID+cc2))*HMID + 2*gy+p)*WMID + (2*gx+qq)] = vv;
          }
        }
      }
    }
  }
}

// ---------------- causal depthwise conv1d (KC=4) + bias + silu ----------------
__global__ __launch_bounds__(256) void k_conv1d(const bf16* __restrict__ xpre, const float* __restrict__ cw,
                         const float* __restrict__ cb, bf16* __restrict__ xbc) {
  int idx = blockIdx.x*256 + threadIdx.x;
  int gch = idx % 96;
  int tb  = idx / 96;
  int ch0 = gch*8;
  int bl0 = tb*8;
  int l0 = bl0 & (L_-1);
  float wv[32];
  #pragma unroll
  for (int i=0;i<8;i++) *(float4*)&wv[i*4] = *(const float4*)&cw[ch0*KC + i*4];
  float bs[8];
  *(float4*)&bs[0] = *(const float4*)&cb[ch0];
  *(float4*)&bs[4] = *(const float4*)&cb[ch0+4];
  uint4 rows[11];
  #pragma unroll
  for (int j=0;j<11;j++){
    int lk = l0 - 3 + j;
    if (lk < 0) rows[j] = make_uint4(0u,0u,0u,0u);
    else rows[j] = *(const uint4*)(xpre + ((size_t)bl0 - 3 + j)*CONVDIM + ch0);
  }
  #pragma unroll
  for (int t=0;t<8;t++){
    float acc[8];
    #pragma unroll
    for (int i=0;i<8;i++) acc[i] = bs[i];
    #pragma unroll
    for (int k=0;k<KC;k++){
      uint4 u = rows[t+k];
      unsigned uu[4]={u.x,u.y,u.z,u.w};
      #pragma unroll
      for (int c2=0;c2<4;c2++){
        float lo = __uint_as_float(uu[c2]<<16);
        float hi = __uint_as_float(uu[c2]&0xffff0000u);
        acc[c2*2]   = fmaf(wv[(c2*2)*4 + k],   lo, acc[c2*2]);
        acc[c2*2+1] = fmaf(wv[(c2*2+1)*4 + k], hi, acc[c2*2+1]);
      }
    }
    unsigned ou[4];
    #pragma unroll
    for (int c2=0;c2<4;c2++){
      float v0 = acc[c2*2], v1 = acc[c2*2+1];
      v0 = v0 / (1.f + __expf(-v0));
      v1 = v1 / (1.f + __expf(-v1));
      ou[c2] = pack2bf(v0, v1);
    }
    *(uint4*)(xbc + (size_t)(bl0+t)*CONVDIM + ch0) = make_uint4(ou[0],ou[1],ou[2],ou[3]);
  }
}

// ================= SSD pass 1 (512 thr, operand-swapped GEMMs, packed I/O) =================
__global__ __launch_bounds__(512) void k_ssd1(const bf16* __restrict__ xbc,
    const float* __restrict__ dtv, const float* __restrict__ A_log,
    bf16* __restrict__ ys, bf16* __restrict__ Sst) {
  int blk = blockIdx.x;
  int c = blk & (NCH-1), h = (blk>>5)&7, b = blk>>8;
  int tid = threadIdx.x;
  int lane = tid & 63, wid = tid >> 6;     // 8 waves
  int r = lane & 15, q = lane >> 4;
  size_t rowbase = (size_t)b*L_ + (size_t)c*QCH;
  float eA = __expf(A_log[h]);

  __shared__ __align__(16) bf16 sB[128*128];
  __shared__ __align__(16) bf16 sC[128*128];
  __shared__ __align__(16) bf16 sDX[64*128];
  __shared__ __align__(16) bf16 sBT[128*128];
  __shared__ float sDT[128];
  __shared__ float sL[128];
  __shared__ float sWS[128];
  __shared__ float sWT[2];

  #pragma unroll
  for (int i=0;i<8;i++){
    int id = i*512 + tid;
    int row = id >> 5, cg = id & 31;
    uint4 u = *(const uint4*)(xbc + (rowbase+row)*CONVDIM + DI + cg*8);
    if (cg < 16) *(uint4*)&sB[row*128 + ((cg ^ (row&15))<<3)] = u;
    else { int cg2 = cg-16; *(uint4*)&sC[row*128 + ((cg2 ^ (row&15))<<3)] = u; }
  }
  {
    int s0 = (tid >> 3)*2;
    int p0 = (tid & 7)*8;
    const bf16* x0 = xbc + (rowbase+s0)*CONVDIM + h*HD + p0;
    uint4 u0 = *(const uint4*)x0;
    uint4 u1 = *(const uint4*)(x0 + CONVDIM);
    unsigned a0[4]={u0.x,u0.y,u0.z,u0.w}, a1[4]={u1.x,u1.y,u1.z,u1.w};
    int cb2 = s0 >> 3, se = s0 & 7;
    #pragma unroll
    for (int jp=0;jp<4;jp++){
      unsigned w0=a0[jp], w1=a1[jp];
      unsigned lo = (w0 & 0xffffu) | (w1 << 16);
      unsigned hi = (w0 >> 16) | (w1 & 0xffff0000u);
      int pA = p0 + jp*2, pB = pA+1;
      *(unsigned*)&sDX[pA*128 + ((cb2 ^ (pA&15))<<3) + se] = lo;
      *(unsigned*)&sDX[pB*128 + ((cb2 ^ (pB&15))<<3) + se] = hi;
    }
  }
  if (tid < 128) sDT[tid] = dtv[(rowbase+tid)*NH + h];
  __syncthreads();

  float inc = 0.f;
  if (tid < 128){
    inc = sDT[tid];
    #pragma unroll
    for (int off=1; off<64; off<<=1){
      float u = __shfl_up(inc, off);
      if (lane >= off) inc += u;
    }
    if (lane==63) sWT[wid] = inc;
  }
  __syncthreads();
  if (tid < 128){
    if (wid==1) inc += sWT[0];
    sL[tid] = inc;
  }

  int wr = wid >> 1, wc = wid & 1;
  f32x4 accG[2][4];
  #pragma unroll
  for (int i=0;i<2;i++)
    #pragma unroll
    for (int j=0;j<4;j++) accG[i][j] = (f32x4){0.f,0.f,0.f,0.f};
  #pragma unroll
  for (int ks=0; ks<4; ks++){
    bf16x8 af[2], bfv[4];
    #pragma unroll
    for (int mf=0;mf<2;mf++){
      int s = wr*32 + mf*16 + r;
      af[mf] = *(const bf16x8*)&sB[s*128 + (((ks*4+q) ^ (s&15))<<3)];
    }
    #pragma unroll
    for (int nf=0;nf<4;nf++){
      int t = wc*64 + nf*16 + r;
      bfv[nf] = *(const bf16x8*)&sC[t*128 + (((ks*4+q) ^ (t&15))<<3)];
    }
    #pragma unroll
    for (int mf=0;mf<2;mf++)
      #pragma unroll
      for (int nf=0;nf<4;nf++)
        accG[mf][nf] = __builtin_amdgcn_mfma_f32_16x16x32_bf16(af[mf], bfv[nf], accG[mf][nf], 0, 0, 0);
  }
  __syncthreads();

  bf16* sW = sC;
  #pragma unroll
  for (int mf=0;mf<2;mf++){
    int sb4 = wr*32 + mf*16 + q*4;
    int cb4 = sb4 >> 3, se4 = sb4 & 7;
    #pragma unroll
    for (int nf=0;nf<4;nf++){
      int t = wc*64 + nf*16 + r;
      float Lt = sL[t];
      float w[4];
      #pragma unroll
      for (int rr=0;rr<4;rr++){
        int s = sb4 + rr;
        float v = 0.f;
        if (s <= t) v = accG[mf][nf][rr] * sDT[s] * __expf(-eA*(Lt - sL[s]));
        w[rr] = v;
      }
      *(uint2*)&sW[t*128 + ((cb4 ^ (t&15))<<3) + se4] =
          make_uint2(pack2bf(w[0],w[1]), pack2bf(w[2],w[3]));
    }
  }
  if (tid < 128) sWS[tid] = sDT[tid]*__expf(-eA*(sL[127]-sL[tid]));
  __syncthreads();

  {
    int n = tid >> 2, sg = tid & 3;
    #pragma unroll
    for (int i8=0;i8<4;i8++){
      unsigned short vals[8];
      #pragma unroll
      for (int j=0;j<8;j++){
        int s = sg*32 + i8*8 + j;
        float bv = bf2f(sB[s*128 + (((n>>3) ^ (s&15))<<3) + (n&7)]);
        vals[j] = f2bf(bv * sWS[s]);
      }
      int s8 = sg*4 + i8;
      *(uint4*)&sBT[n*128 + ((s8 ^ (n&15))<<3)] = *(const uint4*)vals;
    }
  }
  __syncthreads();

  {
    int wrp = wid >> 2, wct = wid & 3;
    f32x4 acc2[2][2];
    #pragma unroll
    for (int i=0;i<2;i++){ acc2[i][0]=(f32x4){0.f,0.f,0.f,0.f}; acc2[i][1]=(f32x4){0.f,0.f,0.f,0.f}; }
    #pragma unroll
    for (int ks=0; ks<4; ks++){
      bf16x8 af[2], bfv[2];
      #pragma unroll
      for (int mf=0;mf<2;mf++){
        int p = wrp*32 + mf*16 + r;
        af[mf] = *(const bf16x8*)&sDX[p*128 + (((ks*4+q) ^ (p&15))<<3)];
      }
      #pragma unroll
      for (int nf=0;nf<2;nf++){
        int t = wct*32 + nf*16 + r;
        bfv[nf] = *(const bf16x8*)&sW[t*128 + (((ks*4+q) ^ (t&15))<<3)];
      }
      #pragma unroll
      for (int mf=0;mf<2;mf++)
        #pragma unroll
        for (int nf=0;nf<2;nf++)
          acc2[mf][nf] = __builtin_amdgcn_mfma_f32_16x16x32_bf16(af[mf], bfv[nf], acc2[mf][nf], 0, 0, 0);
    }
    #pragma unroll
    for (int mf=0;mf<2;mf++){
      int pb = wrp*32 + mf*16 + q*4;
      #pragma unroll
      for (int nf=0;nf<2;nf++){
        int t = wct*32 + nf*16 + r;
        f32x4 v = acc2[mf][nf];
        *(uint2*)(ys + (rowbase+t)*DI + h*HD + pb) =
            make_uint2(pack2bf(v[0],v[1]), pack2bf(v[2],v[3]));
      }
    }
  }

  {
    int wrn = wid >> 1, wcp = wid & 1;
    f32x4 acc3[2][2];
    #pragma unroll
    for (int i=0;i<2;i++){ acc3[i][0]=(f32x4){0.f,0.f,0.f,0.f}; acc3[i][1]=(f32x4){0.f,0.f,0.f,0.f}; }
    #pragma unroll
    for (int ks=0; ks<4; ks++){
      bf16x8 af[2], bfv[2];
      #pragma unroll
      for (int mf=0;mf<2;mf++){
        int n = wrn*32 + mf*16 + r;
        af[mf] = *(const bf16x8*)&sBT[n*128 + (((ks*4+q) ^ (n&15))<<3)];
      }
      #pragma unroll
      for (int nf=0;nf<2;nf++){
        int p = wcp*32 + nf*16 + r;
        bfv[nf] = *(const bf16x8*)&sDX[p*128 + (((ks*4+q) ^ (p&15))<<3)];
      }
      #pragma unroll
      for (int mf=0;mf<2;mf++)
        #pragma unroll
        for (int nf=0;nf<2;nf++)
          acc3[mf][nf] = __builtin_amdgcn_mfma_f32_16x16x32_bf16(af[mf], bfv[nf], acc3[mf][nf], 0, 0, 0);
    }
    size_t sb = (((size_t)(b*NH+h))*NCH + c)*8192;
    #pragma unroll
    for (int mf=0;mf<2;mf++){
      int nb = wrn*32 + mf*16 + q*4;
      #pragma unroll
      for (int nf=0;nf<2;nf++){
        int p = wcp*32 + nf*16 + r;
        f32x4 v = acc3[mf][nf];
        *(uint2*)(Sst + sb + (size_t)p*128 + nb) =
            make_uint2(pack2bf(v[0],v[1]), pack2bf(v[2],v[3]));
      }
    }
  }
}

// ---------------- pass 2: prefix-combine chunk states ----------------
template<int NCHT, int QCHT>
__global__ __launch_bounds__(256) void k_scan2(bf16* __restrict__ Sst, const float* __restrict__ dAv) {
  constexpr int SEG = QCHT/16;
  int blk = blockIdx.x;
  int bh = blk>>2, q = blk&3;
  int b = bh>>3, h = bh&7;
  int tid = threadIdx.x;
  __shared__ float sP[NCHT];
  {
    int c = tid / SEG, seg = tid & (SEG-1);
    float prod = 1.f;
    size_t base = ((size_t)b*L_ + c*QCHT + seg*16)*NH + h;
    #pragma unroll
    for (int k=0;k<16;k++) prod *= dAv[base + (size_t)k*NH];
    #pragma unroll
    for (int off=1; off<SEG; off<<=1) prod *= __shfl_xor(prod, off);
    if (seg==0) sP[c] = prod;
  }
  __syncthreads();
  int e0 = q*2048 + tid*8;
  float acc[8];
  #pragma unroll
  for (int j=0;j<8;j++) acc[j]=0.f;
  size_t sbase = (size_t)bh*NCHT*8192 + e0;
  for (int c=0;c<NCHT;c++){
    bf16* ptr = Sst + sbase + (size_t)c*8192;
    uint4 u = *(const uint4*)ptr;
    unsigned int uu[4] = {u.x,u.y,u.z,u.w};
    float tv[8];
    #pragma unroll
    for (int k=0;k<4;k++){
      tv[2*k]   = __uint_as_float(uu[k]<<16);
      tv[2*k+1] = __uint_as_float(uu[k]&0xffff0000u);
    }
    uint4 o;
    o.x = pack2bf(acc[0],acc[1]); o.y = pack2bf(acc[2],acc[3]);
    o.z = pack2bf(acc[4],acc[5]); o.w = pack2bf(acc[6],acc[7]);
    asm volatile("s_waitcnt vmcnt(0)" ::: "memory");
    *(uint4*)ptr = o;
    float P = sP[c];
    #pragma unroll
    for (int j=0;j<8;j++) acc[j] = tv[j] + P*acc[j];
  }
}

// ================= SSD pass 3: Y += exp(-eA*L_t) * (C x I_c), swapped (b64 RMW) =================
__global__ __launch_bounds__(256) void k_ssd3(const bf16* __restrict__ xbc,
    const float* __restrict__ dtv, const float* __restrict__ A_log,
    const bf16* __restrict__ Sst, bf16* __restrict__ ys) {
  int blk = blockIdx.x;
  int c = blk & (NCH-1), h = (blk>>5)&7, b = blk>>8;
  int tid = threadIdx.x;
  int lane = tid & 63, wid = tid >> 6;
  int r = lane & 15, q = lane >> 4;
  size_t rowbase = (size_t)b*L_ + (size_t)c*QCH;
  float eA = __expf(A_log[h]);

  __shared__ __align__(16) bf16 sC[128*128];
  __shared__ float sDT[128];
  __shared__ float sAt[128];
  __shared__ float sWT[2];

  #pragma unroll
  for (int i=0;i<8;i++){
    int id = i*256 + tid;
    int row = id >> 4, cg = id & 15;
    uint4 u = *(const uint4*)(xbc + (rowbase+row)*CONVDIM + DI + NS + cg*8);
    *(uint4*)&sC[row*128 + ((cg ^ (row&15))<<3)] = u;
  }
  if (tid < 128) sDT[tid] = dtv[(rowbase+tid)*NH + h];
  __syncthreads();
  float inc = 0.f;
  if (tid < 128){
    inc = sDT[tid];
    #pragma unroll
    for (int off=1; off<64; off<<=1){
      float u = __shfl_up(inc, off);
      if (lane >= off) inc += u;
    }
    if (lane==63) sWT[wid] = inc;
  }
  __syncthreads();
  if (tid < 128){
    if (wid==1) inc += sWT[0];
    sAt[tid] = __expf(-eA*inc);
  }
  __syncthreads();

  int wrp = wid >> 1, wct = wid & 1;
  size_t sb = (((size_t)(b*NH+h))*NCH + c)*8192;
  f32x4 accP[2][4];
  #pragma unroll
  for (int i=0;i<2;i++)
    #pragma unroll
    for (int j=0;j<4;j++) accP[i][j] = (f32x4){0.f,0.f,0.f,0.f};
  #pragma unroll
  for (int ks=0; ks<4; ks++){
    bf16x8 af[2], bfv[4];
    #pragma unroll
    for (int mf=0;mf<2;mf++){
      int p = wrp*32 + mf*16 + r;
      af[mf] = *(const bf16x8*)(Sst + sb + (size_t)p*128 + ks*32 + q*8);
    }
    #pragma unroll
    for (int nf=0;nf<4;nf++){
      int t = wct*64 + nf*16 + r;
      bfv[nf] = *(const bf16x8*)&sC[t*128 + (((ks*4+q) ^ (t&15))<<3)];
    }
    #pragma unroll
    for (int mf=0;mf<2;mf++)
      #pragma unroll
      for (int nf=0;nf<4;nf++)
        accP[mf][nf] = __builtin_amdgcn_mfma_f32_16x16x32_bf16(af[mf], bfv[nf], accP[mf][nf], 0, 0, 0);
  }
  #pragma unroll
  for (int mf=0;mf<2;mf++){
    int pb = wrp*32 + mf*16 + q*4;
    #pragma unroll
    for (int nf=0;nf<4;nf++){
      int t = wct*64 + nf*16 + r;
      float at = sAt[t];
      bf16* yp = ys + (rowbase+t)*DI + h*HD + pb;
      uint2 old = *(uint2*)yp;
      float o0 = bf2f((bf16)(old.x & 0xffffu))  + at*accP[mf][nf][0];
      float o1 = bf2f((bf16)(old.x >> 16))      + at*accP[mf][nf][1];
      float o2 = bf2f((bf16)(old.y & 0xffffu))  + at*accP[mf][nf][2];
      float o3 = bf2f((bf16)(old.y >> 16))      + at*accP[mf][nf][3];
      *(uint2*)yp = make_uint2(pack2bf(o0,o1), pack2bf(o2,o3));
    }
  }
}

// ---------------- y = (ys + D*xh)*silu(z), RMSNorm*w, in place (bf16) ----------------
__global__ __launch_bounds__(256) void k_combine(bf16* __restrict__ ys, const bf16* __restrict__ xbc,
                         const bf16* __restrict__ z, const float* __restrict__ Dp,
                         const float* __restrict__ nw) {
  int bl = blockIdx.x;
  int tid = threadIdx.x;
  bf16* yrow = ys + (size_t)bl*DI;
  const bf16* xrow = xbc + (size_t)bl*CONVDIM;
  const bf16* zrow = z + (size_t)bl*DI;
  float v[2]; float ss = 0.f;
  #pragma unroll
  for (int i=0;i<2;i++) {
    int d = tid + i*256;
    float xh = bf2f(xrow[d]);
    float y = bf2f(yrow[d]) + Dp[d>>6]*xh;
    float zv = bf2f(zrow[d]);
    y *= zv / (1.f + expf(-zv));
    v[i] = y; ss += y*y;
  }
  #pragma unroll
  for (int off=1; off<64; off<<=1) ss += __shfl_xor(ss, off);
  __shared__ float sb[4];
  if ((tid&63)==0) sb[tid>>6]=ss;
  __syncthreads();
  float total = sb[0]+sb[1]+sb[2]+sb[3];
  float scale = rsqrtf(total * (1.f/512.f) + 1e-5f);
  #pragma unroll
  for (int i=0;i<2;i++) {
    int d = tid + i*256;
    yrow[d] = f2bf(v[i]*scale*nw[d]);
  }
}

extern "C" void kernel_launch(void* const* d_in, const int* in_sizes, int n_in,
                              void* d_out, int out_size, void* d_ws, size_t ws_size,
                              hipStream_t stream) {
  const float* x         = (const float*)d_in[0];
  const float* conv_w    = (const float*)d_in[1];
  const float* conv_b    = (const float*)d_in[2];
  const float* bn_gamma  = (const float*)d_in[3];
  const float* bn_beta   = (const float*)d_in[4];
  const float* patch_w   = (const float*)d_in[5];
  const float* patch_b   = (const float*)d_in[6];
  const float* in_proj_w = (const float*)d_in[7];
  const float* conv1d_w  = (const float*)d_in[8];
  const float* conv1d_b  = (const float*)d_in[9];
  const float* dt_bias   = (const float*)d_in[10];
  const float* A_log     = (const float*)d_in[11];
  const float* Dp        = (const float*)d_in[12];
  const float* norm_w    = (const float*)d_in[13];
  const float* out_proj_w= (const float*)d_in[14];
  const float* final_w   = (const float*)d_in[15];
  const float* final_b   = (const float*)d_in[16];
  float* out = (float*)d_out;

  char* Wb = (char*)d_ws;
  float* h_buf = (float*)(Wb + 0);
  bf16*  winb  = (bf16*)(Wb + 0);
  bf16*  woutb = (bf16*)(Wb + 0);
  bf16*  wfinb = (bf16*)(Wb + 262144);
  bf16*  xpost = (bf16*)(Wb + 0);
  float2* part = (float2*)(Wb + 50331648);
  bf16*  tok   = (bf16*)(Wb + 50331648);
  bf16*  zbuf  = (bf16*)(Wb + 67108864);
  bf16*  y2b   = (bf16*)(Wb + 67108864);
  bf16*  xpre  = (bf16*)(Wb + 100663296);
  bf16*  ysb   = (bf16*)(Wb + 100663296);
  bf16*  Sst   = (bf16*)(Wb + 134217728);
  float* dtv   = (float*)(Wb + 134217728 + 33554432);
  float* dAv   = dtv + 262144;
  float* stats = dAv + 262144;
  const size_t NEED = 134217728ull + 33554432 + 2097152 + 256;
  if (ws_size < NEED) {
    hipMemsetAsync(d_out, 0, (size_t)out_size*sizeof(float), stream);
    return;
  }

  k_conv1<<<dim3((B_*CMID*HMID*WMID)/256), dim3(256), 0, stream>>>(x, conv_w, conv_b, h_buf);
  k_bnstatsA<<<dim3(512), dim3(256), 0, stream>>>(h_buf, part);
  k_bnstatsB<<<dim3(1), dim3(64), 0, stream>>>(part, stats);
  k_patch<<<dim3(MTOK/8), dim3(256), 0, stream>>>(h_buf, patch_w, patch_b, stats, bn_gamma, bn_beta, tok);
  k_cvtw<<<dim3((NPADIN*DM)/256), dim3(256), 0, stream>>>(in_proj_w, winb, PROJ, 8, NPADIN*DM);
  k_mgemm<0><<<dim3(MTOK/128, NPADIN/128), dim3(256), 0, stream>>>(tok, winb, DM,
      zbuf, xpre, nullptr, nullptr, dt_bias, A_log, dtv, dAv, nullptr, nullptr);
  k_conv1d<<<dim3((MTOK/8*96)/256), dim3(256), 0, stream>>>(xpre, conv1d_w, conv1d_b, xpost);
  k_ssd1<<<dim3(B_*NH*NCH), dim3(512), 0, stream>>>(xpost, dtv, A_log, ysb, Sst);
  k_scan2<NCH,QCH><<<dim3(B_*NH*4), dim3(256), 0, stream>>>(Sst, dAv);
  k_ssd3<<<dim3(B_*NH*NCH), dim3(256), 0, stream>>>(xpost, dtv, A_log, Sst, ysb);
  k_combine<<<dim3(MTOK), dim3(256), 0, stream>>>(ysb, xpost, zbuf, Dp, norm_w);
  k_cvtw<<<dim3((DM*DI)/256), dim3(256), 0, stream>>>(out_proj_w, woutb, DM, 9, DM*DI);
  k_cvtw<<<dim3((128*DM)/256), dim3(256), 0, stream>>>(final_w, wfinb, 64, 8, 128*DM);
  k_mgemm<1><<<dim3(MTOK/128, DM/128), dim3(256), 0, stream>>>(ysb, woutb, DI,
      nullptr, nullptr, y2b, tok, nullptr, nullptr, nullptr, nullptr, nullptr, nullptr);
  k_mgemm<2><<<dim3(MTOK/128, 1), dim3(256), 0, stream>>>(y2b, wfinb, DM,
      nullptr, nullptr, nullptr, nullptr, nullptr, nullptr, nullptr, nullptr, out, final_b);
}

// Round 11
// 326.631 us; speedup vs baseline: 11.2828x; 1.0567x over previous
//
#include <hip/hip_runtime.h>
#include <math.h>

#define B_  8
#define CIN 3
#define HIN 256
#define WIN 256
#define CMID 16
#define HMID 128
#define WMID 128
#define DM 256
#define L_ 4096
#define DI 512
#define NH 8
#define HD 64
#define NS 128
#define KC 4
#define CONVDIM 768
#define PROJ 1288
#define NPADIN 1408
#define MTOK (B_*L_)
#define QCH 128          // chunk length (SSD)
#define NCH 32           // number of chunks

typedef unsigned short bf16;
typedef __attribute__((ext_vector_type(8))) short bf16x8;
typedef __attribute__((ext_vector_type(4))) float f32x4;

__device__ inline float bf2f(bf16 u) { return __uint_as_float(((unsigned int)u) << 16); }
__device__ inline bf16 f2bf(float f) {
  unsigned int x = __float_as_uint(f);
  return (bf16)((x + 0x7fffu + ((x >> 16) & 1u)) >> 16);
}
__device__ inline unsigned int pack2bf(float a, float b) {
  return (unsigned int)f2bf(a) | ((unsigned int)f2bf(b) << 16);
}

// ---------------- conv 3x3 stride 2 pad 1 ----------------
__global__ void k_conv1(const float* __restrict__ x, const float* __restrict__ w,
                        const float* __restrict__ bias, float* __restrict__ out) {
  int idx = blockIdx.x*256 + threadIdx.x;
  if (idx >= B_*CMID*HMID*WMID) return;
  int xo = idx & 127, yo = (idx>>7)&127, co = (idx>>14)&15, b = idx>>18;
  float acc = bias[co];
  const float* xb = x + (size_t)b*CIN*HIN*WIN;
  const float* wc = w + co*CIN*9;
  #pragma unroll
  for (int ci=0; ci<CIN; ci++)
    #pragma unroll
    for (int ky=0; ky<3; ky++) {
      int yi = 2*yo - 1 + ky;
      if (yi < 0 || yi >= HIN) continue;
      #pragma unroll
      for (int kx=0; kx<3; kx++) {
        int xi = 2*xo - 1 + kx;
        if (xi < 0 || xi >= WIN) continue;
        acc += xb[(ci*HIN + yi)*WIN + xi] * wc[(ci*3+ky)*3+kx];
      }
    }
  out[idx] = acc;
}

// ---------------- BN stats stage A ----------------
__global__ __launch_bounds__(256) void k_bnstatsA(const float* __restrict__ h, float2* __restrict__ part) {
  int blk = blockIdx.x;
  const float4* base = (const float4*)(h + ((size_t)(blk>>2))*16384 + (blk&3)*4096);
  int tid = threadIdx.x;
  float s=0.f, s2=0.f;
  #pragma unroll
  for (int i=0;i<4;i++){
    float4 v = base[i*256 + tid];
    s += v.x+v.y+v.z+v.w;
    s2 += v.x*v.x + v.y*v.y + v.z*v.z + v.w*v.w;
  }
  #pragma unroll
  for (int off=1; off<64; off<<=1) { s += __shfl_xor(s, off); s2 += __shfl_xor(s2, off); }
  __shared__ float sb[2][4];
  if ((tid&63)==0){ sb[0][tid>>6]=s; sb[1][tid>>6]=s2; }
  __syncthreads();
  if (tid==0) part[blk] = make_float2(sb[0][0]+sb[0][1]+sb[0][2]+sb[0][3],
                                      sb[1][0]+sb[1][1]+sb[1][2]+sb[1][3]);
}

// ---------------- BN stats stage B ----------------
__global__ void k_bnstatsB(const float2* __restrict__ part, float* __restrict__ stats) {
  int lane = threadIdx.x;
  int c = lane >> 2, j0 = lane & 3;
  float s=0.f, s2=0.f;
  #pragma unroll
  for (int j=j0; j<32; j+=4){
    int b = j >> 2, chunk = j & 3;
    float2 p = part[(b*16+c)*4 + chunk];
    s += p.x; s2 += p.y;
  }
  s += __shfl_xor(s,1); s2 += __shfl_xor(s2,1);
  s += __shfl_xor(s,2); s2 += __shfl_xor(s2,2);
  if (j0==0){
    const float inv = 1.f/131072.f;
    float mean = s*inv;
    float var  = s2*inv - mean*mean;
    stats[c]      = mean;
    stats[16 + c] = rsqrtf(var + 1e-5f);
  }
}

// ---------------- patch conv 2x2 s2 (+fused BN+GELU) + bias + sincos -> tok ----------------
__global__ __launch_bounds__(256) void k_patch(const float* __restrict__ h, const float* __restrict__ pw,
                       const float* __restrict__ pb, const float* __restrict__ stats,
                       const float* __restrict__ gamma, const float* __restrict__ beta,
                       bf16* __restrict__ tok) {
  int grp = blockIdx.x;
  int b = grp >> 9, g8 = grp & 511;
  int g0 = g8 << 3;
  int gy = g0 >> 6, gx0 = g0 & 63;
  __shared__ float sh[8][64];
  int tid = threadIdx.x;
  {
    int tk = tid >> 5, jj = (tid & 31)*2;
    int ci = jj >> 2, p = (jj >> 1) & 1;
    const float* src = &h[((size_t)(b*CMID+ci)*HMID + 2*gy+p)*WMID + 2*(gx0+tk)];
    float2 xv = *(const float2*)src;
    float mean = stats[ci], rstd = stats[16+ci];
    float sc = rstd*gamma[ci], be = beta[ci] - mean*sc;
    float v0 = xv.x*sc + be;
    float v1 = xv.y*sc + be;
    v0 = 0.5f*v0*(1.f + erff(v0*0.70710678118654752f));
    v1 = 0.5f*v1*(1.f + erff(v1*0.70710678118654752f));
    sh[tk][jj] = v0; sh[tk][jj+1] = v1;
  }
  __syncthreads();
  int d = tid;
  float wr[64];
  #pragma unroll
  for (int i4=0;i4<16;i4++) *(float4*)&wr[i4*4] = *(const float4*)&pw[d*64 + i4*4];
  float bias = pb[d];
  int i = d & 63;
  float omega = expf(-(float)i * (9.210340371976184f/64.f));
  #pragma unroll
  for (int tk=0;tk<8;tk++){
    float acc = bias;
    #pragma unroll
    for (int j=0;j<64;j++) acc = fmaf(sh[tk][j], wr[j], acc);
    float gv = (d < 128) ? (float)(gx0+tk) : (float)gy;
    float ph = gv * omega;
    float pos = (d & 64) ? __cosf(ph) : __sinf(ph);
    tok[((size_t)((b<<12) + g0 + tk))*DM + d] = f2bf(acc + pos);
  }
}

// ---------------- weight f32 -> bf16 (with zero-padding to Npad rows) ----------------
__global__ void k_cvtw(const float* __restrict__ src, bf16* __restrict__ dst,
                       int N, int kshift, int total) {
  int idx = blockIdx.x*256 + threadIdx.x;
  if (idx >= total) return;
  int n = idx >> kshift;
  dst[idx] = (n < N) ? f2bf(src[idx]) : (bf16)0;
}

// ---------------- MFMA bf16 GEMM, 256x128 tile, 512 thr, OPERAND-SWAPPED ----------------
// af = Bw fragments (n-rows), bfv = A fragments (m-rows) -> acc rows = n quads, cols = m.
template<int EPI>
__global__ __launch_bounds__(512) void k_mgemm(
    const bf16* __restrict__ A, const bf16* __restrict__ Bw, int K,
    bf16* __restrict__ o_z, bf16* __restrict__ o_x,
    bf16* __restrict__ o_y, const bf16* __restrict__ res,
    const float* __restrict__ dt_bias, const float* __restrict__ A_log,
    float* __restrict__ dtv, float* __restrict__ dAv,
    float* __restrict__ o_f, const float* __restrict__ fbias) {
  __shared__ __align__(16) bf16 sA[2][256*32];
  __shared__ __align__(16) bf16 sB[2][128*32];
  int tid = threadIdx.x;
  int lane = tid & 63, wid = tid >> 6;     // 8 waves
  int wr = wid >> 1, wc = wid & 1;         // wr: m tile (4x64), wc: n tile (2x64)
  int m0 = blockIdx.x*256, n0 = blockIdx.y*128;
  int nk = K >> 5;

  f32x4 acc[4][4];
  #pragma unroll
  for (int i=0;i<4;i++)
    #pragma unroll
    for (int j=0;j<4;j++)
      acc[i][j] = (f32x4){0.f,0.f,0.f,0.f};

  auto stage = [&](int buf, int ks){
    int kk = ks << 5;
    #pragma unroll
    for (int i=0;i<2;i++){
      int j = i*512 + tid;
      int row = j >> 2, cc = j & 3;
      int kg = cc ^ (row & 3);
      unsigned ldsoff = (unsigned)((i*512 + wid*64) * 16);
      __builtin_amdgcn_global_load_lds(
        (const __attribute__((address_space(1))) void*)(A + (size_t)(m0+row)*K + kk + kg*8),
        (__attribute__((address_space(3))) void*)((char*)&sA[buf][0] + ldsoff), 16, 0, 0);
    }
    {
      int row = tid >> 2, cc = tid & 3;
      int kg = cc ^ (row & 3);
      unsigned ldsoff = (unsigned)((wid*64) * 16);
      __builtin_amdgcn_global_load_lds(
        (const __attribute__((address_space(1))) void*)(Bw + (size_t)(n0+row)*K + kk + kg*8),
        (__attribute__((address_space(3))) void*)((char*)&sB[buf][0] + ldsoff), 16, 0, 0);
    }
  };

  int r = lane & 15, q = lane >> 4;
  int kgo = (q ^ (r & 3)) << 3;

  stage(0, 0);
  for (int ks=0; ks<nk; ++ks){
    int cur = ks & 1;
    __syncthreads();
    if (ks+1 < nk) stage(cur^1, ks+1);
    bf16x8 af[4], bfv[4];
    #pragma unroll
    for (int a=0;a<4;a++){
      int rown = wc*64 + a*16 + r;
      af[a] = *(const bf16x8*)&sB[cur][rown*32 + kgo];
    }
    #pragma unroll
    for (int bfr=0;bfr<4;bfr++){
      int rowm = wr*64 + bfr*16 + r;
      bfv[bfr] = *(const bf16x8*)&sA[cur][rowm*32 + kgo];
    }
    #pragma unroll
    for (int a=0;a<4;a++)
      #pragma unroll
      for (int bfr=0;bfr<4;bfr++)
        acc[a][bfr] = __builtin_amdgcn_mfma_f32_16x16x32_bf16(af[a], bfv[bfr], acc[a][bfr], 0, 0, 0);
  }

  #pragma unroll
  for (int a=0;a<4;a++){
    int n4 = n0 + wc*64 + a*16 + q*4;
    #pragma unroll
    for (int bfr=0;bfr<4;bfr++){
      int m = m0 + wr*64 + bfr*16 + r;
      f32x4 v = acc[a][bfr];
      if (EPI == 0){
        if (n4 < DI) {
          *(uint2*)(o_z + (size_t)m*DI + n4) = make_uint2(pack2bf(v[0],v[1]), pack2bf(v[2],v[3]));
        } else if (n4 < DI + CONVDIM) {
          *(uint2*)(o_x + (size_t)m*CONVDIM + (n4 - DI)) = make_uint2(pack2bf(v[0],v[1]), pack2bf(v[2],v[3]));
        } else if (n4 < PROJ) {
          #pragma unroll
          for (int rr=0;rr<4;rr++){
            int hh = n4 + rr - (DI + CONVDIM);
            float xv = v[rr] + dt_bias[hh];
            float dt = (xv > 20.f) ? xv : log1pf(expf(xv));
            dtv[(size_t)m*NH + hh] = dt;
            dAv[(size_t)m*NH + hh] = expf(-expf(A_log[hh]) * dt);
          }
        }
      } else if (EPI == 1) {
        uint2 rv = *(const uint2*)(res + (size_t)m*DM + n4);
        float r0 = bf2f((bf16)(rv.x & 0xffffu)), r1 = bf2f((bf16)(rv.x >> 16));
        float r2 = bf2f((bf16)(rv.y & 0xffffu)), r3 = bf2f((bf16)(rv.y >> 16));
        *(uint2*)(o_y + (size_t)m*DM + n4) =
            make_uint2(pack2bf(v[0]+r0, v[1]+r1), pack2bf(v[2]+r2, v[3]+r3));
      } else {
        #pragma unroll
        for (int rr=0;rr<4;rr++){
          int n = n4 + rr;
          if (n < 64) {
            float vv = v[rr] + fbias[n];
            int b = m >> 12, g = m & 4095;
            int gy = g >> 6, gx = g & 63;
            int p = n >> 5, qq = (n>>4)&1, cc2 = n & 15;
            o_f[(((size_t)(b*CMID+cc2))*HMID + 2*gy+p)*WMID + (2*gx+qq)] = vv;
          }
        }
      }
    }
  }
}

// ---------------- causal depthwise conv1d (KC=4) + bias + silu ----------------
__global__ __launch_bounds__(256) void k_conv1d(const bf16* __restrict__ xpre, const float* __restrict__ cw,
                         const float* __restrict__ cb, bf16* __restrict__ xbc) {
  int idx = blockIdx.x*256 + threadIdx.x;
  int gch = idx % 96;
  int tb  = idx / 96;
  int ch0 = gch*8;
  int bl0 = tb*8;
  int l0 = bl0 & (L_-1);
  float wv[32];
  #pragma unroll
  for (int i=0;i<8;i++) *(float4*)&wv[i*4] = *(const float4*)&cw[ch0*KC + i*4];
  float bs[8];
  *(float4*)&bs[0] = *(const float4*)&cb[ch0];
  *(float4*)&bs[4] = *(const float4*)&cb[ch0+4];
  uint4 rows[11];
  #pragma unroll
  for (int j=0;j<11;j++){
    int lk = l0 - 3 + j;
    if (lk < 0) rows[j] = make_uint4(0u,0u,0u,0u);
    else rows[j] = *(const uint4*)(xpre + ((size_t)bl0 - 3 + j)*CONVDIM + ch0);
  }
  #pragma unroll
  for (int t=0;t<8;t++){
    float acc[8];
    #pragma unroll
    for (int i=0;i<8;i++) acc[i] = bs[i];
    #pragma unroll
    for (int k=0;k<KC;k++){
      uint4 u = rows[t+k];
      unsigned uu[4]={u.x,u.y,u.z,u.w};
      #pragma unroll
      for (int c2=0;c2<4;c2++){
        float lo = __uint_as_float(uu[c2]<<16);
        float hi = __uint_as_float(uu[c2]&0xffff0000u);
        acc[c2*2]   = fmaf(wv[(c2*2)*4 + k],   lo, acc[c2*2]);
        acc[c2*2+1] = fmaf(wv[(c2*2+1)*4 + k], hi, acc[c2*2+1]);
      }
    }
    unsigned ou[4];
    #pragma unroll
    for (int c2=0;c2<4;c2++){
      float v0 = acc[c2*2], v1 = acc[c2*2+1];
      v0 = v0 / (1.f + __expf(-v0));
      v1 = v1 / (1.f + __expf(-v1));
      ou[c2] = pack2bf(v0, v1);
    }
    *(uint4*)(xbc + (size_t)(bl0+t)*CONVDIM + ch0) = make_uint4(ou[0],ou[1],ou[2],ou[3]);
  }
}

// ================= SSD pass 1: 80KB LDS (2 blocks/CU), in-place BT, late DX =================
__global__ __launch_bounds__(512) void k_ssd1(const bf16* __restrict__ xbc,
    const float* __restrict__ dtv, const float* __restrict__ A_log,
    bf16* __restrict__ ys, bf16* __restrict__ Sst) {
  int blk = blockIdx.x;
  int c = blk & (NCH-1), h = (blk>>5)&7, b = blk>>8;
  int tid = threadIdx.x;
  int lane = tid & 63, wid = tid >> 6;     // 8 waves
  int r = lane & 15, q = lane >> 4;
  size_t rowbase = (size_t)b*L_ + (size_t)c*QCH;
  float eA = __expf(A_log[h]);

  __shared__ __align__(16) char smem[81920];
  bf16* sB  = (bf16*)smem;                 // 32K: B [s][n] -> becomes BT [n][s]
  bf16* sC  = (bf16*)(smem + 32768);       // 32K: C [t][n] -> becomes W [t][s]
  bf16* sDX = (bf16*)(smem + 65536);       // 16K: x^T [p][s], staged late
  float* fDT = (float*)(smem + 65536);     // overlay on sDX region (dead before DX staged)
  float* fL  = fDT + 128;
  float* fWS = fL + 128;
  float* fWT = fWS + 128;

  // ---- P1: stage B,C + dt ----
  #pragma unroll
  for (int i=0;i<8;i++){
    int id = i*512 + tid;
    int row = id >> 5, cg = id & 31;
    uint4 u = *(const uint4*)(xbc + (rowbase+row)*CONVDIM + DI + cg*8);
    if (cg < 16) *(uint4*)&sB[row*128 + ((cg ^ (row&15))<<3)] = u;
    else { int cg2 = cg-16; *(uint4*)&sC[row*128 + ((cg2 ^ (row&15))<<3)] = u; }
  }
  if (tid < 128) fDT[tid] = dtv[(rowbase+tid)*NH + h];
  __syncthreads();

  // ---- P2: prefix sum dt -> fL (two waves) ; G1 all threads ----
  float inc = 0.f;
  if (tid < 128){
    inc = fDT[tid];
    #pragma unroll
    for (int off=1; off<64; off<<=1){
      float u = __shfl_up(inc, off);
      if (lane >= off) inc += u;
    }
    if (lane==63) fWT[wid] = inc;
  }
  __syncthreads();
  if (tid < 128){
    if (wid==1) inc += fWT[0];
    fL[tid] = inc;
  }

  int wr = wid >> 1, wc = wid & 1;
  f32x4 accG[2][4];
  #pragma unroll
  for (int i=0;i<2;i++)
    #pragma unroll
    for (int j=0;j<4;j++) accG[i][j] = (f32x4){0.f,0.f,0.f,0.f};
  #pragma unroll
  for (int ks=0; ks<4; ks++){
    bf16x8 af[2], bfv[4];
    #pragma unroll
    for (int mf=0;mf<2;mf++){
      int s = wr*32 + mf*16 + r;
      af[mf] = *(const bf16x8*)&sB[s*128 + (((ks*4+q) ^ (s&15))<<3)];
    }
    #pragma unroll
    for (int nf=0;nf<4;nf++){
      int t = wc*64 + nf*16 + r;
      bfv[nf] = *(const bf16x8*)&sC[t*128 + (((ks*4+q) ^ (t&15))<<3)];
    }
    #pragma unroll
    for (int mf=0;mf<2;mf++)
      #pragma unroll
      for (int nf=0;nf<4;nf++)
        accG[mf][nf] = __builtin_amdgcn_mfma_f32_16x16x32_bf16(af[mf], bfv[nf], accG[mf][nf], 0, 0, 0);
  }
  __syncthreads();   // sC reads done; fL visible

  // ---- P3: W[t][s] into sC ; ws ----
  bf16* sW = sC;
  #pragma unroll
  for (int mf=0;mf<2;mf++){
    int sb4 = wr*32 + mf*16 + q*4;
    int cb4 = sb4 >> 3, se4 = sb4 & 7;
    #pragma unroll
    for (int nf=0;nf<4;nf++){
      int t = wc*64 + nf*16 + r;
      float Lt = fL[t];
      float w[4];
      #pragma unroll
      for (int rr=0;rr<4;rr++){
        int s = sb4 + rr;
        float v = 0.f;
        if (s <= t) v = accG[mf][nf][rr] * fDT[s] * __expf(-eA*(Lt - fL[s]));
        w[rr] = v;
      }
      *(uint2*)&sW[t*128 + ((cb4 ^ (t&15))<<3) + se4] =
          make_uint2(pack2bf(w[0],w[1]), pack2bf(w[2],w[3]));
    }
  }
  if (tid < 128) fWS[tid] = fDT[tid]*__expf(-eA*(fL[127]-fL[tid]));
  __syncthreads();

  // ---- P4a: read B*ws into regs (BT source) ----
  int nT = tid >> 2, sg = tid & 3;
  unsigned short vals[32];
  #pragma unroll
  for (int i8=0;i8<4;i8++){
    #pragma unroll
    for (int j=0;j<8;j++){
      int s = sg*32 + i8*8 + j;
      float bv = bf2f(sB[s*128 + (((nT>>3) ^ (s&15))<<3) + (nT&7)]);
      vals[i8*8+j] = f2bf(bv * fWS[s]);
    }
  }
  __syncthreads();   // all B reads + fWS reads complete

  // ---- P4b: write BT in place into sB ; stage x^T into sDX (overlay now dead) ----
  #pragma unroll
  for (int i8=0;i8<4;i8++){
    int s8 = sg*4 + i8;
    *(uint4*)&sB[nT*128 + ((s8 ^ (nT&15))<<3)] = *(const uint4*)&vals[i8*8];
  }
  {
    int s0 = (tid >> 3)*2;
    int p0 = (tid & 7)*8;
    const bf16* x0 = xbc + (rowbase+s0)*CONVDIM + h*HD + p0;
    uint4 u0 = *(const uint4*)x0;
    uint4 u1 = *(const uint4*)(x0 + CONVDIM);
    unsigned a0[4]={u0.x,u0.y,u0.z,u0.w}, a1[4]={u1.x,u1.y,u1.z,u1.w};
    int cb2 = s0 >> 3, se = s0 & 7;
    #pragma unroll
    for (int jp=0;jp<4;jp++){
      unsigned w0=a0[jp], w1=a1[jp];
      unsigned lo = (w0 & 0xffffu) | (w1 << 16);
      unsigned hi = (w0 >> 16) | (w1 & 0xffff0000u);
      int pA = p0 + jp*2, pB = pA+1;
      *(unsigned*)&sDX[pA*128 + ((cb2 ^ (pA&15))<<3) + se] = lo;
      *(unsigned*)&sDX[pB*128 + ((cb2 ^ (pB&15))<<3) + se] = hi;
    }
  }
  __syncthreads();

  // ---- P5: G2 -> ys ; G3 -> Sst ----
  {
    int wrp = wid >> 2, wct = wid & 3;
    f32x4 acc2[2][2];
    #pragma unroll
    for (int i=0;i<2;i++){ acc2[i][0]=(f32x4){0.f,0.f,0.f,0.f}; acc2[i][1]=(f32x4){0.f,0.f,0.f,0.f}; }
    #pragma unroll
    for (int ks=0; ks<4; ks++){
      bf16x8 af[2], bfv[2];
      #pragma unroll
      for (int mf=0;mf<2;mf++){
        int p = wrp*32 + mf*16 + r;
        af[mf] = *(const bf16x8*)&sDX[p*128 + (((ks*4+q) ^ (p&15))<<3)];
      }
      #pragma unroll
      for (int nf=0;nf<2;nf++){
        int t = wct*32 + nf*16 + r;
        bfv[nf] = *(const bf16x8*)&sW[t*128 + (((ks*4+q) ^ (t&15))<<3)];
      }
      #pragma unroll
      for (int mf=0;mf<2;mf++)
        #pragma unroll
        for (int nf=0;nf<2;nf++)
          acc2[mf][nf] = __builtin_amdgcn_mfma_f32_16x16x32_bf16(af[mf], bfv[nf], acc2[mf][nf], 0, 0, 0);
    }
    #pragma unroll
    for (int mf=0;mf<2;mf++){
      int pb = wrp*32 + mf*16 + q*4;
      #pragma unroll
      for (int nf=0;nf<2;nf++){
        int t = wct*32 + nf*16 + r;
        f32x4 v = acc2[mf][nf];
        *(uint2*)(ys + (rowbase+t)*DI + h*HD + pb) =
            make_uint2(pack2bf(v[0],v[1]), pack2bf(v[2],v[3]));
      }
    }
  }
  {
    int wrn = wid >> 1, wcp = wid & 1;
    f32x4 acc3[2][2];
    #pragma unroll
    for (int i=0;i<2;i++){ acc3[i][0]=(f32x4){0.f,0.f,0.f,0.f}; acc3[i][1]=(f32x4){0.f,0.f,0.f,0.f}; }
    #pragma unroll
    for (int ks=0; ks<4; ks++){
      bf16x8 af[2], bfv[2];
      #pragma unroll
      for (int mf=0;mf<2;mf++){
        int n = wrn*32 + mf*16 + r;
        af[mf] = *(const bf16x8*)&sB[n*128 + (((ks*4+q) ^ (n&15))<<3)];
      }
      #pragma unroll
      for (int nf=0;nf<2;nf++){
        int p = wcp*32 + nf*16 + r;
        bfv[nf] = *(const bf16x8*)&sDX[p*128 + (((ks*4+q) ^ (p&15))<<3)];
      }
      #pragma unroll
      for (int mf=0;mf<2;mf++)
        #pragma unroll
        for (int nf=0;nf<2;nf++)
          acc3[mf][nf] = __builtin_amdgcn_mfma_f32_16x16x32_bf16(af[mf], bfv[nf], acc3[mf][nf], 0, 0, 0);
    }
    size_t sb = (((size_t)(b*NH+h))*NCH + c)*8192;
    #pragma unroll
    for (int mf=0;mf<2;mf++){
      int nb = wrn*32 + mf*16 + q*4;
      #pragma unroll
      for (int nf=0;nf<2;nf++){
        int p = wcp*32 + nf*16 + r;
        f32x4 v = acc3[mf][nf];
        *(uint2*)(Sst + sb + (size_t)p*128 + nb) =
            make_uint2(pack2bf(v[0],v[1]), pack2bf(v[2],v[3]));
      }
    }
  }
}

// ---------------- pass 2: prefix-combine chunk states ----------------
template<int NCHT, int QCHT>
__global__ __launch_bounds__(256) void k_scan2(bf16* __restrict__ Sst, const float* __restrict__ dAv) {
  constexpr int SEG = QCHT/16;
  int blk = blockIdx.x;
  int bh = blk>>2, q = blk&3;
  int b = bh>>3, h = bh&7;
  int tid = threadIdx.x;
  __shared__ float sP[NCHT];
  {
    int c = tid / SEG, seg = tid & (SEG-1);
    float prod = 1.f;
    size_t base = ((size_t)b*L_ + c*QCHT + seg*16)*NH + h;
    #pragma unroll
    for (int k=0;k<16;k++) prod *= dAv[base + (size_t)k*NH];
    #pragma unroll
    for (int off=1; off<SEG; off<<=1) prod *= __shfl_xor(prod, off);
    if (seg==0) sP[c] = prod;
  }
  __syncthreads();
  int e0 = q*2048 + tid*8;
  float acc[8];
  #pragma unroll
  for (int j=0;j<8;j++) acc[j]=0.f;
  size_t sbase = (size_t)bh*NCHT*8192 + e0;
  for (int c=0;c<NCHT;c++){
    bf16* ptr = Sst + sbase + (size_t)c*8192;
    uint4 u = *(const uint4*)ptr;
    unsigned int uu[4] = {u.x,u.y,u.z,u.w};
    float tv[8];
    #pragma unroll
    for (int k=0;k<4;k++){
      tv[2*k]   = __uint_as_float(uu[k]<<16);
      tv[2*k+1] = __uint_as_float(uu[k]&0xffff0000u);
    }
    uint4 o;
    o.x = pack2bf(acc[0],acc[1]); o.y = pack2bf(acc[2],acc[3]);
    o.z = pack2bf(acc[4],acc[5]); o.w = pack2bf(acc[6],acc[7]);
    asm volatile("s_waitcnt vmcnt(0)" ::: "memory");
    *(uint4*)ptr = o;
    float P = sP[c];
    #pragma unroll
    for (int j=0;j<8;j++) acc[j] = tv[j] + P*acc[j];
  }
}

// ================= SSD pass 3: Y += exp(-eA*L_t) * (C x I_c), swapped (b64 RMW) =================
__global__ __launch_bounds__(256) void k_ssd3(const bf16* __restrict__ xbc,
    const float* __restrict__ dtv, const float* __restrict__ A_log,
    const bf16* __restrict__ Sst, bf16* __restrict__ ys) {
  int blk = blockIdx.x;
  int c = blk & (NCH-1), h = (blk>>5)&7, b = blk>>8;
  int tid = threadIdx.x;
  int lane = tid & 63, wid = tid >> 6;
  int r = lane & 15, q = lane >> 4;
  size_t rowbase = (size_t)b*L_ + (size_t)c*QCH;
  float eA = __expf(A_log[h]);

  __shared__ __align__(16) bf16 sC[128*128];
  __shared__ float sDT[128];
  __shared__ float sAt[128];
  __shared__ float sWT[2];

  #pragma unroll
  for (int i=0;i<8;i++){
    int id = i*256 + tid;
    int row = id >> 4, cg = id & 15;
    uint4 u = *(const uint4*)(xbc + (rowbase+row)*CONVDIM + DI + NS + cg*8);
    *(uint4*)&sC[row*128 + ((cg ^ (row&15))<<3)] = u;
  }
  if (tid < 128) sDT[tid] = dtv[(rowbase+tid)*NH + h];
  __syncthreads();
  float inc = 0.f;
  if (tid < 128){
    inc = sDT[tid];
    #pragma unroll
    for (int off=1; off<64; off<<=1){
      float u = __shfl_up(inc, off);
      if (lane >= off) inc += u;
    }
    if (lane==63) sWT[wid] = inc;
  }
  __syncthreads();
  if (tid < 128){
    if (wid==1) inc += sWT[0];
    sAt[tid] = __expf(-eA*inc);
  }
  __syncthreads();

  int wrp = wid >> 1, wct = wid & 1;
  size_t sb = (((size_t)(b*NH+h))*NCH + c)*8192;
  f32x4 accP[2][4];
  #pragma unroll
  for (int i=0;i<2;i++)
    #pragma unroll
    for (int j=0;j<4;j++) accP[i][j] = (f32x4){0.f,0.f,0.f,0.f};
  #pragma unroll
  for (int ks=0; ks<4; ks++){
    bf16x8 af[2], bfv[4];
    #pragma unroll
    for (int mf=0;mf<2;mf++){
      int p = wrp*32 + mf*16 + r;
      af[mf] = *(const bf16x8*)(Sst + sb + (size_t)p*128 + ks*32 + q*8);
    }
    #pragma unroll
    for (int nf=0;nf<4;nf++){
      int t = wct*64 + nf*16 + r;
      bfv[nf] = *(const bf16x8*)&sC[t*128 + (((ks*4+q) ^ (t&15))<<3)];
    }
    #pragma unroll
    for (int mf=0;mf<2;mf++)
      #pragma unroll
      for (int nf=0;nf<4;nf++)
        accP[mf][nf] = __builtin_amdgcn_mfma_f32_16x16x32_bf16(af[mf], bfv[nf], accP[mf][nf], 0, 0, 0);
  }
  #pragma unroll
  for (int mf=0;mf<2;mf++){
    int pb = wrp*32 + mf*16 + q*4;
    #pragma unroll
    for (int nf=0;nf<4;nf++){
      int t = wct*64 + nf*16 + r;
      float at = sAt[t];
      bf16* yp = ys + (rowbase+t)*DI + h*HD + pb;
      uint2 old = *(uint2*)yp;
      float o0 = bf2f((bf16)(old.x & 0xffffu))  + at*accP[mf][nf][0];
      float o1 = bf2f((bf16)(old.x >> 16))      + at*accP[mf][nf][1];
      float o2 = bf2f((bf16)(old.y & 0xffffu))  + at*accP[mf][nf][2];
      float o3 = bf2f((bf16)(old.y >> 16))      + at*accP[mf][nf][3];
      *(uint2*)yp = make_uint2(pack2bf(o0,o1), pack2bf(o2,o3));
    }
  }
}

// ---------------- y = (ys + D*xh)*silu(z), RMSNorm*w, in place (bf16) ----------------
__global__ __launch_bounds__(256) void k_combine(bf16* __restrict__ ys, const bf16* __restrict__ xbc,
                         const bf16* __restrict__ z, const float* __restrict__ Dp,
                         const float* __restrict__ nw) {
  int bl = blockIdx.x;
  int tid = threadIdx.x;
  bf16* yrow = ys + (size_t)bl*DI;
  const bf16* xrow = xbc + (size_t)bl*CONVDIM;
  const bf16* zrow = z + (size_t)bl*DI;
  float v[2]; float ss = 0.f;
  #pragma unroll
  for (int i=0;i<2;i++) {
    int d = tid + i*256;
    float xh = bf2f(xrow[d]);
    float y = bf2f(yrow[d]) + Dp[d>>6]*xh;
    float zv = bf2f(zrow[d]);
    y *= zv / (1.f + expf(-zv));
    v[i] = y; ss += y*y;
  }
  #pragma unroll
  for (int off=1; off<64; off<<=1) ss += __shfl_xor(ss, off);
  __shared__ float sb[4];
  if ((tid&63)==0) sb[tid>>6]=ss;
  __syncthreads();
  float total = sb[0]+sb[1]+sb[2]+sb[3];
  float scale = rsqrtf(total * (1.f/512.f) + 1e-5f);
  #pragma unroll
  for (int i=0;i<2;i++) {
    int d = tid + i*256;
    yrow[d] = f2bf(v[i]*scale*nw[d]);
  }
}

extern "C" void kernel_launch(void* const* d_in, const int* in_sizes, int n_in,
                              void* d_out, int out_size, void* d_ws, size_t ws_size,
                              hipStream_t stream) {
  const float* x         = (const float*)d_in[0];
  const float* conv_w    = (const float*)d_in[1];
  const float* conv_b    = (const float*)d_in[2];
  const float* bn_gamma  = (const float*)d_in[3];
  const float* bn_beta   = (const float*)d_in[4];
  const float* patch_w   = (const float*)d_in[5];
  const float* patch_b   = (const float*)d_in[6];
  const float* in_proj_w = (const float*)d_in[7];
  const float* conv1d_w  = (const float*)d_in[8];
  const float* conv1d_b  = (const float*)d_in[9];
  const float* dt_bias   = (const float*)d_in[10];
  const float* A_log     = (const float*)d_in[11];
  const float* Dp        = (const float*)d_in[12];
  const float* norm_w    = (const float*)d_in[13];
  const float* out_proj_w= (const float*)d_in[14];
  const float* final_w   = (const float*)d_in[15];
  const float* final_b   = (const float*)d_in[16];
  float* out = (float*)d_out;

  char* Wb = (char*)d_ws;
  float* h_buf = (float*)(Wb + 0);
  bf16*  winb  = (bf16*)(Wb + 0);
  bf16*  woutb = (bf16*)(Wb + 0);
  bf16*  wfinb = (bf16*)(Wb + 262144);
  bf16*  xpost = (bf16*)(Wb + 0);
  float2* part = (float2*)(Wb + 50331648);
  bf16*  tok   = (bf16*)(Wb + 50331648);
  bf16*  zbuf  = (bf16*)(Wb + 67108864);
  bf16*  y2b   = (bf16*)(Wb + 67108864);
  bf16*  xpre  = (bf16*)(Wb + 100663296);
  bf16*  ysb   = (bf16*)(Wb + 100663296);
  bf16*  Sst   = (bf16*)(Wb + 134217728);
  float* dtv   = (float*)(Wb + 134217728 + 33554432);
  float* dAv   = dtv + 262144;
  float* stats = dAv + 262144;
  const size_t NEED = 134217728ull + 33554432 + 2097152 + 256;
  if (ws_size < NEED) {
    hipMemsetAsync(d_out, 0, (size_t)out_size*sizeof(float), stream);
    return;
  }

  k_conv1<<<dim3((B_*CMID*HMID*WMID)/256), dim3(256), 0, stream>>>(x, conv_w, conv_b, h_buf);
  k_bnstatsA<<<dim3(512), dim3(256), 0, stream>>>(h_buf, part);
  k_bnstatsB<<<dim3(1), dim3(64), 0, stream>>>(part, stats);
  k_patch<<<dim3(MTOK/8), dim3(256), 0, stream>>>(h_buf, patch_w, patch_b, stats, bn_gamma, bn_beta, tok);
  k_cvtw<<<dim3((NPADIN*DM)/256), dim3(256), 0, stream>>>(in_proj_w, winb, PROJ, 8, NPADIN*DM);
  k_mgemm<0><<<dim3(MTOK/256, NPADIN/128), dim3(512), 0, stream>>>(tok, winb, DM,
      zbuf, xpre, nullptr, nullptr, dt_bias, A_log, dtv, dAv, nullptr, nullptr);
  k_conv1d<<<dim3((MTOK/8*96)/256), dim3(256), 0, stream>>>(xpre, conv1d_w, conv1d_b, xpost);
  k_ssd1<<<dim3(B_*NH*NCH), dim3(512), 0, stream>>>(xpost, dtv, A_log, ysb, Sst);
  k_scan2<NCH,QCH><<<dim3(B_*NH*4), dim3(256), 0, stream>>>(Sst, dAv);
  k_ssd3<<<dim3(B_*NH*NCH), dim3(256), 0, stream>>>(xpost, dtv, A_log, Sst, ysb);
  k_combine<<<dim3(MTOK), dim3(256), 0, stream>>>(ysb, xpost, zbuf, Dp, norm_w);
  k_cvtw<<<dim3((DM*DI)/256), dim3(256), 0, stream>>>(out_proj_w, woutb, DM, 9, DM*DI);
  k_cvtw<<<dim3((128*DM)/256), dim3(256), 0, stream>>>(final_w, wfinb, 64, 8, 128*DM);
  k_mgemm<1><<<dim3(MTOK/256, DM/128), dim3(512), 0, stream>>>(ysb, woutb, DI,
      nullptr, nullptr, y2b, tok, nullptr, nullptr, nullptr, nullptr, nullptr, nullptr);
  k_mgemm<2><<<dim3(MTOK/256, 1), dim3(512), 0, stream>>>(y2b, wfinb, DM,
      nullptr, nullptr, nullptr, nullptr, nullptr, nullptr, nullptr, nullptr, out, final_b);
}